// Round 10
// baseline (1678.532 us; speedup 1.0000x reference)
//
// FCGPFA variational iteration for MI355X (gfx950). Round 10:
// (a) left-looking register mini-chol: 1 LDS fence per column (was 3) and no
//     rank-1 LDS update -> chol64 critical path ~3x shorter (both fp64 setup
//     chols and the per-iteration fp32 chol);
// (b) iteration tail fused: k_pre+k_mhat+k_cholM+k_fin -> k_sys (one WG per
//     system; C staged once in LDS; no Wg/Mh2/grad/sv/del/u/y buffers);
// (c) setup fused: R-build+chol -> k_qinv; cfix dropped; dh0 = 1+eps exact.
//
#include <hip/hip_runtime.h>
#include <math.h>

namespace {
constexpr int Mb   = 16;
constexpr int Nn   = 96;
constexpr int NTF  = 350;
constexpr int Tt   = 300;
constexpr int NSUB = 8;
constexpr int NTAU = 20;
constexpr int NL   = 8;
constexpr int ML   = Mb * NL;   // 128 systems
constexpr int R_   = 64;        // low-rank dimension
constexpr int LDA  = 65;        // A/W row stride
constexpr int CLL  = 67;        // C LDS row stride (odd -> 2-way banks)
constexpr float EPS = 0.001f;
}

__device__ __forceinline__ float  sqrt_(float x)  { return sqrtf(x); }
__device__ __forceinline__ double sqrt_(double x) { return sqrt(x); }

__device__ __forceinline__ void lfence() {
  asm volatile("s_waitcnt lgkmcnt(0)" ::: "memory");
}

// ---------------- 32x32 GEMM helpers on 256 threads (proven r5-r9) ----------
template <typename T, bool ACC>
__device__ __forceinline__ void gemm32(T* __restrict__ D, const T* __restrict__ A,
                                       const T* __restrict__ B, int lda, int ldb,
                                       int ldd, int tid) {
  const int r = tid & 31, c0 = (tid >> 5) * 4;
  T a0 = ACC ? D[r * ldd + c0 + 0] : (T)0;
  T a1 = ACC ? D[r * ldd + c0 + 1] : (T)0;
  T a2 = ACC ? D[r * ldd + c0 + 2] : (T)0;
  T a3 = ACC ? D[r * ldd + c0 + 3] : (T)0;
  for (int k = 0; k < 32; ++k) {
    const T a = A[r * lda + k];
    a0 += a * B[k * ldb + c0 + 0];
    a1 += a * B[k * ldb + c0 + 1];
    a2 += a * B[k * ldb + c0 + 2];
    a3 += a * B[k * ldb + c0 + 3];
  }
  D[r * ldd + c0 + 0] = a0; D[r * ldd + c0 + 1] = a1;
  D[r * ldd + c0 + 2] = a2; D[r * ldd + c0 + 3] = a3;
}

template <typename T>
__device__ __forceinline__ void gemm32_neg(T* __restrict__ D, const T* __restrict__ A,
                                           const T* __restrict__ B, int lda, int ldb,
                                           int ldd, int tid) {
  const int r = tid & 31, c0 = (tid >> 5) * 4;
  T a0 = (T)0, a1 = (T)0, a2 = (T)0, a3 = (T)0;
  for (int k = 0; k < 32; ++k) {
    const T a = A[r * lda + k];
    a0 += a * B[k * ldb + c0 + 0];
    a1 += a * B[k * ldb + c0 + 1];
    a2 += a * B[k * ldb + c0 + 2];
    a3 += a * B[k * ldb + c0 + 3];
  }
  D[r * ldd + c0 + 0] = -a0; D[r * ldd + c0 + 1] = -a1;
  D[r * ldd + c0 + 2] = -a2; D[r * ldd + c0 + 3] = -a3;
}

// ------------- 64x64 Cholesky (lower) + W = L^-1, 256 threads ---------------
// A (stride 65) LDS: full symmetric in, lower = L out. W (65, LDS or global):
// block-lower inverse (upper-right block untouched and never read).
// rd: 64 inv-pivots. V2: 2*32*33 scratch. buf: >=33 broadcast row.
// Mini-chol: LEFT-LOOKING, lane r owns row r in registers, ONE lfence/column
// (wave-level broadcast identical in mechanism to the r1-r9-proven pattern;
// in-order DS pipe per wave covers read-before-next-write, proven r5-r9).
template <typename T>
__device__ void chol64_trtri64(T* __restrict__ A, T* __restrict__ W,
                               T* __restrict__ rd, T* __restrict__ V2,
                               T* __restrict__ buf, int tid) {
  for (int pb = 0; pb < 2; ++pb) {
    const int o = pb * 32;
    if (tid < 64) {
      const int r = tid;               // lanes 32..63: dummies
      T v[32];
      if (r < 32) {
#pragma unroll
        for (int k = 0; k < 32; ++k) v[k] = A[(o + r) * LDA + (o + k)];
      } else {
#pragma unroll
        for (int k = 0; k < 32; ++k) v[k] = (T)0;
      }
      T myis = (T)0;
#pragma unroll
      for (int c = 0; c < 32; ++c) {
        if (r == c) {                  // broadcast finalized row c (+ raw pivot)
#pragma unroll
          for (int k = 0; k <= c; ++k) buf[k] = v[k];
        }
        lfence();
        T dotp = (T)0, dotv = (T)0;
#pragma unroll
        for (int k = 0; k < c; ++k) {
          const T b = buf[k];
          dotp += b * b;
          dotv += v[k] * b;
        }
        const T psq = buf[c] - dotp;   // all lanes compute pivot redundantly
        T s, is;
        if (psq > (T)1e-12) { s = sqrt_(psq); is = (T)1 / s; }
        else                { s = (T)0;       is = (T)0; }
        if (r == c)                 { v[c] = s; myis = is; }
        else if (r > c && r < 32)   v[c] = (v[c] - dotv) * is;
      }
      if (r < 32) {
#pragma unroll
        for (int k = 0; k < 32; ++k) if (k <= r) A[(o + r) * LDA + (o + k)] = v[k];
        rd[o + r] = myis;
      }
    }
    __syncthreads();
    if (pb == 0) {
      // panel solve rows 32..63 (diag-block L rows broadcast from A)
      if (tid < 32) {
        const int i = 32 + tid;
        T v[32];
#pragma unroll
        for (int c = 0; c < 32; ++c) v[c] = A[i * LDA + c];
#pragma unroll
        for (int c = 0; c < 32; ++c) {
          T acc = v[c];
          for (int k = 0; k < c; ++k) acc -= v[k] * A[c * LDA + k];
          v[c] = acc * rd[c];
        }
#pragma unroll
        for (int c = 0; c < 32; ++c) A[i * LDA + c] = v[c];
      }
      __syncthreads();
      // trailing update (32..63)^2 lower, 36 4x4 tiles (proven r9)
      for (int tix = tid; tix < 36; tix += 256) {
        int ti = (int)((sqrtf(8.f * (float)tix + 1.f) - 1.f) * 0.5f);
        while ((ti + 1) * (ti + 2) / 2 <= tix) ++ti;
        while (ti * (ti + 1) / 2 > tix) --ti;
        const int tj = tix - ti * (ti + 1) / 2;
        const int gi = 32 + ti * 4, gj = 32 + tj * 4;
        T acc[4][4];
#pragma unroll
        for (int r = 0; r < 4; ++r)
#pragma unroll
          for (int c = 0; c < 4; ++c) acc[r][c] = (T)0;
        for (int k = 0; k < 32; ++k) {
          T a[4], b[4];
#pragma unroll
          for (int r = 0; r < 4; ++r) a[r] = A[(gi + r) * LDA + k];
#pragma unroll
          for (int c = 0; c < 4; ++c) b[c] = A[(gj + c) * LDA + k];
#pragma unroll
          for (int r = 0; r < 4; ++r)
#pragma unroll
            for (int c = 0; c < 4; ++c) acc[r][c] += a[r] * b[c];
        }
#pragma unroll
        for (int r = 0; r < 4; ++r)
#pragma unroll
          for (int c = 0; c < 4; ++c)
            A[(gi + r) * LDA + (gj + c)] -= acc[r][c];
      }
      __syncthreads();
    }
  }
  // diag-block inverses: 2 waves, lane = column (in-order DS pipe; proven)
  {
    const int wv = tid >> 6, lane = tid & 63;
    if (wv < 2 && lane < 32) {
      const int o = wv * 32, c = lane;
      T* V = V2 + wv * 32 * 33;
      V[c * 33 + c] = rd[o + c];
      for (int r = c + 1; r < 32; ++r) {
        T acc = (T)0;
        for (int k = c; k < r; ++k)
          acc += A[(o + r) * LDA + (o + k)] * V[k * 33 + c];
        V[r * 33 + c] = -acc * rd[o + r];
      }
      for (int r = 0; r < 32; ++r)
        W[(o + r) * LDA + (o + c)] = (r < c) ? (T)0 : V[r * 33 + c];
    }
  }
  __syncthreads();
  // off-diagonal: W10 = -W11 (L10 W00), V2 reused as 33-stride scratch
  gemm32<T, false>(V2, A + 32 * LDA, W, LDA, LDA, 33, tid);
  __syncthreads();
  gemm32_neg<T>(W + 32 * LDA, W + 32 * LDA + 32, V2, LDA, 33, LDA, tid);
  __syncthreads();
}

// ---------------------------------------------------------------- S1: weights
__global__ __launch_bounds__(256) void k_weights(
    const float* __restrict__ Yraw, const float* __restrict__ kern,
    const float* __restrict__ wproj, float* __restrict__ WA,
    float* __restrict__ WB, float* __restrict__ Yt) {
  __shared__ float sk[NTAU * NSUB];
  __shared__ float sp[NSUB * NL];
  const int tid = threadIdx.x;
  if (tid < NTAU * NSUB) sk[tid] = kern[tid];
  if (tid < NSUB * NL)   sp[tid] = wproj[tid];
  __syncthreads();
  const int g = blockIdx.x * 256 + tid;            // g = (m*Tt + t)*Nn + n
  if (g >= Mb * Tt * Nn) return;
  const int n  = g % Nn;
  const int mt = g / Nn;
  const int t  = mt % Tt;
  const int m  = mt / Tt;
  const float* yr = Yraw + ((size_t)m * Nn + n) * NTF + 30 + t;
  float ya[NTAU + 1];
#pragma unroll
  for (int j = 0; j <= NTAU; ++j) ya[j] = yr[j];
  float gs[NSUB];
#pragma unroll
  for (int s = 0; s < NSUB; ++s) {
    float acc = 0.f;
#pragma unroll
    for (int j = 0; j < NTAU; ++j) acc += ya[j] * sk[(NTAU - 1 - j) * NSUB + s];
    gs[s] = (fabsf(acc) < 1e-5f) ? 0.f : acc;      // reference threshold
  }
  float w[NL];
#pragma unroll
  for (int l = 0; l < NL; ++l) {
    float acc = 0.f;
#pragma unroll
    for (int s = 0; s < NSUB; ++s) acc += gs[s] * sp[s * NL + l];
    w[l] = acc;
  }
  float4* wa4 = reinterpret_cast<float4*>(WA + (size_t)g * NL);
  wa4[0] = make_float4(w[0], w[1], w[2], w[3]);
  wa4[1] = make_float4(w[4], w[5], w[6], w[7]);
#pragma unroll
  for (int l = 0; l < NL; ++l)
    WB[(((size_t)m * NL + l) * Tt + t) * Nn + n] = w[l];
  Yt[g] = ya[NTAU];
}

// ---- S2a: M = K[S,S] (pivot order) -> fp64 chol64+trtri64 -> W_S (global) --
__global__ __launch_bounds__(256) void k_scholM(
    const float* __restrict__ K, double* __restrict__ WS64) {
  __shared__ double A[R_ * LDA];
  __shared__ double V2[2 * 32 * 33];
  __shared__ double rd[R_];
  __shared__ double buf[40];
  const int tid = threadIdx.x;
  for (int e = tid; e < R_ * R_; e += 256) {
    const int a = e >> 6, b = e & 63;
    const int pa = (a * 103) % Tt, pb = (b * 103) % Tt;
    A[a * LDA + b] = (double)K[(size_t)pa * Tt + pb];
  }
  __syncthreads();
  chol64_trtri64<double>(A, WS64, rd, V2, buf, tid);
}

// ---- S2b: C[t][k] = sum_{j<=k} W_S[k][j] * K[p_j][t]  (64 WGs, coalesced) --
__global__ __launch_bounds__(320) void k_cmake(
    const float* __restrict__ K, const double* __restrict__ WS64,
    float* __restrict__ Cg) {
  const int k = blockIdx.x;            // 0..63
  __shared__ double wrow[R_];
  const int t = threadIdx.x;
  if (t < R_) wrow[t] = WS64[(size_t)k * LDA + t];
  __syncthreads();
  if (t < Tt) {
    double acc = 0.0;
    for (int j = 0; j <= k; ++j)
      acc += wrow[j] * (double)K[(size_t)((j * 103) % Tt) * Tt + t];
    Cg[(size_t)t * R_ + k] = (float)acc;
  }
}

// ---- S3a: R = eps I + C^T C (fp64, in LDS) -> chol64+trtri64 -> W (global) -
__global__ __launch_bounds__(256) void k_qinv(
    const float* __restrict__ Cg, double* __restrict__ W64) {
  __shared__ float  Cf[Tt * CLL];      // 80.4 KB
  __shared__ double A[R_ * LDA];       // 33.3 KB
  __shared__ double V2[2 * 32 * 33];   // 16.9 KB
  __shared__ double rd[R_];
  __shared__ double buf[40];
  const int tid = threadIdx.x;
  for (int e = tid; e < Tt * R_; e += 256) {
    const int r = e >> 6, c = e & 63;
    Cf[r * CLL + c] = Cg[e];
  }
  __syncthreads();
  // R lower-half via 4x4 tiles (a >= b), mirror write, +eps on diag
  {
    const int a = tid & 15, b = tid >> 4;
    if (a >= b) {
      const int i0 = a * 4, j0 = b * 4;
      double acc[4][4];
#pragma unroll
      for (int r = 0; r < 4; ++r)
#pragma unroll
        for (int c = 0; c < 4; ++c) acc[r][c] = 0.0;
      for (int t = 0; t < Tt; ++t) {
        float ua[4], vb[4];
#pragma unroll
        for (int q = 0; q < 4; ++q) {
          ua[q] = Cf[t * CLL + i0 + q];
          vb[q] = Cf[t * CLL + j0 + q];
        }
#pragma unroll
        for (int r = 0; r < 4; ++r)
#pragma unroll
          for (int c = 0; c < 4; ++c) acc[r][c] += (double)ua[r] * (double)vb[c];
      }
#pragma unroll
      for (int r = 0; r < 4; ++r)
#pragma unroll
        for (int c = 0; c < 4; ++c) {
          const int gi = i0 + r, gj = j0 + c;
          const double v = acc[r][c] + ((gi == gj) ? 0.001 : 0.0);
          A[gi * LDA + gj] = v;
          if (a > b) A[gj * LDA + gi] = v;
        }
    }
  }
  __syncthreads();
  chol64_trtri64<double>(A, W64, rd, V2, buf, tid);
}

// --------------- S3b: Q64 = W^T W (fp64, 16 WGs, proven) --------------------
__global__ __launch_bounds__(256) void k_qmul(
    const double* __restrict__ W64, double* __restrict__ Qg) {
  const int e = blockIdx.x * 256 + threadIdx.x;
  if (e >= R_ * R_) return;
  const int i = e >> 6, j = e & 63;
  const int k0 = (i > j) ? i : j;
  double acc = 0.0;
  for (int k = k0; k < R_; ++k) acc += W64[k * LDA + i] * W64[k * LDA + j];
  Qg[e] = acc;
}

// ------------------------------- S4: init (dh0 = 1 + eps: Khat[t][t]=1+-1e-8)
__global__ __launch_bounds__(256) void k_init(
    float* __restrict__ mu, float* __restrict__ dh) {
  const int g = blockIdx.x * 256 + threadIdx.x;
  if (g >= Mb * Tt * NL) return;
  mu[g] = 0.f;
  dh[g] = 1.0f + EPS;
}

// ---------------------------------------------------------------- I1: lambda
__global__ __launch_bounds__(256) void k_lambda(
    const float* __restrict__ WA, const float* __restrict__ mu,
    const float* __restrict__ dh, const float* __restrict__ biasp,
    float* __restrict__ lam) {
  const int g = blockIdx.x * 256 + threadIdx.x;
  if (g >= Mb * Tt * Nn) return;
  const int mt = g / Nn;
  const float b = biasp[0];
  const float4* wa = reinterpret_cast<const float4*>(WA + (size_t)g * NL);
  const float4* mp = reinterpret_cast<const float4*>(mu + (size_t)mt * NL);
  const float4* dp = reinterpret_cast<const float4*>(dh + (size_t)mt * NL);
  const float4 w0 = wa[0], w1 = wa[1];
  const float4 m0 = mp[0], m1 = mp[1];
  const float4 h0 = dp[0], h1 = dp[1];
  float e = b;
  e += w0.x * (m0.x + 0.5f * w0.x * h0.x);
  e += w0.y * (m0.y + 0.5f * w0.y * h0.y);
  e += w0.z * (m0.z + 0.5f * w0.z * h0.z);
  e += w0.w * (m0.w + 0.5f * w0.w * h0.w);
  e += w1.x * (m1.x + 0.5f * w1.x * h1.x);
  e += w1.y * (m1.y + 0.5f * w1.y * h1.y);
  e += w1.z * (m1.z + 0.5f * w1.z * h1.z);
  e += w1.w * (m1.w + 0.5f * w1.w * h1.w);
  lam[g] = expf(e);
}

// --------------------------------------- I2: g1 = W^T(Y-lam), d = (W^2)^T lam
__global__ __launch_bounds__(320) void k_gd(
    const float* __restrict__ WB, const float* __restrict__ Yt,
    const float* __restrict__ lam, float* __restrict__ g1, float* __restrict__ dvec) {
  const int ml = blockIdx.x;
  const int m = ml / NL;
  const int t = threadIdx.x;
  if (t >= Tt) return;
  float ga = 0.f, dd = 0.f;
  const float4* wb = reinterpret_cast<const float4*>(WB + ((size_t)ml * Tt + t) * Nn);
  const float4* yt = reinterpret_cast<const float4*>(Yt + ((size_t)m * Tt + t) * Nn);
  const float4* la = reinterpret_cast<const float4*>(lam + ((size_t)m * Tt + t) * Nn);
  for (int q = 0; q < Nn / 4; ++q) {
    const float4 w = wb[q], y = yt[q], v = la[q];
    ga += w.x * (y.x - v.x) + w.y * (y.y - v.y) + w.z * (y.z - v.z) + w.w * (y.w - v.w);
    dd += w.x * w.x * v.x + w.y * w.y * v.y + w.z * w.z * v.z + w.w * w.w * v.w;
  }
  g1[(size_t)ml * Tt + t]   = ga;
  dvec[(size_t)ml * Tt + t] = dd;
}

// ---- I3: fused per-system solve: pre + Mhat + chol + trtri + y + fin -------
__global__ __launch_bounds__(256) void k_sys(
    const float* __restrict__ Cg, const double* __restrict__ Qg,
    const float* __restrict__ g1, const float* __restrict__ dvec,
    float* __restrict__ mug, float* __restrict__ dhg) {
  const int ml = blockIdx.x;
  const int mt = ml / NL, lat = ml % NL;
  const int tid = threadIdx.x;
  __shared__ float  Cf[Tt * CLL];      // 80.4 KB
  __shared__ float  A[R_ * LDA];       // 16.6 KB
  __shared__ float  W[R_ * LDA];       // 16.6 KB
  __shared__ float  V2[2 * 32 * 33];   // 8.4 KB
  __shared__ float  rd[R_];
  __shared__ float  buf[40];
  __shared__ float  muv[Tt], gv[Tt], sv[Tt], dl[Tt], sg[Tt];
  __shared__ double pv[R_], qv[R_];
  __shared__ double partd[R_][5];
  __shared__ float  partf[R_][5];
  __shared__ float  uv[R_], t1v[R_], yv[R_];

  // P1: stage C (coalesced) + P2: vectors
  for (int e = tid; e < Tt * R_; e += 256) {
    const int r = e >> 6, c = e & 63;
    Cf[r * CLL + c] = Cg[e];
  }
  for (int t = tid; t < Tt; t += 256) {
    const float m_ = mug[((size_t)mt * Tt + t) * NL + lat];
    const float g_ = g1[(size_t)ml * Tt + t];
    const float d_ = dvec[(size_t)ml * Tt + t];
    muv[t] = m_; gv[t] = g_;
    const float s = 1.f / (1.f + EPS * d_);
    sv[t] = s;
    dl[t] = d_ * s;
  }
  __syncthreads();
  // P3: pv = C^T mu (fp64, 64 cols x 5 chunks of 60)
  for (int w = tid; w < R_ * 5; w += 256) {
    const int k = w / 5, ch = w - (w / 5) * 5;
    double acc = 0.0;
    const int t0 = ch * 60;
    for (int t = t0; t < t0 + 60; ++t)
      acc += (double)Cf[t * CLL + k] * (double)muv[t];
    partd[k][ch] = acc;
  }
  __syncthreads();
  if (tid < R_) {
    double a = 0.0;
#pragma unroll
    for (int ch = 0; ch < 5; ++ch) a += partd[tid][ch];
    pv[tid] = a;
  }
  __syncthreads();
  // P4: qv = Q pv (fp64, coalesced global)
  if (tid < R_) {
    double acc = 0.0;
    for (int j = 0; j < R_; ++j) acc += Qg[(size_t)j * R_ + tid] * pv[j];
    qv[tid] = acc;
  }
  __syncthreads();
  // P5: grad = g1 - 1000*(mu - C q) [fp64 inner]; sg = s*grad
  for (int t = tid; t < Tt; t += 256) {
    double cq = 0.0;
    for (int k = 0; k < R_; ++k) cq += (double)Cf[t * CLL + k] * qv[k];
    const double gnew = (double)gv[t] - 1000.0 * ((double)muv[t] - cq);
    const float gf = (float)gnew;
    gv[t] = gf;
    sg[t] = sv[t] * gf;
  }
  __syncthreads();
  // P6: uv = C^T sg (fp32 partial scheme)
  for (int w = tid; w < R_ * 5; w += 256) {
    const int k = w / 5, ch = w - (w / 5) * 5;
    float acc = 0.f;
    const int t0 = ch * 60;
    for (int t = t0; t < t0 + 60; ++t) acc += Cf[t * CLL + k] * sg[t];
    partf[k][ch] = acc;
  }
  __syncthreads();
  if (tid < R_) {
    float a = 0.f;
#pragma unroll
    for (int ch = 0; ch < 5; ++ch) a += partf[tid][ch];
    uv[tid] = a;
  }
  // P7: Mhat = I + C^T diag(dl) C -> A (4x4 tiles a>=b, mirror; no return!)
  {
    const int a = tid & 15, b = tid >> 4;
    if (a >= b) {
      const int i0 = a * 4, j0 = b * 4;
      float acc[4][4];
#pragma unroll
      for (int r = 0; r < 4; ++r)
#pragma unroll
        for (int c = 0; c < 4; ++c) acc[r][c] = 0.f;
      for (int t = 0; t < Tt; ++t) {
        const float w = dl[t];
        float ua[4], vb[4];
#pragma unroll
        for (int q = 0; q < 4; ++q) {
          ua[q] = Cf[t * CLL + i0 + q] * w;
          vb[q] = Cf[t * CLL + j0 + q];
        }
#pragma unroll
        for (int r = 0; r < 4; ++r)
#pragma unroll
          for (int c = 0; c < 4; ++c) acc[r][c] += ua[r] * vb[c];
      }
#pragma unroll
      for (int r = 0; r < 4; ++r)
#pragma unroll
        for (int c = 0; c < 4; ++c) {
          const int gi = i0 + r, gj = j0 + c;
          A[gi * LDA + gj] = acc[r][c] + ((gi == gj) ? 1.f : 0.f);
          if (a > b) A[gj * LDA + gi] = acc[r][c];
        }
    }
  }
  __syncthreads();
  // P8: chol + trtri (fp32, left-looking mini-chol)
  chol64_trtri64<float>(A, W, rd, V2, buf, tid);
  // P9: y = W^T (W u)
  if (tid < R_) {
    float acc = 0.f;
    for (int j = 0; j <= tid; ++j) acc += W[tid * LDA + j] * uv[j];
    t1v[tid] = acc;
  }
  __syncthreads();
  if (tid < R_) {
    float acc = 0.f;
    for (int i = tid; i < R_; ++i) acc += W[i * LDA + tid] * t1v[i];
    yv[tid] = acc;
  }
  __syncthreads();
  // P10: per row t: jsq = ||W c_t||^2 (triangular), cy = c_t . y; mu,dh out
  for (int t = tid; t < Tt; t += 256) {
    float jsq = 0.f;
    for (int j = 0; j < R_; ++j) {
      float x = 0.f;
      for (int k = 0; k <= j; ++k) x += Cf[t * CLL + k] * W[j * LDA + k];
      jsq += x * x;
    }
    float cy = 0.f;
    for (int k = 0; k < R_; ++k) cy += Cf[t * CLL + k] * yv[k];
    const float s = sv[t];
    const size_t idx = ((size_t)mt * Tt + t) * NL + lat;
    const float x2 = EPS * s * gv[t] + s * cy;
    mug[idx] = muv[t] + 0.5f * x2;                  // LR = 0.5
    dhg[idx] = -(EPS * s + s * s * jsq);
  }
}

// ---------------------------------------------------------------- F1: output
__global__ __launch_bounds__(256) void k_out(
    const float* __restrict__ mu, float* __restrict__ out) {
  const int g = blockIdx.x * 256 + threadIdx.x;   // g = (m*NL + l)*Tt + t
  if (g >= Mb * NL * Tt) return;
  const int t = g % Tt;
  const int ml = g / Tt;
  const int m = ml / NL, l = ml % NL;
  out[g] = mu[((size_t)m * Tt + t) * NL + l];
}

// ------------------------------------------------------------------- launcher
extern "C" void kernel_launch(void* const* d_in, const int* in_sizes, int n_in,
                              void* d_out, int out_size, void* d_ws, size_t ws_size,
                              hipStream_t stream) {
  (void)in_sizes; (void)n_in; (void)out_size;
  const float* Yraw  = (const float*)d_in[0];
  const float* kern  = (const float*)d_in[1];
  const float* wproj = (const float*)d_in[2];
  const float* K     = (const float*)d_in[3];
  const float* biasp = (const float*)d_in[4];
  float* out = (float*)d_out;

  char* base = (char*)d_ws;
  size_t off = 0;
  auto alloc = [&](size_t bytes) -> void* {
    void* p = base + off;
    off += (bytes + 511) & ~(size_t)511;
    return p;
  };
  float*  WA    = (float*) alloc((size_t)Mb * Tt * Nn * NL * 4);
  float*  WB    = (float*) alloc((size_t)Mb * Tt * Nn * NL * 4);
  float*  Yt    = (float*) alloc((size_t)Mb * Tt * Nn * 4);
  float*  lam   = (float*) alloc((size_t)Mb * Tt * Nn * 4);
  float*  mu    = (float*) alloc((size_t)Mb * Tt * NL * 4);
  float*  dh    = (float*) alloc((size_t)Mb * Tt * NL * 4);
  float*  g1    = (float*) alloc((size_t)ML * Tt * 4);
  float*  dvec  = (float*) alloc((size_t)ML * Tt * 4);
  float*  Cg    = (float*) alloc((size_t)Tt * R_ * 4);
  double* WS64  = (double*)alloc((size_t)R_ * LDA * 8);
  double* W64   = (double*)alloc((size_t)R_ * LDA * 8);
  double* Q64   = (double*)alloc((size_t)R_ * R_ * 8);
  if (off > ws_size) return;

  const int gMTN = (Mb * Tt * Nn) / 256;       // 1800
  const int gMTL = (Mb * Tt * NL + 255) / 256; // 150
  const int gRR  = (R_ * R_ + 255) / 256;      // 16

  k_weights<<<gMTN, 256, 0, stream>>>(Yraw, kern, wproj, WA, WB, Yt);
  k_scholM<<<1, 256, 0, stream>>>(K, WS64);
  k_cmake<<<R_, 320, 0, stream>>>(K, WS64, Cg);
  k_qinv<<<1, 256, 0, stream>>>(Cg, W64);
  k_qmul<<<gRR, 256, 0, stream>>>(W64, Q64);
  k_init<<<gMTL, 256, 0, stream>>>(mu, dh);

  for (int it = 0; it < 5; ++it) {
    k_lambda<<<gMTN, 256, 0, stream>>>(WA, mu, dh, biasp, lam);
    k_gd<<<ML, 320, 0, stream>>>(WB, Yt, lam, g1, dvec);
    k_sys<<<ML, 256, 0, stream>>>(Cg, Q64, g1, dvec, mu, dh);
  }
  k_out<<<gMTL, 256, 0, stream>>>(mu, out);
}

// Round 11
// 898.469 us; speedup vs baseline: 1.8682x; 1.8682x over previous
//
// FCGPFA variational iteration for MI355X (gfx950). Round 11:
// round-9 multi-kernel iteration structure (proven 1113us; round-10's k_sys
// mega-fusion regressed to 1 WG/CU and is reverted) + round-10's two proven
// wins: (a) left-looking 1-fence register mini-chol in all chol64 call sites
// (~3x shorter serial chain; HW-verified correct in r10); (b) fused setup
// k_qinv = R-build + chol (k_rmul/k_qchol dropped), dh0 = 1+eps constant.
//
#include <hip/hip_runtime.h>
#include <math.h>

namespace {
constexpr int Mb   = 16;
constexpr int Nn   = 96;
constexpr int NTF  = 350;
constexpr int Tt   = 300;
constexpr int NSUB = 8;
constexpr int NTAU = 20;
constexpr int NL   = 8;
constexpr int ML   = Mb * NL;   // 128 systems
constexpr int R_   = 64;        // low-rank dimension (2 x 32)
constexpr int CS   = 65;        // C global row stride
constexpr int CL   = 66;        // C LDS row stride (even -> float2 ok)
constexpr int LDA  = 65;        // A/W row stride
constexpr int TP   = 320;
constexpr int CROWS= 384;       // C rows padded for 4 x 96 t-blocks
constexpr float EPS = 0.001f;
}

__device__ __forceinline__ float  sqrt_(float x)  { return sqrtf(x); }
__device__ __forceinline__ double sqrt_(double x) { return sqrt(x); }

__device__ __forceinline__ void lfence() {
  asm volatile("s_waitcnt lgkmcnt(0)" ::: "memory");
}

// ---------------- 32x32 GEMM helpers on 256 threads (proven r5-r10) ---------
template <typename T, bool ACC>
__device__ __forceinline__ void gemm32(T* __restrict__ D, const T* __restrict__ A,
                                       const T* __restrict__ B, int lda, int ldb,
                                       int ldd, int tid) {
  const int r = tid & 31, c0 = (tid >> 5) * 4;
  T a0 = ACC ? D[r * ldd + c0 + 0] : (T)0;
  T a1 = ACC ? D[r * ldd + c0 + 1] : (T)0;
  T a2 = ACC ? D[r * ldd + c0 + 2] : (T)0;
  T a3 = ACC ? D[r * ldd + c0 + 3] : (T)0;
  for (int k = 0; k < 32; ++k) {
    const T a = A[r * lda + k];
    a0 += a * B[k * ldb + c0 + 0];
    a1 += a * B[k * ldb + c0 + 1];
    a2 += a * B[k * ldb + c0 + 2];
    a3 += a * B[k * ldb + c0 + 3];
  }
  D[r * ldd + c0 + 0] = a0; D[r * ldd + c0 + 1] = a1;
  D[r * ldd + c0 + 2] = a2; D[r * ldd + c0 + 3] = a3;
}

template <typename T>
__device__ __forceinline__ void gemm32_neg(T* __restrict__ D, const T* __restrict__ A,
                                           const T* __restrict__ B, int lda, int ldb,
                                           int ldd, int tid) {
  const int r = tid & 31, c0 = (tid >> 5) * 4;
  T a0 = (T)0, a1 = (T)0, a2 = (T)0, a3 = (T)0;
  for (int k = 0; k < 32; ++k) {
    const T a = A[r * lda + k];
    a0 += a * B[k * ldb + c0 + 0];
    a1 += a * B[k * ldb + c0 + 1];
    a2 += a * B[k * ldb + c0 + 2];
    a3 += a * B[k * ldb + c0 + 3];
  }
  D[r * ldd + c0 + 0] = -a0; D[r * ldd + c0 + 1] = -a1;
  D[r * ldd + c0 + 2] = -a2; D[r * ldd + c0 + 3] = -a3;
}

// ------------- 64x64 Cholesky (lower) + W = L^-1, 256 threads ---------------
// Left-looking register mini-chol, ONE lfence/column (HW-verified r10).
// A (stride 65) LDS: full symmetric in, lower = L out. W: block-lower inverse
// (pre-zero W). rd: 64 inv-pivots. V2: 2*32*33. buf: >=33 broadcast row.
template <typename T>
__device__ void chol64_trtri64(T* __restrict__ A, T* __restrict__ W,
                               T* __restrict__ rd, T* __restrict__ V2,
                               T* __restrict__ buf, int tid) {
  for (int pb = 0; pb < 2; ++pb) {
    const int o = pb * 32;
    if (tid < 64) {
      const int r = tid;               // lanes 32..63: dummies
      T v[32];
      if (r < 32) {
#pragma unroll
        for (int k = 0; k < 32; ++k) v[k] = A[(o + r) * LDA + (o + k)];
      } else {
#pragma unroll
        for (int k = 0; k < 32; ++k) v[k] = (T)0;
      }
      T myis = (T)0;
#pragma unroll
      for (int c = 0; c < 32; ++c) {
        if (r == c) {                  // broadcast finalized row c (+ raw pivot)
#pragma unroll
          for (int k = 0; k <= c; ++k) buf[k] = v[k];
        }
        lfence();
        T dotp = (T)0, dotv = (T)0;
#pragma unroll
        for (int k = 0; k < c; ++k) {
          const T b = buf[k];
          dotp += b * b;
          dotv += v[k] * b;
        }
        const T psq = buf[c] - dotp;   // all lanes compute pivot redundantly
        T s, is;
        if (psq > (T)1e-12) { s = sqrt_(psq); is = (T)1 / s; }
        else                { s = (T)0;       is = (T)0; }
        if (r == c)                 { v[c] = s; myis = is; }
        else if (r > c && r < 32)   v[c] = (v[c] - dotv) * is;
      }
      if (r < 32) {
#pragma unroll
        for (int k = 0; k < 32; ++k) if (k <= r) A[(o + r) * LDA + (o + k)] = v[k];
        rd[o + r] = myis;
      }
    }
    __syncthreads();
    if (pb == 0) {
      // panel solve rows 32..63 (diag-block L rows read from A)
      if (tid < 32) {
        const int i = 32 + tid;
        T v[32];
#pragma unroll
        for (int c = 0; c < 32; ++c) v[c] = A[i * LDA + c];
#pragma unroll
        for (int c = 0; c < 32; ++c) {
          T acc = v[c];
          for (int k = 0; k < c; ++k) acc -= v[k] * A[c * LDA + k];
          v[c] = acc * rd[c];
        }
#pragma unroll
        for (int c = 0; c < 32; ++c) A[i * LDA + c] = v[c];
      }
      __syncthreads();
      // trailing update (32..63)^2 lower, 36 4x4 tiles (proven)
      for (int tix = tid; tix < 36; tix += 256) {
        int ti = (int)((sqrtf(8.f * (float)tix + 1.f) - 1.f) * 0.5f);
        while ((ti + 1) * (ti + 2) / 2 <= tix) ++ti;
        while (ti * (ti + 1) / 2 > tix) --ti;
        const int tj = tix - ti * (ti + 1) / 2;
        const int gi = 32 + ti * 4, gj = 32 + tj * 4;
        T acc[4][4];
#pragma unroll
        for (int r = 0; r < 4; ++r)
#pragma unroll
          for (int c = 0; c < 4; ++c) acc[r][c] = (T)0;
        for (int k = 0; k < 32; ++k) {
          T a[4], b[4];
#pragma unroll
          for (int r = 0; r < 4; ++r) a[r] = A[(gi + r) * LDA + k];
#pragma unroll
          for (int c = 0; c < 4; ++c) b[c] = A[(gj + c) * LDA + k];
#pragma unroll
          for (int r = 0; r < 4; ++r)
#pragma unroll
            for (int c = 0; c < 4; ++c) acc[r][c] += a[r] * b[c];
        }
#pragma unroll
        for (int r = 0; r < 4; ++r)
#pragma unroll
          for (int c = 0; c < 4; ++c)
            A[(gi + r) * LDA + (gj + c)] -= acc[r][c];
      }
      __syncthreads();
    }
  }
  // diag-block inverses: 2 waves, lane = column (in-order DS pipe; proven)
  {
    const int wv = tid >> 6, lane = tid & 63;
    if (wv < 2 && lane < 32) {
      const int o = wv * 32, c = lane;
      T* V = V2 + wv * 32 * 33;
      V[c * 33 + c] = rd[o + c];
      for (int r = c + 1; r < 32; ++r) {
        T acc = (T)0;
        for (int k = c; k < r; ++k)
          acc += A[(o + r) * LDA + (o + k)] * V[k * 33 + c];
        V[r * 33 + c] = -acc * rd[o + r];
      }
      for (int r = 0; r < 32; ++r)
        W[(o + r) * LDA + (o + c)] = (r < c) ? (T)0 : V[r * 33 + c];
    }
  }
  __syncthreads();
  // off-diagonal: W10 = -W11 (L10 W00), V2 reused as 33-stride scratch
  gemm32<T, false>(V2, A + 32 * LDA, W, LDA, LDA, 33, tid);
  __syncthreads();
  gemm32_neg<T>(W + 32 * LDA, W + 32 * LDA + 32, V2, LDA, 33, LDA, tid);
  __syncthreads();
}

// ---------------------------------------------------------------- S1: weights
__global__ __launch_bounds__(256) void k_weights(
    const float* __restrict__ Yraw, const float* __restrict__ kern,
    const float* __restrict__ wproj, float* __restrict__ WA,
    float* __restrict__ WB, float* __restrict__ Yt) {
  __shared__ float sk[NTAU * NSUB];
  __shared__ float sp[NSUB * NL];
  const int tid = threadIdx.x;
  if (tid < NTAU * NSUB) sk[tid] = kern[tid];
  if (tid < NSUB * NL)   sp[tid] = wproj[tid];
  __syncthreads();
  const int g = blockIdx.x * 256 + tid;            // g = (m*Tt + t)*Nn + n
  if (g >= Mb * Tt * Nn) return;
  const int n  = g % Nn;
  const int mt = g / Nn;
  const int t  = mt % Tt;
  const int m  = mt / Tt;
  const float* yr = Yraw + ((size_t)m * Nn + n) * NTF + 30 + t;
  float ya[NTAU + 1];
#pragma unroll
  for (int j = 0; j <= NTAU; ++j) ya[j] = yr[j];
  float gs[NSUB];
#pragma unroll
  for (int s = 0; s < NSUB; ++s) {
    float acc = 0.f;
#pragma unroll
    for (int j = 0; j < NTAU; ++j) acc += ya[j] * sk[(NTAU - 1 - j) * NSUB + s];
    gs[s] = (fabsf(acc) < 1e-5f) ? 0.f : acc;      // reference threshold
  }
  float w[NL];
#pragma unroll
  for (int l = 0; l < NL; ++l) {
    float acc = 0.f;
#pragma unroll
    for (int s = 0; s < NSUB; ++s) acc += gs[s] * sp[s * NL + l];
    w[l] = acc;
  }
  float4* wa4 = reinterpret_cast<float4*>(WA + (size_t)g * NL);
  wa4[0] = make_float4(w[0], w[1], w[2], w[3]);
  wa4[1] = make_float4(w[4], w[5], w[6], w[7]);
#pragma unroll
  for (int l = 0; l < NL; ++l)
    WB[(((size_t)m * NL + l) * Tt + t) * Nn + n] = w[l];
  Yt[g] = ya[NTAU];
}

// ---- S2a: M = K[S,S] (pivot order) -> fp64 chol64+trtri64 -> W_S (global) --
__global__ __launch_bounds__(256) void k_scholM(
    const float* __restrict__ K, double* __restrict__ WS64) {
  __shared__ double A[R_ * LDA];
  __shared__ double V2[2 * 32 * 33];
  __shared__ double rd[R_];
  __shared__ double buf[40];
  const int tid = threadIdx.x;
  for (int e = tid; e < R_ * R_; e += 256) {
    const int a = e >> 6, b = e & 63;
    const int pa = (a * 103) % Tt, pb = (b * 103) % Tt;
    A[a * LDA + b] = (double)K[(size_t)pa * Tt + pb];
  }
  __syncthreads();
  chol64_trtri64<double>(A, WS64, rd, V2, buf, tid);
}

// ---- S2b: C[t][k] = sum_{j<=k} W_S[k][j] * K[p_j][t]  (64 WGs, coalesced) --
__global__ __launch_bounds__(320) void k_cmake(
    const float* __restrict__ K, const double* __restrict__ WS64,
    float* __restrict__ Cg) {
  const int k = blockIdx.x;            // 0..63
  __shared__ double wrow[R_];
  const int t = threadIdx.x;
  if (t < R_) wrow[t] = WS64[(size_t)k * LDA + t];
  __syncthreads();
  if (t < Tt) {
    double acc = 0.0;
    for (int j = 0; j <= k; ++j)
      acc += wrow[j] * (double)K[(size_t)((j * 103) % Tt) * Tt + t];
    Cg[(size_t)t * CS + k] = (float)acc;
  }
}

// ---- S2c: zero-pad Cg rows/col ---------------------------------------------
__global__ __launch_bounds__(320) void k_cfix(float* __restrict__ Cg) {
  const int t = threadIdx.x;
  for (int e = t; e < (CROWS - Tt) * CS; e += 320) {
    const int r = Tt + e / CS, c = e - (e / CS) * CS;
    Cg[(size_t)r * CS + c] = 0.f;
  }
  for (int r = t; r < Tt; r += 320) Cg[(size_t)r * CS + R_] = 0.f;
}

// ---- S3a: R = eps I + C^T C (fp64, C in LDS) -> chol64+trtri64 -> W64 ------
__global__ __launch_bounds__(256) void k_qinv(
    const float* __restrict__ Cg, double* __restrict__ W64) {
  __shared__ float  Cf[Tt * CL];       // 79.2 KB
  __shared__ double A[R_ * LDA];       // 33.3 KB
  __shared__ double V2[2 * 32 * 33];   // 16.9 KB
  __shared__ double rd[R_];
  __shared__ double buf[40];
  const int tid = threadIdx.x;
  for (int e = tid; e < Tt * R_; e += 256) {
    const int r = e >> 6, c = e & 63;
    Cf[r * CL + c] = Cg[(size_t)r * CS + c];
  }
  __syncthreads();
  // R lower-half via 4x4 tiles (a >= b), mirror write, +eps on diag
  {
    const int a = tid & 15, b = tid >> 4;
    if (a >= b) {
      const int i0 = a * 4, j0 = b * 4;
      double acc[4][4];
#pragma unroll
      for (int r = 0; r < 4; ++r)
#pragma unroll
        for (int c = 0; c < 4; ++c) acc[r][c] = 0.0;
      for (int t = 0; t < Tt; ++t) {
        float ua[4], vb[4];
#pragma unroll
        for (int q = 0; q < 4; ++q) {
          ua[q] = Cf[t * CL + i0 + q];
          vb[q] = Cf[t * CL + j0 + q];
        }
#pragma unroll
        for (int r = 0; r < 4; ++r)
#pragma unroll
          for (int c = 0; c < 4; ++c) acc[r][c] += (double)ua[r] * (double)vb[c];
      }
#pragma unroll
      for (int r = 0; r < 4; ++r)
#pragma unroll
        for (int c = 0; c < 4; ++c) {
          const int gi = i0 + r, gj = j0 + c;
          const double v = acc[r][c] + ((gi == gj) ? 0.001 : 0.0);
          A[gi * LDA + gj] = v;
          if (a > b) A[gj * LDA + gi] = v;
        }
    }
  }
  __syncthreads();
  chol64_trtri64<double>(A, W64, rd, V2, buf, tid);
}

// --------------- S3b: Q64 = W^T W (fp64, 16 WGs, proven) --------------------
__global__ __launch_bounds__(256) void k_qmul(
    const double* __restrict__ W64, double* __restrict__ Qg) {
  const int e = blockIdx.x * 256 + threadIdx.x;
  if (e >= R_ * R_) return;
  const int i = e >> 6, j = e & 63;
  const int k0 = (i > j) ? i : j;
  double acc = 0.0;
  for (int k = k0; k < R_; ++k) acc += W64[k * LDA + i] * W64[k * LDA + j];
  Qg[e] = acc;
}

// ------------------------------- S4: init (dh0 = 1 + eps, Khat diag ~ 1e-8) -
__global__ __launch_bounds__(256) void k_init(
    float* __restrict__ mu, float* __restrict__ dh) {
  const int g = blockIdx.x * 256 + threadIdx.x;
  if (g >= Mb * Tt * NL) return;
  mu[g] = 0.f;
  dh[g] = 1.0f + EPS;
}

// ---------------------------------------------------------------- I1: lambda
__global__ __launch_bounds__(256) void k_lambda(
    const float* __restrict__ WA, const float* __restrict__ mu,
    const float* __restrict__ dh, const float* __restrict__ biasp,
    float* __restrict__ lam) {
  const int g = blockIdx.x * 256 + threadIdx.x;
  if (g >= Mb * Tt * Nn) return;
  const int mt = g / Nn;
  const float b = biasp[0];
  const float4* wa = reinterpret_cast<const float4*>(WA + (size_t)g * NL);
  const float4* mp = reinterpret_cast<const float4*>(mu + (size_t)mt * NL);
  const float4* dp = reinterpret_cast<const float4*>(dh + (size_t)mt * NL);
  const float4 w0 = wa[0], w1 = wa[1];
  const float4 m0 = mp[0], m1 = mp[1];
  const float4 h0 = dp[0], h1 = dp[1];
  float e = b;
  e += w0.x * (m0.x + 0.5f * w0.x * h0.x);
  e += w0.y * (m0.y + 0.5f * w0.y * h0.y);
  e += w0.z * (m0.z + 0.5f * w0.z * h0.z);
  e += w0.w * (m0.w + 0.5f * w0.w * h0.w);
  e += w1.x * (m1.x + 0.5f * w1.x * h1.x);
  e += w1.y * (m1.y + 0.5f * w1.y * h1.y);
  e += w1.z * (m1.z + 0.5f * w1.z * h1.z);
  e += w1.w * (m1.w + 0.5f * w1.w * h1.w);
  lam[g] = expf(e);
}

// --------------------------------------- I2: g1 = W^T(Y-lam), d = (W^2)^T lam
__global__ __launch_bounds__(320) void k_gd(
    const float* __restrict__ WB, const float* __restrict__ Yt,
    const float* __restrict__ lam, float* __restrict__ g1, float* __restrict__ dvec) {
  const int ml = blockIdx.x;
  const int m = ml / NL;
  const int t = threadIdx.x;
  float ga = 0.f, dd = 0.f;
  if (t < Tt) {
    const float4* wb = reinterpret_cast<const float4*>(WB + ((size_t)ml * Tt + t) * Nn);
    const float4* yt = reinterpret_cast<const float4*>(Yt + ((size_t)m * Tt + t) * Nn);
    const float4* la = reinterpret_cast<const float4*>(lam + ((size_t)m * Tt + t) * Nn);
    for (int q = 0; q < Nn / 4; ++q) {
      const float4 w = wb[q], y = yt[q], v = la[q];
      ga += w.x * (y.x - v.x) + w.y * (y.y - v.y) + w.z * (y.z - v.z) + w.w * (y.w - v.w);
      dd += w.x * w.x * v.x + w.y * w.y * v.y + w.z * w.z * v.z + w.w * w.w * v.w;
    }
  }
  g1[(size_t)ml * TP + t]   = (t < Tt) ? ga : 0.f;
  dvec[(size_t)ml * TP + t] = (t < Tt) ? dd : 0.f;
}

// ------- I3: per-system vectors: s, delta; p = C^T mu; q = Q p; grad; u -----
__global__ __launch_bounds__(320) void k_pre(
    const float* __restrict__ Cg, const double* __restrict__ Qg,
    const float* __restrict__ g1, const float* __restrict__ dvec,
    const float* __restrict__ mug, float* __restrict__ gradb,
    float* __restrict__ svb, float* __restrict__ delb, float* __restrict__ ub) {
  const int ml = blockIdx.x;
  const int mt = ml / NL, lat = ml % NL;
  const int tid = threadIdx.x;                     // 0..319
  __shared__ float Cb[32 * CL];
  __shared__ float muv[TP], gv[TP], sv[TP], sg[TP];
  __shared__ double pv[R_], qv[R_];
  {
    float m_ = 0.f, g_ = 0.f, d_ = 0.f;
    if (tid < Tt) {
      m_ = mug[((size_t)mt * Tt + tid) * NL + lat];
      g_ = g1[(size_t)ml * TP + tid];
      d_ = dvec[(size_t)ml * TP + tid];
    }
    muv[tid] = m_; gv[tid] = g_;
    const float s = 1.f / (1.f + EPS * d_);
    sv[tid] = s;
    svb[(size_t)ml * TP + tid]  = s;
    delb[(size_t)ml * TP + tid] = d_ * s;
  }
  __syncthreads();
  double run_p = 0.0;
  for (int b = 0; b < 10; ++b) {
    for (int e = tid; e < 32 * CS; e += 320) {
      const int r = e / CS, c = e - r * CS;
      Cb[r * CL + c] = Cg[(size_t)(b * 32) * CS + e];
    }
    __syncthreads();
    if (tid < R_)
      for (int rr = 0; rr < 32; ++rr)
        run_p += (double)Cb[rr * CL + tid] * (double)muv[b * 32 + rr];
    __syncthreads();
  }
  if (tid < R_) pv[tid] = run_p;
  __syncthreads();
  if (tid < R_) {
    double acc = 0.0;
    for (int j = 0; j < R_; ++j) acc += Qg[(size_t)j * R_ + tid] * pv[j];
    qv[tid] = acc;
  }
  __syncthreads();
  float run_u = 0.f;
  for (int b = 0; b < 10; ++b) {
    for (int e = tid; e < 32 * CS; e += 320) {
      const int r = e / CS, c = e - r * CS;
      Cb[r * CL + c] = Cg[(size_t)(b * 32) * CS + e];
    }
    __syncthreads();
    if (tid < 32) {
      const int t = b * 32 + tid;
      double cq = 0.0;
      for (int k = 0; k < R_; ++k) cq += (double)Cb[tid * CL + k] * qv[k];
      const double gnew = (double)gv[t] - 1000.0 * ((double)muv[t] - cq);
      gv[t] = (float)gnew;
      sg[t] = sv[t] * gv[t];
    }
    __syncthreads();
    if (tid < R_)
      for (int rr = 0; rr < 32; ++rr)
        run_u += Cb[rr * CL + tid] * sg[b * 32 + rr];
    __syncthreads();
  }
  gradb[(size_t)ml * TP + tid] = gv[tid];
  if (tid < R_) ub[(size_t)ml * R_ + tid] = run_u;
}

// ---- I4: Mhat partial = C^T diag(delta) C over a 160-row t-half ------------
__global__ __launch_bounds__(256) void k_mhat(
    const float* __restrict__ Cg, const float* __restrict__ delb,
    float* __restrict__ Mh2) {
  const int s = blockIdx.x >> 1, th = blockIdx.x & 1;
  const int tid = threadIdx.x;
  __shared__ float Cb[160 * CL];
  __shared__ float dl[160];
  {
    const float* Cs = Cg + (size_t)(th * 160) * CS;
    for (int e = tid; e < 160 * CS; e += 256) {
      const int r = e / CS, c = e - r * CS;
      Cb[r * CL + c] = Cs[e];
    }
    for (int e = tid; e < 160; e += 256)
      dl[e] = delb[(size_t)s * TP + th * 160 + e];
  }
  __syncthreads();
  const int a = tid & 15, b = tid >> 4;
  if (a < b) return;                  // tile covered by mirror (no syncs below)
  const int i0 = a * 4, j0 = b * 4;
  float acc[4][4];
#pragma unroll
  for (int r = 0; r < 4; ++r)
#pragma unroll
    for (int c = 0; c < 4; ++c) acc[r][c] = 0.f;
  for (int t = 0; t < 160; ++t) {
    const float w = dl[t];
    const float2 u0 = *reinterpret_cast<const float2*>(&Cb[t * CL + i0]);
    const float2 u1 = *reinterpret_cast<const float2*>(&Cb[t * CL + i0 + 2]);
    const float2 v0 = *reinterpret_cast<const float2*>(&Cb[t * CL + j0]);
    const float2 v1 = *reinterpret_cast<const float2*>(&Cb[t * CL + j0 + 2]);
    const float ua[4] = {u0.x * w, u0.y * w, u1.x * w, u1.y * w};
    const float vb[4] = {v0.x, v0.y, v1.x, v1.y};
#pragma unroll
    for (int r = 0; r < 4; ++r)
#pragma unroll
      for (int c = 0; c < 4; ++c) acc[r][c] += ua[r] * vb[c];
  }
  float* base = Mh2 + (size_t)blockIdx.x * (R_ * R_);
#pragma unroll
  for (int r = 0; r < 4; ++r)
#pragma unroll
    for (int c = 0; c < 4; ++c)
      base[(i0 + r) * R_ + (j0 + c)] = acc[r][c];
  if (a > b) {
#pragma unroll
    for (int r = 0; r < 4; ++r)
#pragma unroll
      for (int c = 0; c < 4; ++c)
        base[(j0 + c) * R_ + (i0 + r)] = acc[r][c];
  }
}

// ---- I5: Mhat = I + sum halves; chol64 + trtri64; y = W^T(W u) -------------
__global__ __launch_bounds__(256) void k_cholM(
    const float* __restrict__ Mh2, const float* __restrict__ ub,
    float* __restrict__ Wg, float* __restrict__ yb) {
  const int s = blockIdx.x;
  const int tid = threadIdx.x;
  __shared__ float A[R_ * LDA];
  __shared__ float W[R_ * LDA];
  __shared__ float V2[2 * 32 * 33];
  __shared__ float rd[R_];
  __shared__ float buf[40];
  __shared__ float uvs[R_], t1[R_];
  const float* M0 = Mh2 + (size_t)(2 * s) * (R_ * R_);
  const float* M1 = Mh2 + (size_t)(2 * s + 1) * (R_ * R_);
  for (int e = tid; e < R_ * R_; e += 256) {
    const int i = e >> 6, j = e & 63;
    A[i * LDA + j] = M0[e] + M1[e] + ((i == j) ? 1.f : 0.f);
  }
  for (int e = tid; e < R_ * LDA; e += 256) W[e] = 0.f;
  if (tid < R_) uvs[tid] = ub[(size_t)s * R_ + tid];
  __syncthreads();
  chol64_trtri64<float>(A, W, rd, V2, buf, tid);
  if (tid < R_) {
    float acc = 0.f;
    for (int j = 0; j <= tid; ++j) acc += W[tid * LDA + j] * uvs[j];
    t1[tid] = acc;
  }
  __syncthreads();
  if (tid < R_) {
    float acc = 0.f;
    for (int i = tid; i < R_; ++i) acc += W[i * LDA + tid] * t1[i];
    yb[(size_t)s * R_ + tid] = acc;
  }
  float* Wo = Wg + (size_t)s * R_ * LDA;
  for (int e = tid; e < R_ * LDA; e += 256) Wo[e] = W[e];
}

// ---- I6: X = C W^T (6x4 tiles, triangular kmax) -> jsq -> dh, mu update ----
// 512 WGs = (system, t-block of 96).
__global__ __launch_bounds__(256) void k_fin(
    const float* __restrict__ Cg, const float* __restrict__ Wg,
    const float* __restrict__ yb, const float* __restrict__ gradb,
    const float* __restrict__ svb, float* __restrict__ mug,
    float* __restrict__ dhg) {
  const int bid = blockIdx.x;
  const int ml = bid >> 2, blk = bid & 3;
  const int mt = ml / NL, lat = ml % NL;
  const int tid = threadIdx.x;
  __shared__ float Wf[R_ * CL];       // 64 x 66
  __shared__ float Cb[96 * CL];       // 96 x 66
  {
    const float* Ws = Wg + (size_t)ml * R_ * LDA;
    for (int e = tid; e < R_ * LDA; e += 256) {
      const int r = e / LDA, c = e - r * LDA;
      Wf[r * CL + c] = Ws[e];
    }
    const float* Cs = Cg + (size_t)(blk * 96) * CS;
    for (int e = tid; e < 96 * CS; e += 256) {
      const int r = e / CS, c = e - r * CS;
      Cb[r * CL + c] = Cs[e];
    }
  }
  __syncthreads();
  const int tg = tid & 15, jg = tid >> 4;
  const int t0 = tg * 6, j0 = jg * 4;
  float acc[6][4];
#pragma unroll
  for (int r = 0; r < 6; ++r)
#pragma unroll
    for (int c = 0; c < 4; ++c) acc[r][c] = 0.f;
  const int kmax = j0 + 4;            // W rows j0..j0+3 have zeros for k > row
  for (int k = 0; k < kmax; k += 2) {
    float2 cv[6], wv[4];
#pragma unroll
    for (int r = 0; r < 6; ++r)
      cv[r] = *reinterpret_cast<const float2*>(&Cb[(t0 + r) * CL + k]);
#pragma unroll
    for (int c = 0; c < 4; ++c)
      wv[c] = *reinterpret_cast<const float2*>(&Wf[(j0 + c) * CL + k]);
#pragma unroll
    for (int r = 0; r < 6; ++r)
#pragma unroll
      for (int c = 0; c < 4; ++c)
        acc[r][c] += cv[r].x * wv[c].x + cv[r].y * wv[c].y;
  }
  float jp[6];
#pragma unroll
  for (int r = 0; r < 6; ++r) {
    float s = 0.f;
#pragma unroll
    for (int c = 0; c < 4; ++c) s += acc[r][c] * acc[r][c];
    jp[r] = s;
  }
  __syncthreads();
  float* red = Wf;                    // reuse: 96*17 = 1632 <= 64*66
  float* yv  = Wf + 96 * 17;
#pragma unroll
  for (int r = 0; r < 6; ++r) red[(t0 + r) * 17 + jg] = jp[r];
  if (tid < R_) yv[tid] = yb[(size_t)ml * R_ + tid];
  __syncthreads();
  if (tid < 96) {
    const int t = blk * 96 + tid;
    float S = 0.f;
#pragma unroll
    for (int q = 0; q < 16; ++q) S += red[tid * 17 + q];
    float cy = 0.f;
    for (int k = 0; k < R_; ++k) cy += Cb[tid * CL + k] * yv[k];
    if (t < Tt) {
      const float s = svb[(size_t)ml * TP + t];
      const float g = gradb[(size_t)ml * TP + t];
      const size_t idx = ((size_t)mt * Tt + t) * NL + lat;
      const float x = EPS * s * g + s * cy;
      mug[idx] = mug[idx] + 0.5f * x;               // LR = 0.5
      dhg[idx] = -(EPS * s + s * s * S);
    }
  }
}

// ---------------------------------------------------------------- F1: output
__global__ __launch_bounds__(256) void k_out(
    const float* __restrict__ mu, float* __restrict__ out) {
  const int g = blockIdx.x * 256 + threadIdx.x;   // g = (m*NL + l)*Tt + t
  if (g >= Mb * NL * Tt) return;
  const int t = g % Tt;
  const int ml = g / Tt;
  const int m = ml / NL, l = ml % NL;
  out[g] = mu[((size_t)m * Tt + t) * NL + l];
}

// ------------------------------------------------------------------- launcher
extern "C" void kernel_launch(void* const* d_in, const int* in_sizes, int n_in,
                              void* d_out, int out_size, void* d_ws, size_t ws_size,
                              hipStream_t stream) {
  (void)in_sizes; (void)n_in; (void)out_size;
  const float* Yraw  = (const float*)d_in[0];
  const float* kern  = (const float*)d_in[1];
  const float* wproj = (const float*)d_in[2];
  const float* K     = (const float*)d_in[3];
  const float* biasp = (const float*)d_in[4];
  float* out = (float*)d_out;

  char* base = (char*)d_ws;
  size_t off = 0;
  auto alloc = [&](size_t bytes) -> void* {
    void* p = base + off;
    off += (bytes + 511) & ~(size_t)511;
    return p;
  };
  float*  WA    = (float*) alloc((size_t)Mb * Tt * Nn * NL * 4);
  float*  WB    = (float*) alloc((size_t)Mb * Tt * Nn * NL * 4);
  float*  Yt    = (float*) alloc((size_t)Mb * Tt * Nn * 4);
  float*  lam   = (float*) alloc((size_t)Mb * Tt * Nn * 4);
  float*  mu    = (float*) alloc((size_t)Mb * Tt * NL * 4);
  float*  dh    = (float*) alloc((size_t)Mb * Tt * NL * 4);
  float*  g1    = (float*) alloc((size_t)ML * TP * 4);
  float*  dvec  = (float*) alloc((size_t)ML * TP * 4);
  float*  gradb = (float*) alloc((size_t)ML * TP * 4);
  float*  svb   = (float*) alloc((size_t)ML * TP * 4);
  float*  delb  = (float*) alloc((size_t)ML * TP * 4);
  float*  ub    = (float*) alloc((size_t)ML * R_ * 4);
  float*  yb    = (float*) alloc((size_t)ML * R_ * 4);
  float*  Cg    = (float*) alloc((size_t)CROWS * CS * 4);
  double* WS64  = (double*)alloc((size_t)R_ * LDA * 8);
  double* W64   = (double*)alloc((size_t)R_ * LDA * 8);
  double* Q64   = (double*)alloc((size_t)R_ * R_ * 8);
  float*  Mh2   = (float*) alloc((size_t)ML * 2 * R_ * R_ * 4);
  float*  Wg    = (float*) alloc((size_t)ML * R_ * LDA * 4);
  if (off > ws_size) return;

  const int gMTN = (Mb * Tt * Nn) / 256;       // 1800
  const int gMTL = (Mb * Tt * NL + 255) / 256; // 150
  const int gRR  = (R_ * R_ + 255) / 256;      // 16

  k_weights<<<gMTN, 256, 0, stream>>>(Yraw, kern, wproj, WA, WB, Yt);
  k_scholM<<<1, 256, 0, stream>>>(K, WS64);
  k_cmake<<<R_, 320, 0, stream>>>(K, WS64, Cg);
  k_cfix<<<1, 320, 0, stream>>>(Cg);
  k_qinv<<<1, 256, 0, stream>>>(Cg, W64);
  k_qmul<<<gRR, 256, 0, stream>>>(W64, Q64);
  k_init<<<gMTL, 256, 0, stream>>>(mu, dh);

  for (int it = 0; it < 5; ++it) {
    k_lambda<<<gMTN, 256, 0, stream>>>(WA, mu, dh, biasp, lam);
    k_gd<<<ML, 320, 0, stream>>>(WB, Yt, lam, g1, dvec);
    k_pre<<<ML, 320, 0, stream>>>(Cg, Q64, g1, dvec, mu, gradb, svb, delb, ub);
    k_mhat<<<ML * 2, 256, 0, stream>>>(Cg, delb, Mh2);
    k_cholM<<<ML, 256, 0, stream>>>(Mh2, ub, Wg, yb);
    k_fin<<<ML * 4, 256, 0, stream>>>(Cg, Wg, yb, gradb, svb, mu, dh);
  }
  k_out<<<gMTL, 256, 0, stream>>>(mu, out);
}

// Round 12
// 893.312 us; speedup vs baseline: 1.8790x; 1.0058x over previous
//
// FCGPFA variational iteration for MI355X (gfx950). Round 12: round-11 (898us)
// with (a) k_qinv split: parallel k_rmul (16 WGs, R=eps I+C^T C) + 1-WG
// chol-only k_qchol -- kills the 122us serial fp64 R-build; (b) k_gd+k_pre
// fused into k_gdpre (same 128-WG x 320-thread shape, outputs stay in LDS,
// zero redundant work -- unlike r8's failed k_lgd); (c) k_cfix merged into
// k_cmake (grid 65). All other kernels byte-identical to round 11.
//
#include <hip/hip_runtime.h>
#include <math.h>

namespace {
constexpr int Mb   = 16;
constexpr int Nn   = 96;
constexpr int NTF  = 350;
constexpr int Tt   = 300;
constexpr int NSUB = 8;
constexpr int NTAU = 20;
constexpr int NL   = 8;
constexpr int ML   = Mb * NL;   // 128 systems
constexpr int R_   = 64;        // low-rank dimension (2 x 32)
constexpr int CS   = 65;        // C global row stride
constexpr int CL   = 66;        // C LDS row stride (even -> float2 ok)
constexpr int LDA  = 65;        // A/W row stride
constexpr int TP   = 320;
constexpr int CROWS= 384;       // C rows padded for 4 x 96 t-blocks
constexpr float EPS = 0.001f;
}

__device__ __forceinline__ float  sqrt_(float x)  { return sqrtf(x); }
__device__ __forceinline__ double sqrt_(double x) { return sqrt(x); }

__device__ __forceinline__ void lfence() {
  asm volatile("s_waitcnt lgkmcnt(0)" ::: "memory");
}

// ---------------- 32x32 GEMM helpers on 256 threads (proven r5-r11) ---------
template <typename T, bool ACC>
__device__ __forceinline__ void gemm32(T* __restrict__ D, const T* __restrict__ A,
                                       const T* __restrict__ B, int lda, int ldb,
                                       int ldd, int tid) {
  const int r = tid & 31, c0 = (tid >> 5) * 4;
  T a0 = ACC ? D[r * ldd + c0 + 0] : (T)0;
  T a1 = ACC ? D[r * ldd + c0 + 1] : (T)0;
  T a2 = ACC ? D[r * ldd + c0 + 2] : (T)0;
  T a3 = ACC ? D[r * ldd + c0 + 3] : (T)0;
  for (int k = 0; k < 32; ++k) {
    const T a = A[r * lda + k];
    a0 += a * B[k * ldb + c0 + 0];
    a1 += a * B[k * ldb + c0 + 1];
    a2 += a * B[k * ldb + c0 + 2];
    a3 += a * B[k * ldb + c0 + 3];
  }
  D[r * ldd + c0 + 0] = a0; D[r * ldd + c0 + 1] = a1;
  D[r * ldd + c0 + 2] = a2; D[r * ldd + c0 + 3] = a3;
}

template <typename T>
__device__ __forceinline__ void gemm32_neg(T* __restrict__ D, const T* __restrict__ A,
                                           const T* __restrict__ B, int lda, int ldb,
                                           int ldd, int tid) {
  const int r = tid & 31, c0 = (tid >> 5) * 4;
  T a0 = (T)0, a1 = (T)0, a2 = (T)0, a3 = (T)0;
  for (int k = 0; k < 32; ++k) {
    const T a = A[r * lda + k];
    a0 += a * B[k * ldb + c0 + 0];
    a1 += a * B[k * ldb + c0 + 1];
    a2 += a * B[k * ldb + c0 + 2];
    a3 += a * B[k * ldb + c0 + 3];
  }
  D[r * ldd + c0 + 0] = -a0; D[r * ldd + c0 + 1] = -a1;
  D[r * ldd + c0 + 2] = -a2; D[r * ldd + c0 + 3] = -a3;
}

// ------------- 64x64 Cholesky (lower) + W = L^-1, 256 threads ---------------
// Left-looking register mini-chol, ONE lfence/column (HW-verified r10/r11).
template <typename T>
__device__ void chol64_trtri64(T* __restrict__ A, T* __restrict__ W,
                               T* __restrict__ rd, T* __restrict__ V2,
                               T* __restrict__ buf, int tid) {
  for (int pb = 0; pb < 2; ++pb) {
    const int o = pb * 32;
    if (tid < 64) {
      const int r = tid;               // lanes 32..63: dummies
      T v[32];
      if (r < 32) {
#pragma unroll
        for (int k = 0; k < 32; ++k) v[k] = A[(o + r) * LDA + (o + k)];
      } else {
#pragma unroll
        for (int k = 0; k < 32; ++k) v[k] = (T)0;
      }
      T myis = (T)0;
#pragma unroll
      for (int c = 0; c < 32; ++c) {
        if (r == c) {                  // broadcast finalized row c (+ raw pivot)
#pragma unroll
          for (int k = 0; k <= c; ++k) buf[k] = v[k];
        }
        lfence();
        T dotp = (T)0, dotv = (T)0;
#pragma unroll
        for (int k = 0; k < c; ++k) {
          const T b = buf[k];
          dotp += b * b;
          dotv += v[k] * b;
        }
        const T psq = buf[c] - dotp;   // all lanes compute pivot redundantly
        T s, is;
        if (psq > (T)1e-12) { s = sqrt_(psq); is = (T)1 / s; }
        else                { s = (T)0;       is = (T)0; }
        if (r == c)                 { v[c] = s; myis = is; }
        else if (r > c && r < 32)   v[c] = (v[c] - dotv) * is;
      }
      if (r < 32) {
#pragma unroll
        for (int k = 0; k < 32; ++k) if (k <= r) A[(o + r) * LDA + (o + k)] = v[k];
        rd[o + r] = myis;
      }
    }
    __syncthreads();
    if (pb == 0) {
      // panel solve rows 32..63
      if (tid < 32) {
        const int i = 32 + tid;
        T v[32];
#pragma unroll
        for (int c = 0; c < 32; ++c) v[c] = A[i * LDA + c];
#pragma unroll
        for (int c = 0; c < 32; ++c) {
          T acc = v[c];
          for (int k = 0; k < c; ++k) acc -= v[k] * A[c * LDA + k];
          v[c] = acc * rd[c];
        }
#pragma unroll
        for (int c = 0; c < 32; ++c) A[i * LDA + c] = v[c];
      }
      __syncthreads();
      // trailing update (32..63)^2 lower, 36 4x4 tiles
      for (int tix = tid; tix < 36; tix += 256) {
        int ti = (int)((sqrtf(8.f * (float)tix + 1.f) - 1.f) * 0.5f);
        while ((ti + 1) * (ti + 2) / 2 <= tix) ++ti;
        while (ti * (ti + 1) / 2 > tix) --ti;
        const int tj = tix - ti * (ti + 1) / 2;
        const int gi = 32 + ti * 4, gj = 32 + tj * 4;
        T acc[4][4];
#pragma unroll
        for (int r = 0; r < 4; ++r)
#pragma unroll
          for (int c = 0; c < 4; ++c) acc[r][c] = (T)0;
        for (int k = 0; k < 32; ++k) {
          T a[4], b[4];
#pragma unroll
          for (int r = 0; r < 4; ++r) a[r] = A[(gi + r) * LDA + k];
#pragma unroll
          for (int c = 0; c < 4; ++c) b[c] = A[(gj + c) * LDA + k];
#pragma unroll
          for (int r = 0; r < 4; ++r)
#pragma unroll
            for (int c = 0; c < 4; ++c) acc[r][c] += a[r] * b[c];
        }
#pragma unroll
        for (int r = 0; r < 4; ++r)
#pragma unroll
          for (int c = 0; c < 4; ++c)
            A[(gi + r) * LDA + (gj + c)] -= acc[r][c];
      }
      __syncthreads();
    }
  }
  // diag-block inverses: 2 waves, lane = column (in-order DS pipe; proven)
  {
    const int wv = tid >> 6, lane = tid & 63;
    if (wv < 2 && lane < 32) {
      const int o = wv * 32, c = lane;
      T* V = V2 + wv * 32 * 33;
      V[c * 33 + c] = rd[o + c];
      for (int r = c + 1; r < 32; ++r) {
        T acc = (T)0;
        for (int k = c; k < r; ++k)
          acc += A[(o + r) * LDA + (o + k)] * V[k * 33 + c];
        V[r * 33 + c] = -acc * rd[o + r];
      }
      for (int r = 0; r < 32; ++r)
        W[(o + r) * LDA + (o + c)] = (r < c) ? (T)0 : V[r * 33 + c];
    }
  }
  __syncthreads();
  // off-diagonal: W10 = -W11 (L10 W00), V2 reused as 33-stride scratch
  gemm32<T, false>(V2, A + 32 * LDA, W, LDA, LDA, 33, tid);
  __syncthreads();
  gemm32_neg<T>(W + 32 * LDA, W + 32 * LDA + 32, V2, LDA, 33, LDA, tid);
  __syncthreads();
}

// ---------------------------------------------------------------- S1: weights
__global__ __launch_bounds__(256) void k_weights(
    const float* __restrict__ Yraw, const float* __restrict__ kern,
    const float* __restrict__ wproj, float* __restrict__ WA,
    float* __restrict__ WB, float* __restrict__ Yt) {
  __shared__ float sk[NTAU * NSUB];
  __shared__ float sp[NSUB * NL];
  const int tid = threadIdx.x;
  if (tid < NTAU * NSUB) sk[tid] = kern[tid];
  if (tid < NSUB * NL)   sp[tid] = wproj[tid];
  __syncthreads();
  const int g = blockIdx.x * 256 + tid;            // g = (m*Tt + t)*Nn + n
  if (g >= Mb * Tt * Nn) return;
  const int n  = g % Nn;
  const int mt = g / Nn;
  const int t  = mt % Tt;
  const int m  = mt / Tt;
  const float* yr = Yraw + ((size_t)m * Nn + n) * NTF + 30 + t;
  float ya[NTAU + 1];
#pragma unroll
  for (int j = 0; j <= NTAU; ++j) ya[j] = yr[j];
  float gs[NSUB];
#pragma unroll
  for (int s = 0; s < NSUB; ++s) {
    float acc = 0.f;
#pragma unroll
    for (int j = 0; j < NTAU; ++j) acc += ya[j] * sk[(NTAU - 1 - j) * NSUB + s];
    gs[s] = (fabsf(acc) < 1e-5f) ? 0.f : acc;      // reference threshold
  }
  float w[NL];
#pragma unroll
  for (int l = 0; l < NL; ++l) {
    float acc = 0.f;
#pragma unroll
    for (int s = 0; s < NSUB; ++s) acc += gs[s] * sp[s * NL + l];
    w[l] = acc;
  }
  float4* wa4 = reinterpret_cast<float4*>(WA + (size_t)g * NL);
  wa4[0] = make_float4(w[0], w[1], w[2], w[3]);
  wa4[1] = make_float4(w[4], w[5], w[6], w[7]);
#pragma unroll
  for (int l = 0; l < NL; ++l)
    WB[(((size_t)m * NL + l) * Tt + t) * Nn + n] = w[l];
  Yt[g] = ya[NTAU];
}

// ---- S2a: M = K[S,S] (pivot order) -> fp64 chol64+trtri64 -> W_S (global) --
__global__ __launch_bounds__(256) void k_scholM(
    const float* __restrict__ K, double* __restrict__ WS64) {
  __shared__ double A[R_ * LDA];
  __shared__ double V2[2 * 32 * 33];
  __shared__ double rd[R_];
  __shared__ double buf[40];
  const int tid = threadIdx.x;
  for (int e = tid; e < R_ * R_; e += 256) {
    const int a = e >> 6, b = e & 63;
    const int pa = (a * 103) % Tt, pb = (b * 103) % Tt;
    A[a * LDA + b] = (double)K[(size_t)pa * Tt + pb];
  }
  __syncthreads();
  chol64_trtri64<double>(A, WS64, rd, V2, buf, tid);
}

// ---- S2b: C[t][k] = sum_{j<=k} W_S[k][j]*K[p_j][t]; k==R_ WG zeroes pad col
__global__ __launch_bounds__(320) void k_cmake(
    const float* __restrict__ K, const double* __restrict__ WS64,
    float* __restrict__ Cg) {
  const int k = blockIdx.x;            // 0..64
  const int t = threadIdx.x;
  if (k == R_) {                       // zero the pad column for all rows
    for (int r = t; r < CROWS; r += 320) Cg[(size_t)r * CS + R_] = 0.f;
    return;
  }
  __shared__ double wrow[R_];
  if (t < R_) wrow[t] = WS64[(size_t)k * LDA + t];
  __syncthreads();
  if (t < Tt) {
    double acc = 0.0;
    for (int j = 0; j <= k; ++j)
      acc += wrow[j] * (double)K[(size_t)((j * 103) % Tt) * Tt + t];
    Cg[(size_t)t * CS + k] = (float)acc;
  }
  // zero this column's pad rows
  for (int r = Tt + t; r < CROWS; r += 320) Cg[(size_t)r * CS + k] = 0.f;
}

// ---------------- S3a: R64 = eps*I + C^T C (fp64, 16 WGs; proven r9) --------
__global__ __launch_bounds__(256) void k_rmul(
    const float* __restrict__ Cg, double* __restrict__ R64) {
  const int e = blockIdx.x * 256 + threadIdx.x;
  if (e >= R_ * R_) return;
  const int i = e >> 6, j = e & 63;
  double acc = (i == j) ? 0.001 : 0.0;
  for (int r = 0; r < Tt; ++r)
    acc += (double)Cg[(size_t)r * CS + i] * (double)Cg[(size_t)r * CS + j];
  R64[e] = acc;
}

// --------------- S3b: chol64+trtri64 of R (fp64), W -> global ---------------
__global__ __launch_bounds__(256) void k_qchol(
    const double* __restrict__ R64, double* __restrict__ W64) {
  __shared__ double A[R_ * LDA];       // 33.3 KB
  __shared__ double V2[2 * 32 * 33];   // 16.9 KB
  __shared__ double rd[R_];
  __shared__ double buf[40];
  const int tid = threadIdx.x;
  for (int e = tid; e < R_ * R_; e += 256) {
    const int i = e >> 6, j = e & 63;
    A[i * LDA + j] = R64[e];
  }
  __syncthreads();
  chol64_trtri64<double>(A, W64, rd, V2, buf, tid);
}

// --------------- S3c: Q64 = W^T W (fp64, 16 WGs, proven) --------------------
__global__ __launch_bounds__(256) void k_qmul(
    const double* __restrict__ W64, double* __restrict__ Qg) {
  const int e = blockIdx.x * 256 + threadIdx.x;
  if (e >= R_ * R_) return;
  const int i = e >> 6, j = e & 63;
  const int k0 = (i > j) ? i : j;
  double acc = 0.0;
  for (int k = k0; k < R_; ++k) acc += W64[k * LDA + i] * W64[k * LDA + j];
  Qg[e] = acc;
}

// ------------------------------- S4: init (dh0 = 1 + eps, Khat diag ~ 1e-8) -
__global__ __launch_bounds__(256) void k_init(
    float* __restrict__ mu, float* __restrict__ dh) {
  const int g = blockIdx.x * 256 + threadIdx.x;
  if (g >= Mb * Tt * NL) return;
  mu[g] = 0.f;
  dh[g] = 1.0f + EPS;
}

// ---------------------------------------------------------------- I1: lambda
__global__ __launch_bounds__(256) void k_lambda(
    const float* __restrict__ WA, const float* __restrict__ mu,
    const float* __restrict__ dh, const float* __restrict__ biasp,
    float* __restrict__ lam) {
  const int g = blockIdx.x * 256 + threadIdx.x;
  if (g >= Mb * Tt * Nn) return;
  const int mt = g / Nn;
  const float b = biasp[0];
  const float4* wa = reinterpret_cast<const float4*>(WA + (size_t)g * NL);
  const float4* mp = reinterpret_cast<const float4*>(mu + (size_t)mt * NL);
  const float4* dp = reinterpret_cast<const float4*>(dh + (size_t)mt * NL);
  const float4 w0 = wa[0], w1 = wa[1];
  const float4 m0 = mp[0], m1 = mp[1];
  const float4 h0 = dp[0], h1 = dp[1];
  float e = b;
  e += w0.x * (m0.x + 0.5f * w0.x * h0.x);
  e += w0.y * (m0.y + 0.5f * w0.y * h0.y);
  e += w0.z * (m0.z + 0.5f * w0.z * h0.z);
  e += w0.w * (m0.w + 0.5f * w0.w * h0.w);
  e += w1.x * (m1.x + 0.5f * w1.x * h1.x);
  e += w1.y * (m1.y + 0.5f * w1.y * h1.y);
  e += w1.z * (m1.z + 0.5f * w1.z * h1.z);
  e += w1.w * (m1.w + 0.5f * w1.w * h1.w);
  lam[g] = expf(e);
}

// ---- I2: fused gd + pre: g1/d in LDS -> s, delta; p; q; grad; u ------------
__global__ __launch_bounds__(320) void k_gdpre(
    const float* __restrict__ WB, const float* __restrict__ Yt,
    const float* __restrict__ lam, const float* __restrict__ Cg,
    const double* __restrict__ Qg, const float* __restrict__ mug,
    float* __restrict__ gradb, float* __restrict__ svb,
    float* __restrict__ delb, float* __restrict__ ub) {
  const int ml = blockIdx.x;
  const int m = ml / NL, lat = ml % NL;
  const int tid = threadIdx.x;                     // 0..319
  __shared__ float Cb[32 * CL];
  __shared__ float muv[TP], gv[TP], sv[TP], sg[TP];
  __shared__ double pv[R_], qv[R_];
  // Phase A (= k_gd): ga, dd from WB/Yt/lam; then s, delta (all in LDS)
  {
    float ga = 0.f, dd = 0.f, m_ = 0.f;
    if (tid < Tt) {
      m_ = mug[((size_t)m * Tt + tid) * NL + lat];
      const float4* wb = reinterpret_cast<const float4*>(WB + ((size_t)ml * Tt + tid) * Nn);
      const float4* yt = reinterpret_cast<const float4*>(Yt + ((size_t)m * Tt + tid) * Nn);
      const float4* la = reinterpret_cast<const float4*>(lam + ((size_t)m * Tt + tid) * Nn);
      for (int q = 0; q < Nn / 4; ++q) {
        const float4 w = wb[q], y = yt[q], v = la[q];
        ga += w.x * (y.x - v.x) + w.y * (y.y - v.y) + w.z * (y.z - v.z) + w.w * (y.w - v.w);
        dd += w.x * w.x * v.x + w.y * w.y * v.y + w.z * w.z * v.z + w.w * w.w * v.w;
      }
    }
    muv[tid] = m_;
    gv[tid] = (tid < Tt) ? ga : 0.f;
    const float d_ = (tid < Tt) ? dd : 0.f;
    const float s = 1.f / (1.f + EPS * d_);
    sv[tid] = s;
    svb[(size_t)ml * TP + tid]  = s;
    delb[(size_t)ml * TP + tid] = d_ * s;
  }
  __syncthreads();
  // Phase B: p = C^T mu (fp64, staged 32-row blocks; proven r9/r11 pattern)
  double run_p = 0.0;
  for (int b = 0; b < 10; ++b) {
    for (int e = tid; e < 32 * CS; e += 320) {
      const int r = e / CS, c = e - r * CS;
      Cb[r * CL + c] = Cg[(size_t)(b * 32) * CS + e];
    }
    __syncthreads();
    if (tid < R_)
      for (int rr = 0; rr < 32; ++rr)
        run_p += (double)Cb[rr * CL + tid] * (double)muv[b * 32 + rr];
    __syncthreads();
  }
  if (tid < R_) pv[tid] = run_p;
  __syncthreads();
  // Phase C: q = Q p (fp64)
  if (tid < R_) {
    double acc = 0.0;
    for (int j = 0; j < R_; ++j) acc += Qg[(size_t)j * R_ + tid] * pv[j];
    qv[tid] = acc;
  }
  __syncthreads();
  // Phase D: grad = g1 - 1000*(mu - C q) [fp64 inner]; u = C^T (s*grad)
  float run_u = 0.f;
  for (int b = 0; b < 10; ++b) {
    for (int e = tid; e < 32 * CS; e += 320) {
      const int r = e / CS, c = e - r * CS;
      Cb[r * CL + c] = Cg[(size_t)(b * 32) * CS + e];
    }
    __syncthreads();
    if (tid < 32) {
      const int t = b * 32 + tid;
      double cq = 0.0;
      for (int k = 0; k < R_; ++k) cq += (double)Cb[tid * CL + k] * qv[k];
      const double gnew = (double)gv[t] - 1000.0 * ((double)muv[t] - cq);
      gv[t] = (float)gnew;
      sg[t] = sv[t] * gv[t];
    }
    __syncthreads();
    if (tid < R_)
      for (int rr = 0; rr < 32; ++rr)
        run_u += Cb[rr * CL + tid] * sg[b * 32 + rr];
    __syncthreads();
  }
  gradb[(size_t)ml * TP + tid] = gv[tid];
  if (tid < R_) ub[(size_t)ml * R_ + tid] = run_u;
}

// ---- I3: Mhat partial = C^T diag(delta) C over a 160-row t-half ------------
__global__ __launch_bounds__(256) void k_mhat(
    const float* __restrict__ Cg, const float* __restrict__ delb,
    float* __restrict__ Mh2) {
  const int s = blockIdx.x >> 1, th = blockIdx.x & 1;
  const int tid = threadIdx.x;
  __shared__ float Cb[160 * CL];
  __shared__ float dl[160];
  {
    const float* Cs = Cg + (size_t)(th * 160) * CS;
    for (int e = tid; e < 160 * CS; e += 256) {
      const int r = e / CS, c = e - r * CS;
      Cb[r * CL + c] = Cs[e];
    }
    for (int e = tid; e < 160; e += 256)
      dl[e] = delb[(size_t)s * TP + th * 160 + e];
  }
  __syncthreads();
  const int a = tid & 15, b = tid >> 4;
  if (a < b) return;                  // tile covered by mirror (no syncs below)
  const int i0 = a * 4, j0 = b * 4;
  float acc[4][4];
#pragma unroll
  for (int r = 0; r < 4; ++r)
#pragma unroll
    for (int c = 0; c < 4; ++c) acc[r][c] = 0.f;
  for (int t = 0; t < 160; ++t) {
    const float w = dl[t];
    const float2 u0 = *reinterpret_cast<const float2*>(&Cb[t * CL + i0]);
    const float2 u1 = *reinterpret_cast<const float2*>(&Cb[t * CL + i0 + 2]);
    const float2 v0 = *reinterpret_cast<const float2*>(&Cb[t * CL + j0]);
    const float2 v1 = *reinterpret_cast<const float2*>(&Cb[t * CL + j0 + 2]);
    const float ua[4] = {u0.x * w, u0.y * w, u1.x * w, u1.y * w};
    const float vb[4] = {v0.x, v0.y, v1.x, v1.y};
#pragma unroll
    for (int r = 0; r < 4; ++r)
#pragma unroll
      for (int c = 0; c < 4; ++c) acc[r][c] += ua[r] * vb[c];
  }
  float* base = Mh2 + (size_t)blockIdx.x * (R_ * R_);
#pragma unroll
  for (int r = 0; r < 4; ++r)
#pragma unroll
    for (int c = 0; c < 4; ++c)
      base[(i0 + r) * R_ + (j0 + c)] = acc[r][c];
  if (a > b) {
#pragma unroll
    for (int r = 0; r < 4; ++r)
#pragma unroll
      for (int c = 0; c < 4; ++c)
        base[(j0 + c) * R_ + (i0 + r)] = acc[r][c];
  }
}

// ---- I4: Mhat = I + sum halves; chol64 + trtri64; y = W^T(W u) -------------
__global__ __launch_bounds__(256) void k_cholM(
    const float* __restrict__ Mh2, const float* __restrict__ ub,
    float* __restrict__ Wg, float* __restrict__ yb) {
  const int s = blockIdx.x;
  const int tid = threadIdx.x;
  __shared__ float A[R_ * LDA];
  __shared__ float W[R_ * LDA];
  __shared__ float V2[2 * 32 * 33];
  __shared__ float rd[R_];
  __shared__ float buf[40];
  __shared__ float uvs[R_], t1[R_];
  const float* M0 = Mh2 + (size_t)(2 * s) * (R_ * R_);
  const float* M1 = Mh2 + (size_t)(2 * s + 1) * (R_ * R_);
  for (int e = tid; e < R_ * R_; e += 256) {
    const int i = e >> 6, j = e & 63;
    A[i * LDA + j] = M0[e] + M1[e] + ((i == j) ? 1.f : 0.f);
  }
  for (int e = tid; e < R_ * LDA; e += 256) W[e] = 0.f;
  if (tid < R_) uvs[tid] = ub[(size_t)s * R_ + tid];
  __syncthreads();
  chol64_trtri64<float>(A, W, rd, V2, buf, tid);
  if (tid < R_) {
    float acc = 0.f;
    for (int j = 0; j <= tid; ++j) acc += W[tid * LDA + j] * uvs[j];
    t1[tid] = acc;
  }
  __syncthreads();
  if (tid < R_) {
    float acc = 0.f;
    for (int i = tid; i < R_; ++i) acc += W[i * LDA + tid] * t1[i];
    yb[(size_t)s * R_ + tid] = acc;
  }
  float* Wo = Wg + (size_t)s * R_ * LDA;
  for (int e = tid; e < R_ * LDA; e += 256) Wo[e] = W[e];
}

// ---- I5: X = C W^T (6x4 tiles, triangular kmax) -> jsq -> dh, mu update ----
// 512 WGs = (system, t-block of 96).
__global__ __launch_bounds__(256) void k_fin(
    const float* __restrict__ Cg, const float* __restrict__ Wg,
    const float* __restrict__ yb, const float* __restrict__ gradb,
    const float* __restrict__ svb, float* __restrict__ mug,
    float* __restrict__ dhg) {
  const int bid = blockIdx.x;
  const int ml = bid >> 2, blk = bid & 3;
  const int mt = ml / NL, lat = ml % NL;
  const int tid = threadIdx.x;
  __shared__ float Wf[R_ * CL];       // 64 x 66
  __shared__ float Cb[96 * CL];       // 96 x 66
  {
    const float* Ws = Wg + (size_t)ml * R_ * LDA;
    for (int e = tid; e < R_ * LDA; e += 256) {
      const int r = e / LDA, c = e - r * LDA;
      Wf[r * CL + c] = Ws[e];
    }
    const float* Cs = Cg + (size_t)(blk * 96) * CS;
    for (int e = tid; e < 96 * CS; e += 256) {
      const int r = e / CS, c = e - r * CS;
      Cb[r * CL + c] = Cs[e];
    }
  }
  __syncthreads();
  const int tg = tid & 15, jg = tid >> 4;
  const int t0 = tg * 6, j0 = jg * 4;
  float acc[6][4];
#pragma unroll
  for (int r = 0; r < 6; ++r)
#pragma unroll
    for (int c = 0; c < 4; ++c) acc[r][c] = 0.f;
  const int kmax = j0 + 4;            // W rows j0..j0+3 have zeros for k > row
  for (int k = 0; k < kmax; k += 2) {
    float2 cv[6], wv[4];
#pragma unroll
    for (int r = 0; r < 6; ++r)
      cv[r] = *reinterpret_cast<const float2*>(&Cb[(t0 + r) * CL + k]);
#pragma unroll
    for (int c = 0; c < 4; ++c)
      wv[c] = *reinterpret_cast<const float2*>(&Wf[(j0 + c) * CL + k]);
#pragma unroll
    for (int r = 0; r < 6; ++r)
#pragma unroll
      for (int c = 0; c < 4; ++c)
        acc[r][c] += cv[r].x * wv[c].x + cv[r].y * wv[c].y;
  }
  float jp[6];
#pragma unroll
  for (int r = 0; r < 6; ++r) {
    float s = 0.f;
#pragma unroll
    for (int c = 0; c < 4; ++c) s += acc[r][c] * acc[r][c];
    jp[r] = s;
  }
  __syncthreads();
  float* red = Wf;                    // reuse: 96*17 = 1632 <= 64*66
  float* yv  = Wf + 96 * 17;
#pragma unroll
  for (int r = 0; r < 6; ++r) red[(t0 + r) * 17 + jg] = jp[r];
  if (tid < R_) yv[tid] = yb[(size_t)ml * R_ + tid];
  __syncthreads();
  if (tid < 96) {
    const int t = blk * 96 + tid;
    float S = 0.f;
#pragma unroll
    for (int q = 0; q < 16; ++q) S += red[tid * 17 + q];
    float cy = 0.f;
    for (int k = 0; k < R_; ++k) cy += Cb[tid * CL + k] * yv[k];
    if (t < Tt) {
      const float s = svb[(size_t)ml * TP + t];
      const float g = gradb[(size_t)ml * TP + t];
      const size_t idx = ((size_t)mt * Tt + t) * NL + lat;
      const float x = EPS * s * g + s * cy;
      mug[idx] = mug[idx] + 0.5f * x;               // LR = 0.5
      dhg[idx] = -(EPS * s + s * s * S);
    }
  }
}

// ---------------------------------------------------------------- F1: output
__global__ __launch_bounds__(256) void k_out(
    const float* __restrict__ mu, float* __restrict__ out) {
  const int g = blockIdx.x * 256 + threadIdx.x;   // g = (m*NL + l)*Tt + t
  if (g >= Mb * NL * Tt) return;
  const int t = g % Tt;
  const int ml = g / Tt;
  const int m = ml / NL, l = ml % NL;
  out[g] = mu[((size_t)m * Tt + t) * NL + l];
}

// ------------------------------------------------------------------- launcher
extern "C" void kernel_launch(void* const* d_in, const int* in_sizes, int n_in,
                              void* d_out, int out_size, void* d_ws, size_t ws_size,
                              hipStream_t stream) {
  (void)in_sizes; (void)n_in; (void)out_size;
  const float* Yraw  = (const float*)d_in[0];
  const float* kern  = (const float*)d_in[1];
  const float* wproj = (const float*)d_in[2];
  const float* K     = (const float*)d_in[3];
  const float* biasp = (const float*)d_in[4];
  float* out = (float*)d_out;

  char* base = (char*)d_ws;
  size_t off = 0;
  auto alloc = [&](size_t bytes) -> void* {
    void* p = base + off;
    off += (bytes + 511) & ~(size_t)511;
    return p;
  };
  float*  WA    = (float*) alloc((size_t)Mb * Tt * Nn * NL * 4);
  float*  WB    = (float*) alloc((size_t)Mb * Tt * Nn * NL * 4);
  float*  Yt    = (float*) alloc((size_t)Mb * Tt * Nn * 4);
  float*  lam   = (float*) alloc((size_t)Mb * Tt * Nn * 4);
  float*  mu    = (float*) alloc((size_t)Mb * Tt * NL * 4);
  float*  dh    = (float*) alloc((size_t)Mb * Tt * NL * 4);
  float*  gradb = (float*) alloc((size_t)ML * TP * 4);
  float*  svb   = (float*) alloc((size_t)ML * TP * 4);
  float*  delb  = (float*) alloc((size_t)ML * TP * 4);
  float*  ub    = (float*) alloc((size_t)ML * R_ * 4);
  float*  yb    = (float*) alloc((size_t)ML * R_ * 4);
  float*  Cg    = (float*) alloc((size_t)CROWS * CS * 4);
  double* WS64  = (double*)alloc((size_t)R_ * LDA * 8);
  double* W64   = (double*)alloc((size_t)R_ * LDA * 8);
  double* R64   = (double*)alloc((size_t)R_ * R_ * 8);
  double* Q64   = (double*)alloc((size_t)R_ * R_ * 8);
  float*  Mh2   = (float*) alloc((size_t)ML * 2 * R_ * R_ * 4);
  float*  Wg    = (float*) alloc((size_t)ML * R_ * LDA * 4);
  if (off > ws_size) return;

  const int gMTN = (Mb * Tt * Nn) / 256;       // 1800
  const int gMTL = (Mb * Tt * NL + 255) / 256; // 150
  const int gRR  = (R_ * R_ + 255) / 256;      // 16

  k_weights<<<gMTN, 256, 0, stream>>>(Yraw, kern, wproj, WA, WB, Yt);
  k_scholM<<<1, 256, 0, stream>>>(K, WS64);
  k_cmake<<<R_ + 1, 320, 0, stream>>>(K, WS64, Cg);
  k_rmul<<<gRR, 256, 0, stream>>>(Cg, R64);
  k_qchol<<<1, 256, 0, stream>>>(R64, W64);
  k_qmul<<<gRR, 256, 0, stream>>>(W64, Q64);
  k_init<<<gMTL, 256, 0, stream>>>(mu, dh);

  for (int it = 0; it < 5; ++it) {
    k_lambda<<<gMTN, 256, 0, stream>>>(WA, mu, dh, biasp, lam);
    k_gdpre<<<ML, 320, 0, stream>>>(WB, Yt, lam, Cg, Q64, mu,
                                    gradb, svb, delb, ub);
    k_mhat<<<ML * 2, 256, 0, stream>>>(Cg, delb, Mh2);
    k_cholM<<<ML, 256, 0, stream>>>(Mh2, ub, Wg, yb);
    k_fin<<<ML * 4, 256, 0, stream>>>(Cg, Wg, yb, gradb, svb, mu, dh);
  }
  k_out<<<gMTL, 256, 0, stream>>>(mu, out);
}

// Round 13
// 587.584 us; speedup vs baseline: 2.8567x; 1.5203x over previous
//
// FCGPFA variational iteration for MI355X (gfx950). Round 13: rank 64 -> 32.
// Eigen-decay exp(-0.088 j^2) => rank-32 Nystrom residual ~1e-9 << eps=1e-3.
// Evenly spaced pivots p_k = (600k+300)/64 (fill 4.7 << sigma=20).
// chol32_trtri32 = mini-chol + 1-wave trtri ONLY (no panel solve / trailing /
// off-diag gemm) -> the two ~105us serial fp64 chols collapse to ~25us.
// k_mhat+k_cholM merged into k_mcho (Mhat in LDS, 71KB -> 2 WGs/CU).
//
#include <hip/hip_runtime.h>
#include <math.h>

namespace {
constexpr int Mb   = 16;
constexpr int Nn   = 96;
constexpr int NTF  = 350;
constexpr int Tt   = 300;
constexpr int NSUB = 8;
constexpr int NTAU = 20;
constexpr int NL   = 8;
constexpr int ML   = Mb * NL;   // 128 systems
constexpr int R_   = 32;        // low-rank dimension
constexpr int CS   = 33;        // C global row stride
constexpr int CL   = 34;        // C LDS row stride (even -> float2 ok)
constexpr int LDW  = 33;        // A/W row stride
constexpr int TP   = 320;
constexpr int CROWS= 384;       // C rows padded for 4 x 96 t-blocks
constexpr float EPS = 0.001f;
}

__device__ __forceinline__ int PIV(int k) { return (600 * k + 300) >> 6; }

__device__ __forceinline__ float  sqrt_(float x)  { return sqrtf(x); }
__device__ __forceinline__ double sqrt_(double x) { return sqrt(x); }

__device__ __forceinline__ void lfence() {
  asm volatile("s_waitcnt lgkmcnt(0)" ::: "memory");
}

// ------------- 32x32 Cholesky (lower) + W = L^-1, 256 threads ---------------
// Left-looking register mini-chol (1 lfence/column, proven r10-r12) + 1-wave
// lane-per-column triangular inverse (proven r5-r12). A: LDS 32xLDW.
// W: LDS or global 32xLDW (all 32x32 entries written; upper zeroed).
template <typename T>
__device__ void chol32_trtri32(T* __restrict__ A, T* __restrict__ W,
                               T* __restrict__ rd, T* __restrict__ V,
                               T* __restrict__ buf, int tid) {
  if (tid < 64) {
    const int r = tid;                 // lanes 32..63: dummies
    T v[32];
    if (r < 32) {
#pragma unroll
      for (int k = 0; k < 32; ++k) v[k] = A[r * LDW + k];
    } else {
#pragma unroll
      for (int k = 0; k < 32; ++k) v[k] = (T)0;
    }
    T myis = (T)0;
#pragma unroll
    for (int c = 0; c < 32; ++c) {
      if (r == c) {                    // broadcast finalized row c (+ raw pivot)
#pragma unroll
        for (int k = 0; k <= c; ++k) buf[k] = v[k];
      }
      lfence();
      T dotp = (T)0, dotv = (T)0;
#pragma unroll
      for (int k = 0; k < c; ++k) {
        const T b = buf[k];
        dotp += b * b;
        dotv += v[k] * b;
      }
      const T psq = buf[c] - dotp;     // all lanes compute pivot redundantly
      T s, is;
      if (psq > (T)1e-12) { s = sqrt_(psq); is = (T)1 / s; }
      else                { s = (T)0;       is = (T)0; }
      if (r == c)               { v[c] = s; myis = is; }
      else if (r > c && r < 32) v[c] = (v[c] - dotv) * is;
    }
    if (r < 32) {
#pragma unroll
      for (int k = 0; k < 32; ++k) if (k <= r) A[r * LDW + k] = v[k];
      rd[r] = myis;
    }
  }
  __syncthreads();
  // triangular inverse: lane c computes column c (lane-private, in-order DS)
  if (tid < 32) {
    const int c = tid;
    V[c * LDW + c] = rd[c];
    for (int r = c + 1; r < 32; ++r) {
      T acc = (T)0;
      for (int k = c; k < r; ++k) acc += A[r * LDW + k] * V[k * LDW + c];
      V[r * LDW + c] = -acc * rd[r];
    }
    for (int r = 0; r < 32; ++r)
      W[r * LDW + c] = (r < c) ? (T)0 : V[r * LDW + c];
  }
  __syncthreads();
}

// ---------------------------------------------------------------- S1: weights
__global__ __launch_bounds__(256) void k_weights(
    const float* __restrict__ Yraw, const float* __restrict__ kern,
    const float* __restrict__ wproj, float* __restrict__ WA,
    float* __restrict__ WB, float* __restrict__ Yt) {
  __shared__ float sk[NTAU * NSUB];
  __shared__ float sp[NSUB * NL];
  const int tid = threadIdx.x;
  if (tid < NTAU * NSUB) sk[tid] = kern[tid];
  if (tid < NSUB * NL)   sp[tid] = wproj[tid];
  __syncthreads();
  const int g = blockIdx.x * 256 + tid;            // g = (m*Tt + t)*Nn + n
  if (g >= Mb * Tt * Nn) return;
  const int n  = g % Nn;
  const int mt = g / Nn;
  const int t  = mt % Tt;
  const int m  = mt / Tt;
  const float* yr = Yraw + ((size_t)m * Nn + n) * NTF + 30 + t;
  float ya[NTAU + 1];
#pragma unroll
  for (int j = 0; j <= NTAU; ++j) ya[j] = yr[j];
  float gs[NSUB];
#pragma unroll
  for (int s = 0; s < NSUB; ++s) {
    float acc = 0.f;
#pragma unroll
    for (int j = 0; j < NTAU; ++j) acc += ya[j] * sk[(NTAU - 1 - j) * NSUB + s];
    gs[s] = (fabsf(acc) < 1e-5f) ? 0.f : acc;      // reference threshold
  }
  float w[NL];
#pragma unroll
  for (int l = 0; l < NL; ++l) {
    float acc = 0.f;
#pragma unroll
    for (int s = 0; s < NSUB; ++s) acc += gs[s] * sp[s * NL + l];
    w[l] = acc;
  }
  float4* wa4 = reinterpret_cast<float4*>(WA + (size_t)g * NL);
  wa4[0] = make_float4(w[0], w[1], w[2], w[3]);
  wa4[1] = make_float4(w[4], w[5], w[6], w[7]);
#pragma unroll
  for (int l = 0; l < NL; ++l)
    WB[(((size_t)m * NL + l) * Tt + t) * Nn + n] = w[l];
  Yt[g] = ya[NTAU];
}

// ---- S2a: M = K[S,S] (fp64) -> chol32+trtri32 -> W_S (global) --------------
__global__ __launch_bounds__(256) void k_scholM(
    const float* __restrict__ K, double* __restrict__ WS64) {
  __shared__ double A[R_ * LDW];
  __shared__ double V[R_ * LDW];
  __shared__ double rd[R_];
  __shared__ double buf[40];
  const int tid = threadIdx.x;
  for (int e = tid; e < R_ * R_; e += 256) {
    const int a = e >> 5, b = e & 31;
    A[a * LDW + b] = (double)K[(size_t)PIV(a) * Tt + PIV(b)];
  }
  __syncthreads();
  chol32_trtri32<double>(A, WS64, rd, V, buf, tid);
}

// ---- S2b: C[t][k] = sum_{j<=k} W_S[k][j]*K[p_j][t]; k==R_ zeroes pad col ---
__global__ __launch_bounds__(320) void k_cmake(
    const float* __restrict__ K, const double* __restrict__ WS64,
    float* __restrict__ Cg) {
  const int k = blockIdx.x;            // 0..32
  const int t = threadIdx.x;
  if (k == R_) {
    for (int r = t; r < CROWS; r += 320) Cg[(size_t)r * CS + R_] = 0.f;
    return;
  }
  __shared__ double wrow[R_];
  if (t < R_) wrow[t] = WS64[(size_t)k * LDW + t];
  __syncthreads();
  if (t < Tt) {
    double acc = 0.0;
    for (int j = 0; j <= k; ++j)
      acc += wrow[j] * (double)K[(size_t)PIV(j) * Tt + t];
    Cg[(size_t)t * CS + k] = (float)acc;
  }
  for (int r = Tt + t; r < CROWS; r += 320) Cg[(size_t)r * CS + k] = 0.f;
}

// ---------------- S3a: R64 = eps*I + C^T C (fp64, 4 WGs) --------------------
__global__ __launch_bounds__(256) void k_rmul(
    const float* __restrict__ Cg, double* __restrict__ R64) {
  const int e = blockIdx.x * 256 + threadIdx.x;
  if (e >= R_ * R_) return;
  const int i = e >> 5, j = e & 31;
  double acc = (i == j) ? 0.001 : 0.0;
  for (int r = 0; r < Tt; ++r)
    acc += (double)Cg[(size_t)r * CS + i] * (double)Cg[(size_t)r * CS + j];
  R64[e] = acc;
}

// --------------- S3b: chol32+trtri32 of R (fp64), W -> global ---------------
__global__ __launch_bounds__(256) void k_qchol(
    const double* __restrict__ R64, double* __restrict__ W64) {
  __shared__ double A[R_ * LDW];
  __shared__ double V[R_ * LDW];
  __shared__ double rd[R_];
  __shared__ double buf[40];
  const int tid = threadIdx.x;
  for (int e = tid; e < R_ * R_; e += 256) {
    const int i = e >> 5, j = e & 31;
    A[i * LDW + j] = R64[e];
  }
  __syncthreads();
  chol32_trtri32<double>(A, W64, rd, V, buf, tid);
}

// --------------- S3c: Q64 = W^T W (fp64, 4 WGs) -----------------------------
__global__ __launch_bounds__(256) void k_qmul(
    const double* __restrict__ W64, double* __restrict__ Qg) {
  const int e = blockIdx.x * 256 + threadIdx.x;
  if (e >= R_ * R_) return;
  const int i = e >> 5, j = e & 31;
  const int k0 = (i > j) ? i : j;
  double acc = 0.0;
  for (int k = k0; k < R_; ++k) acc += W64[k * LDW + i] * W64[k * LDW + j];
  Qg[e] = acc;
}

// ------------------------------- S4: init (dh0 = 1 + eps) -------------------
__global__ __launch_bounds__(256) void k_init(
    float* __restrict__ mu, float* __restrict__ dh) {
  const int g = blockIdx.x * 256 + threadIdx.x;
  if (g >= Mb * Tt * NL) return;
  mu[g] = 0.f;
  dh[g] = 1.0f + EPS;
}

// ---------------------------------------------------------------- I1: lambda
__global__ __launch_bounds__(256) void k_lambda(
    const float* __restrict__ WA, const float* __restrict__ mu,
    const float* __restrict__ dh, const float* __restrict__ biasp,
    float* __restrict__ lam) {
  const int g = blockIdx.x * 256 + threadIdx.x;
  if (g >= Mb * Tt * Nn) return;
  const int mt = g / Nn;
  const float b = biasp[0];
  const float4* wa = reinterpret_cast<const float4*>(WA + (size_t)g * NL);
  const float4* mp = reinterpret_cast<const float4*>(mu + (size_t)mt * NL);
  const float4* dp = reinterpret_cast<const float4*>(dh + (size_t)mt * NL);
  const float4 w0 = wa[0], w1 = wa[1];
  const float4 m0 = mp[0], m1 = mp[1];
  const float4 h0 = dp[0], h1 = dp[1];
  float e = b;
  e += w0.x * (m0.x + 0.5f * w0.x * h0.x);
  e += w0.y * (m0.y + 0.5f * w0.y * h0.y);
  e += w0.z * (m0.z + 0.5f * w0.z * h0.z);
  e += w0.w * (m0.w + 0.5f * w0.w * h0.w);
  e += w1.x * (m1.x + 0.5f * w1.x * h1.x);
  e += w1.y * (m1.y + 0.5f * w1.y * h1.y);
  e += w1.z * (m1.z + 0.5f * w1.z * h1.z);
  e += w1.w * (m1.w + 0.5f * w1.w * h1.w);
  lam[g] = expf(e);
}

// ---- I2: fused gd + pre (proven r12 structure, R_=32) ----------------------
__global__ __launch_bounds__(320) void k_gdpre(
    const float* __restrict__ WB, const float* __restrict__ Yt,
    const float* __restrict__ lam, const float* __restrict__ Cg,
    const double* __restrict__ Qg, const float* __restrict__ mug,
    float* __restrict__ gradb, float* __restrict__ svb,
    float* __restrict__ delb, float* __restrict__ ub) {
  const int ml = blockIdx.x;
  const int m = ml / NL, lat = ml % NL;
  const int tid = threadIdx.x;                     // 0..319
  __shared__ float Cb[32 * CL];
  __shared__ float muv[TP], gv[TP], sv[TP], sg[TP];
  __shared__ double pv[R_], qv[R_];
  // Phase A: ga, dd from WB/Yt/lam; s, delta
  {
    float ga = 0.f, dd = 0.f, m_ = 0.f;
    if (tid < Tt) {
      m_ = mug[((size_t)m * Tt + tid) * NL + lat];
      const float4* wb = reinterpret_cast<const float4*>(WB + ((size_t)ml * Tt + tid) * Nn);
      const float4* yt = reinterpret_cast<const float4*>(Yt + ((size_t)m * Tt + tid) * Nn);
      const float4* la = reinterpret_cast<const float4*>(lam + ((size_t)m * Tt + tid) * Nn);
      for (int q = 0; q < Nn / 4; ++q) {
        const float4 w = wb[q], y = yt[q], v = la[q];
        ga += w.x * (y.x - v.x) + w.y * (y.y - v.y) + w.z * (y.z - v.z) + w.w * (y.w - v.w);
        dd += w.x * w.x * v.x + w.y * w.y * v.y + w.z * w.z * v.z + w.w * w.w * v.w;
      }
    }
    muv[tid] = m_;
    gv[tid] = (tid < Tt) ? ga : 0.f;
    const float d_ = (tid < Tt) ? dd : 0.f;
    const float s = 1.f / (1.f + EPS * d_);
    sv[tid] = s;
    svb[(size_t)ml * TP + tid]  = s;
    delb[(size_t)ml * TP + tid] = d_ * s;
  }
  __syncthreads();
  // Phase B: p = C^T mu (fp64, staged 32-row blocks)
  double run_p = 0.0;
  for (int b = 0; b < 10; ++b) {
    for (int e = tid; e < 32 * CS; e += 320) {
      const int r = e / CS, c = e - r * CS;
      Cb[r * CL + c] = Cg[(size_t)(b * 32) * CS + e];
    }
    __syncthreads();
    if (tid < R_)
      for (int rr = 0; rr < 32; ++rr)
        run_p += (double)Cb[rr * CL + tid] * (double)muv[b * 32 + rr];
    __syncthreads();
  }
  if (tid < R_) pv[tid] = run_p;
  __syncthreads();
  // Phase C: q = Q p (fp64)
  if (tid < R_) {
    double acc = 0.0;
    for (int j = 0; j < R_; ++j) acc += Qg[(size_t)j * R_ + tid] * pv[j];
    qv[tid] = acc;
  }
  __syncthreads();
  // Phase D: grad = g1 - 1000*(mu - C q) [fp64 inner]; u = C^T (s*grad)
  float run_u = 0.f;
  for (int b = 0; b < 10; ++b) {
    for (int e = tid; e < 32 * CS; e += 320) {
      const int r = e / CS, c = e - r * CS;
      Cb[r * CL + c] = Cg[(size_t)(b * 32) * CS + e];
    }
    __syncthreads();
    if (tid < 32) {
      const int t = b * 32 + tid;
      double cq = 0.0;
      for (int k = 0; k < R_; ++k) cq += (double)Cb[tid * CL + k] * qv[k];
      const double gnew = (double)gv[t] - 1000.0 * ((double)muv[t] - cq);
      gv[t] = (float)gnew;
      sg[t] = sv[t] * gv[t];
    }
    __syncthreads();
    if (tid < R_)
      for (int rr = 0; rr < 32; ++rr)
        run_u += Cb[rr * CL + tid] * sg[b * 32 + rr];
    __syncthreads();
  }
  gradb[(size_t)ml * TP + tid] = gv[tid];
  if (tid < R_) ub[(size_t)ml * R_ + tid] = run_u;
}

// ---- I3: Mhat = I + C^T diag(delta) C; chol32+trtri32; y = W^T(W u) --------
// One WG per system. 64 tiles x 4 k-chunks (75 rows) = 256 threads.
__global__ __launch_bounds__(256) void k_mcho(
    const float* __restrict__ Cg, const float* __restrict__ delb,
    const float* __restrict__ ub, float* __restrict__ Wg,
    float* __restrict__ yb) {
  const int s = blockIdx.x;
  const int tid = threadIdx.x;
  __shared__ float Cf[Tt * CL];        // 40.8 KB
  __shared__ float dl[Tt];
  __shared__ float part[4 * 64 * 16];  // 16 KB
  __shared__ float A[R_ * LDW];
  __shared__ float W[R_ * LDW];
  __shared__ float V[R_ * LDW];
  __shared__ float rd[R_];
  __shared__ float buf[40];
  __shared__ float uv[R_], t1v[R_];
  for (int e = tid; e < Tt * R_; e += 256) {
    const int r = e >> 5, c = e & 31;
    Cf[r * CL + c] = Cg[(size_t)r * CS + c];
  }
  for (int t = tid; t < Tt; t += 256) dl[t] = delb[(size_t)s * TP + t];
  if (tid < R_) uv[tid] = ub[(size_t)s * R_ + tid];
  __syncthreads();
  // tile partials
  {
    const int tile = tid & 63, ch = tid >> 6;
    const int a = tile >> 3, b = tile & 7;
    const int i0 = a * 4, j0 = b * 4;
    float acc[4][4];
#pragma unroll
    for (int r = 0; r < 4; ++r)
#pragma unroll
      for (int c = 0; c < 4; ++c) acc[r][c] = 0.f;
    const int ta = ch * 75, tb = ta + 75;
    for (int t = ta; t < tb; ++t) {
      const float w = dl[t];
      const float2 u0 = *reinterpret_cast<const float2*>(&Cf[t * CL + i0]);
      const float2 u1 = *reinterpret_cast<const float2*>(&Cf[t * CL + i0 + 2]);
      const float2 v0 = *reinterpret_cast<const float2*>(&Cf[t * CL + j0]);
      const float2 v1 = *reinterpret_cast<const float2*>(&Cf[t * CL + j0 + 2]);
      const float ua[4] = {u0.x * w, u0.y * w, u1.x * w, u1.y * w};
      const float vb[4] = {v0.x, v0.y, v1.x, v1.y};
#pragma unroll
      for (int r = 0; r < 4; ++r)
#pragma unroll
        for (int c = 0; c < 4; ++c) acc[r][c] += ua[r] * vb[c];
    }
    float* p = &part[(ch * 64 + tile) * 16];
#pragma unroll
    for (int r = 0; r < 4; ++r)
#pragma unroll
      for (int c = 0; c < 4; ++c) p[r * 4 + c] = acc[r][c];
  }
  __syncthreads();
  // reduce 4 chunks -> A (+I)
  for (int e = tid; e < R_ * R_; e += 256) {
    const int i = e >> 5, j = e & 31;
    const int tile = (i >> 2) * 8 + (j >> 2);
    const int el = (i & 3) * 4 + (j & 3);
    const float val = part[(0 * 64 + tile) * 16 + el] + part[(1 * 64 + tile) * 16 + el]
                    + part[(2 * 64 + tile) * 16 + el] + part[(3 * 64 + tile) * 16 + el];
    A[i * LDW + j] = val + ((i == j) ? 1.f : 0.f);
  }
  __syncthreads();
  chol32_trtri32<float>(A, W, rd, V, buf, tid);
  // y = W^T (W u)
  if (tid < R_) {
    float acc = 0.f;
    for (int j = 0; j <= tid; ++j) acc += W[tid * LDW + j] * uv[j];
    t1v[tid] = acc;
  }
  __syncthreads();
  if (tid < R_) {
    float acc = 0.f;
    for (int i = tid; i < R_; ++i) acc += W[i * LDW + tid] * t1v[i];
    yb[(size_t)s * R_ + tid] = acc;
  }
  float* Wo = Wg + (size_t)s * R_ * LDW;
  for (int e = tid; e < R_ * LDW; e += 256) Wo[e] = W[e];
}

// ---- I4: X = C W^T (3x4 tiles, triangular kmax) -> jsq -> dh, mu update ----
// 512 WGs = (system, t-block of 96). 32 t-groups x 8 j-groups = 256 threads.
__global__ __launch_bounds__(256) void k_fin(
    const float* __restrict__ Cg, const float* __restrict__ Wg,
    const float* __restrict__ yb, const float* __restrict__ gradb,
    const float* __restrict__ svb, float* __restrict__ mug,
    float* __restrict__ dhg) {
  const int bid = blockIdx.x;
  const int ml = bid >> 2, blk = bid & 3;
  const int mt = ml / NL, lat = ml % NL;
  const int tid = threadIdx.x;
  __shared__ float Wf[R_ * CL];       // 32 x 34
  __shared__ float Cb[96 * CL];       // 96 x 34
  __shared__ float red[96 * 9];
  __shared__ float yv[R_];
  {
    const float* Ws = Wg + (size_t)ml * R_ * LDW;
    for (int e = tid; e < R_ * LDW; e += 256) {
      const int r = e / LDW, c = e - r * LDW;
      Wf[r * CL + c] = Ws[e];
    }
    const float* Cs = Cg + (size_t)(blk * 96) * CS;
    for (int e = tid; e < 96 * CS; e += 256) {
      const int r = e / CS, c = e - r * CS;
      Cb[r * CL + c] = Cs[e];
    }
    if (tid < R_) yv[tid] = yb[(size_t)ml * R_ + tid];
  }
  __syncthreads();
  const int tg = tid & 31, jg = tid >> 5;          // 32 x 8
  const int t0 = tg * 3, j0 = jg * 4;
  float acc[3][4];
#pragma unroll
  for (int r = 0; r < 3; ++r)
#pragma unroll
    for (int c = 0; c < 4; ++c) acc[r][c] = 0.f;
  const int kmax = j0 + 4;            // W rows j0..j0+3 zero beyond row index
  for (int k = 0; k < kmax; k += 2) {
    float2 cv[3], wv[4];
#pragma unroll
    for (int r = 0; r < 3; ++r)
      cv[r] = *reinterpret_cast<const float2*>(&Cb[(t0 + r) * CL + k]);
#pragma unroll
    for (int c = 0; c < 4; ++c)
      wv[c] = *reinterpret_cast<const float2*>(&Wf[(j0 + c) * CL + k]);
#pragma unroll
    for (int r = 0; r < 3; ++r)
#pragma unroll
      for (int c = 0; c < 4; ++c)
        acc[r][c] += cv[r].x * wv[c].x + cv[r].y * wv[c].y;
  }
#pragma unroll
  for (int r = 0; r < 3; ++r) {
    float sjp = 0.f;
#pragma unroll
    for (int c = 0; c < 4; ++c) sjp += acc[r][c] * acc[r][c];
    red[(t0 + r) * 9 + jg] = sjp;
  }
  __syncthreads();
  if (tid < 96) {
    const int t = blk * 96 + tid;
    float S = 0.f;
#pragma unroll
    for (int q = 0; q < 8; ++q) S += red[tid * 9 + q];
    float cy = 0.f;
    for (int k = 0; k < R_; ++k) cy += Cb[tid * CL + k] * yv[k];
    if (t < Tt) {
      const float s = svb[(size_t)ml * TP + t];
      const float g = gradb[(size_t)ml * TP + t];
      const size_t idx = ((size_t)mt * Tt + t) * NL + lat;
      const float x = EPS * s * g + s * cy;
      mug[idx] = mug[idx] + 0.5f * x;               // LR = 0.5
      dhg[idx] = -(EPS * s + s * s * S);
    }
  }
}

// ---------------------------------------------------------------- F1: output
__global__ __launch_bounds__(256) void k_out(
    const float* __restrict__ mu, float* __restrict__ out) {
  const int g = blockIdx.x * 256 + threadIdx.x;   // g = (m*NL + l)*Tt + t
  if (g >= Mb * NL * Tt) return;
  const int t = g % Tt;
  const int ml = g / Tt;
  const int m = ml / NL, l = ml % NL;
  out[g] = mu[((size_t)m * Tt + t) * NL + l];
}

// ------------------------------------------------------------------- launcher
extern "C" void kernel_launch(void* const* d_in, const int* in_sizes, int n_in,
                              void* d_out, int out_size, void* d_ws, size_t ws_size,
                              hipStream_t stream) {
  (void)in_sizes; (void)n_in; (void)out_size;
  const float* Yraw  = (const float*)d_in[0];
  const float* kern  = (const float*)d_in[1];
  const float* wproj = (const float*)d_in[2];
  const float* K     = (const float*)d_in[3];
  const float* biasp = (const float*)d_in[4];
  float* out = (float*)d_out;

  char* base = (char*)d_ws;
  size_t off = 0;
  auto alloc = [&](size_t bytes) -> void* {
    void* p = base + off;
    off += (bytes + 511) & ~(size_t)511;
    return p;
  };
  float*  WA    = (float*) alloc((size_t)Mb * Tt * Nn * NL * 4);
  float*  WB    = (float*) alloc((size_t)Mb * Tt * Nn * NL * 4);
  float*  Yt    = (float*) alloc((size_t)Mb * Tt * Nn * 4);
  float*  lam   = (float*) alloc((size_t)Mb * Tt * Nn * 4);
  float*  mu    = (float*) alloc((size_t)Mb * Tt * NL * 4);
  float*  dh    = (float*) alloc((size_t)Mb * Tt * NL * 4);
  float*  gradb = (float*) alloc((size_t)ML * TP * 4);
  float*  svb   = (float*) alloc((size_t)ML * TP * 4);
  float*  delb  = (float*) alloc((size_t)ML * TP * 4);
  float*  ub    = (float*) alloc((size_t)ML * R_ * 4);
  float*  yb    = (float*) alloc((size_t)ML * R_ * 4);
  float*  Cg    = (float*) alloc((size_t)CROWS * CS * 4);
  double* WS64  = (double*)alloc((size_t)R_ * LDW * 8);
  double* W64   = (double*)alloc((size_t)R_ * LDW * 8);
  double* R64   = (double*)alloc((size_t)R_ * R_ * 8);
  double* Q64   = (double*)alloc((size_t)R_ * R_ * 8);
  float*  Wg    = (float*) alloc((size_t)ML * R_ * LDW * 4);
  if (off > ws_size) return;

  const int gMTN = (Mb * Tt * Nn) / 256;       // 1800
  const int gMTL = (Mb * Tt * NL + 255) / 256; // 150
  const int gRR  = (R_ * R_ + 255) / 256;      // 4

  k_weights<<<gMTN, 256, 0, stream>>>(Yraw, kern, wproj, WA, WB, Yt);
  k_scholM<<<1, 256, 0, stream>>>(K, WS64);
  k_cmake<<<R_ + 1, 320, 0, stream>>>(K, WS64, Cg);
  k_rmul<<<gRR, 256, 0, stream>>>(Cg, R64);
  k_qchol<<<1, 256, 0, stream>>>(R64, W64);
  k_qmul<<<gRR, 256, 0, stream>>>(W64, Q64);
  k_init<<<gMTL, 256, 0, stream>>>(mu, dh);

  for (int it = 0; it < 5; ++it) {
    k_lambda<<<gMTN, 256, 0, stream>>>(WA, mu, dh, biasp, lam);
    k_gdpre<<<ML, 320, 0, stream>>>(WB, Yt, lam, Cg, Q64, mu,
                                    gradb, svb, delb, ub);
    k_mcho<<<ML, 256, 0, stream>>>(Cg, delb, ub, Wg, yb);
    k_fin<<<ML * 4, 256, 0, stream>>>(Cg, Wg, yb, gradb, svb, mu, dh);
  }
  k_out<<<gMTL, 256, 0, stream>>>(mu, out);
}

// Round 14
// 515.321 us; speedup vs baseline: 3.2573x; 1.1402x over previous
//
// FCGPFA variational iteration for MI355X (gfx950). Round 14: round-13 (587us)
// with (a) the unrolled register mini-chol (30KB code -> I-fetch-bound 54us on
// a single cold wave) replaced by an un-unrolled LDS-resident left-looking
// mini-chol (~80 instrs, same proven elimination, 1 lfence/col) in all three
// chol32 call sites; (b) k_gdpre restructured to full-C staging: phase D's
// C.q now 300-thread-parallel, barriers 22 -> 7. All else identical to r13.
//
#include <hip/hip_runtime.h>
#include <math.h>

namespace {
constexpr int Mb   = 16;
constexpr int Nn   = 96;
constexpr int NTF  = 350;
constexpr int Tt   = 300;
constexpr int NSUB = 8;
constexpr int NTAU = 20;
constexpr int NL   = 8;
constexpr int ML   = Mb * NL;   // 128 systems
constexpr int R_   = 32;        // low-rank dimension
constexpr int CS   = 33;        // C global row stride
constexpr int CL   = 34;        // C LDS row stride (even -> float2 ok)
constexpr int LDW  = 33;        // A/W row stride
constexpr int TP   = 320;
constexpr int CROWS= 384;       // C rows padded for 4 x 96 t-blocks
constexpr float EPS = 0.001f;
}

__device__ __forceinline__ int PIV(int k) { return (600 * k + 300) >> 6; }

__device__ __forceinline__ float  sqrt_(float x)  { return sqrtf(x); }
__device__ __forceinline__ double sqrt_(double x) { return sqrt(x); }

__device__ __forceinline__ void lfence() {
  asm volatile("s_waitcnt lgkmcnt(0)" ::: "memory");
}

// ------------- 32x32 Cholesky (lower) + W = L^-1, 256 threads ---------------
// Mini-chol: LDS-resident LEFT-LOOKING, lanes 0..31, dynamic loops (tiny code,
// no register arrays). A (32xLDW LDS): full symmetric in, lower = L out.
// Column c: reads L-row c (cols <c, final) + own original col c; wave-lockstep
// ensures reads precede the column write; lfence publishes before next column.
// Then 1-wave lane-per-column trtri (proven r5-r13). W: all 32x32 written.
template <typename T>
__device__ void chol32_trtri32(T* A, T* W, T* rd, T* V, int tid) {
  if (tid < 32) {
    const int r = tid;
    for (int c = 0; c < 32; ++c) {
      T dotp = (T)0, dotv = (T)0;
      for (int k = 0; k < c; ++k) {
        const T bc = A[c * LDW + k];       // broadcast (same addr all lanes)
        dotp += bc * bc;
        dotv += A[r * LDW + k] * bc;       // own row, conflict-free
      }
      const T pivot = A[c * LDW + c] - dotp;   // read before lane c writes
      T s, is;
      if (pivot > (T)1e-12) { s = sqrt_(pivot); is = (T)1 / s; }
      else                  { s = (T)0;         is = (T)0; }
      if (r == c)      { A[c * LDW + c] = s; rd[c] = is; }
      else if (r > c)  A[r * LDW + c] = (A[r * LDW + c] - dotv) * is;
      lfence();
    }
  }
  __syncthreads();
  // triangular inverse: lane c computes column c (lane-private, in-order DS)
  if (tid < 32) {
    const int c = tid;
    V[c * LDW + c] = rd[c];
    for (int r = c + 1; r < 32; ++r) {
      T acc = (T)0;
      for (int k = c; k < r; ++k) acc += A[r * LDW + k] * V[k * LDW + c];
      V[r * LDW + c] = -acc * rd[r];
    }
    for (int r = 0; r < 32; ++r)
      W[r * LDW + c] = (r < c) ? (T)0 : V[r * LDW + c];
  }
  __syncthreads();
}

// ---------------------------------------------------------------- S1: weights
__global__ __launch_bounds__(256) void k_weights(
    const float* __restrict__ Yraw, const float* __restrict__ kern,
    const float* __restrict__ wproj, float* __restrict__ WA,
    float* __restrict__ WB, float* __restrict__ Yt) {
  __shared__ float sk[NTAU * NSUB];
  __shared__ float sp[NSUB * NL];
  const int tid = threadIdx.x;
  if (tid < NTAU * NSUB) sk[tid] = kern[tid];
  if (tid < NSUB * NL)   sp[tid] = wproj[tid];
  __syncthreads();
  const int g = blockIdx.x * 256 + tid;            // g = (m*Tt + t)*Nn + n
  if (g >= Mb * Tt * Nn) return;
  const int n  = g % Nn;
  const int mt = g / Nn;
  const int t  = mt % Tt;
  const int m  = mt / Tt;
  const float* yr = Yraw + ((size_t)m * Nn + n) * NTF + 30 + t;
  float ya[NTAU + 1];
#pragma unroll
  for (int j = 0; j <= NTAU; ++j) ya[j] = yr[j];
  float gs[NSUB];
#pragma unroll
  for (int s = 0; s < NSUB; ++s) {
    float acc = 0.f;
#pragma unroll
    for (int j = 0; j < NTAU; ++j) acc += ya[j] * sk[(NTAU - 1 - j) * NSUB + s];
    gs[s] = (fabsf(acc) < 1e-5f) ? 0.f : acc;      // reference threshold
  }
  float w[NL];
#pragma unroll
  for (int l = 0; l < NL; ++l) {
    float acc = 0.f;
#pragma unroll
    for (int s = 0; s < NSUB; ++s) acc += gs[s] * sp[s * NL + l];
    w[l] = acc;
  }
  float4* wa4 = reinterpret_cast<float4*>(WA + (size_t)g * NL);
  wa4[0] = make_float4(w[0], w[1], w[2], w[3]);
  wa4[1] = make_float4(w[4], w[5], w[6], w[7]);
#pragma unroll
  for (int l = 0; l < NL; ++l)
    WB[(((size_t)m * NL + l) * Tt + t) * Nn + n] = w[l];
  Yt[g] = ya[NTAU];
}

// ---- S2a: M = K[S,S] (fp64) -> chol32+trtri32 -> W_S (global) --------------
__global__ __launch_bounds__(256) void k_scholM(
    const float* __restrict__ K, double* __restrict__ WS64) {
  __shared__ double A[R_ * LDW];
  __shared__ double V[R_ * LDW];
  __shared__ double rd[R_];
  const int tid = threadIdx.x;
  for (int e = tid; e < R_ * R_; e += 256) {
    const int a = e >> 5, b = e & 31;
    A[a * LDW + b] = (double)K[(size_t)PIV(a) * Tt + PIV(b)];
  }
  __syncthreads();
  chol32_trtri32<double>(A, WS64, rd, V, tid);
}

// ---- S2b: C[t][k] = sum_{j<=k} W_S[k][j]*K[p_j][t]; k==R_ zeroes pad col ---
__global__ __launch_bounds__(320) void k_cmake(
    const float* __restrict__ K, const double* __restrict__ WS64,
    float* __restrict__ Cg) {
  const int k = blockIdx.x;            // 0..32
  const int t = threadIdx.x;
  if (k == R_) {
    for (int r = t; r < CROWS; r += 320) Cg[(size_t)r * CS + R_] = 0.f;
    return;
  }
  __shared__ double wrow[R_];
  if (t < R_) wrow[t] = WS64[(size_t)k * LDW + t];
  __syncthreads();
  if (t < Tt) {
    double acc = 0.0;
    for (int j = 0; j <= k; ++j)
      acc += wrow[j] * (double)K[(size_t)PIV(j) * Tt + t];
    Cg[(size_t)t * CS + k] = (float)acc;
  }
  for (int r = Tt + t; r < CROWS; r += 320) Cg[(size_t)r * CS + k] = 0.f;
}

// ---------------- S3a: R64 = eps*I + C^T C (fp64, 4 WGs) --------------------
__global__ __launch_bounds__(256) void k_rmul(
    const float* __restrict__ Cg, double* __restrict__ R64) {
  const int e = blockIdx.x * 256 + threadIdx.x;
  if (e >= R_ * R_) return;
  const int i = e >> 5, j = e & 31;
  double acc = (i == j) ? 0.001 : 0.0;
  for (int r = 0; r < Tt; ++r)
    acc += (double)Cg[(size_t)r * CS + i] * (double)Cg[(size_t)r * CS + j];
  R64[e] = acc;
}

// --------------- S3b: chol32+trtri32 of R (fp64), W -> global ---------------
__global__ __launch_bounds__(256) void k_qchol(
    const double* __restrict__ R64, double* __restrict__ W64) {
  __shared__ double A[R_ * LDW];
  __shared__ double V[R_ * LDW];
  __shared__ double rd[R_];
  const int tid = threadIdx.x;
  for (int e = tid; e < R_ * R_; e += 256) {
    const int i = e >> 5, j = e & 31;
    A[i * LDW + j] = R64[e];
  }
  __syncthreads();
  chol32_trtri32<double>(A, W64, rd, V, tid);
}

// --------------- S3c: Q64 = W^T W (fp64, 4 WGs) -----------------------------
__global__ __launch_bounds__(256) void k_qmul(
    const double* __restrict__ W64, double* __restrict__ Qg) {
  const int e = blockIdx.x * 256 + threadIdx.x;
  if (e >= R_ * R_) return;
  const int i = e >> 5, j = e & 31;
  const int k0 = (i > j) ? i : j;
  double acc = 0.0;
  for (int k = k0; k < R_; ++k) acc += W64[k * LDW + i] * W64[k * LDW + j];
  Qg[e] = acc;
}

// ------------------------------- S4: init (dh0 = 1 + eps) -------------------
__global__ __launch_bounds__(256) void k_init(
    float* __restrict__ mu, float* __restrict__ dh) {
  const int g = blockIdx.x * 256 + threadIdx.x;
  if (g >= Mb * Tt * NL) return;
  mu[g] = 0.f;
  dh[g] = 1.0f + EPS;
}

// ---------------------------------------------------------------- I1: lambda
__global__ __launch_bounds__(256) void k_lambda(
    const float* __restrict__ WA, const float* __restrict__ mu,
    const float* __restrict__ dh, const float* __restrict__ biasp,
    float* __restrict__ lam) {
  const int g = blockIdx.x * 256 + threadIdx.x;
  if (g >= Mb * Tt * Nn) return;
  const int mt = g / Nn;
  const float b = biasp[0];
  const float4* wa = reinterpret_cast<const float4*>(WA + (size_t)g * NL);
  const float4* mp = reinterpret_cast<const float4*>(mu + (size_t)mt * NL);
  const float4* dp = reinterpret_cast<const float4*>(dh + (size_t)mt * NL);
  const float4 w0 = wa[0], w1 = wa[1];
  const float4 m0 = mp[0], m1 = mp[1];
  const float4 h0 = dp[0], h1 = dp[1];
  float e = b;
  e += w0.x * (m0.x + 0.5f * w0.x * h0.x);
  e += w0.y * (m0.y + 0.5f * w0.y * h0.y);
  e += w0.z * (m0.z + 0.5f * w0.z * h0.z);
  e += w0.w * (m0.w + 0.5f * w0.w * h0.w);
  e += w1.x * (m1.x + 0.5f * w1.x * h1.x);
  e += w1.y * (m1.y + 0.5f * w1.y * h1.y);
  e += w1.z * (m1.z + 0.5f * w1.z * h1.z);
  e += w1.w * (m1.w + 0.5f * w1.w * h1.w);
  lam[g] = expf(e);
}

// ---- I2: fused gd + pre, full-C staging (parallel phase D, 7 barriers) -----
__global__ __launch_bounds__(320) void k_gdpre(
    const float* __restrict__ WB, const float* __restrict__ Yt,
    const float* __restrict__ lam, const float* __restrict__ Cg,
    const double* __restrict__ Qg, const float* __restrict__ mug,
    float* __restrict__ gradb, float* __restrict__ svb,
    float* __restrict__ delb, float* __restrict__ ub) {
  const int ml = blockIdx.x;
  const int m = ml / NL, lat = ml % NL;
  const int tid = threadIdx.x;                     // 0..319
  __shared__ float  Cf[Tt * CL];                   // 40.8 KB
  __shared__ float  muv[Tt], gv[Tt], sv[Tt], sg[Tt];
  __shared__ double pv[R_], qv[R_];
  __shared__ double pB[R_ * 10];
  __shared__ float  pU[R_ * 10];
  // stage C (full) -- all threads
  for (int e = tid; e < Tt * CS; e += 320) {
    const int r = e / CS, c = e - r * CS;
    Cf[r * CL + c] = Cg[e];
  }
  // Phase A: ga, dd from WB/Yt/lam; s, delta
  if (tid < Tt) {
    float ga = 0.f, dd = 0.f;
    const float m_ = mug[((size_t)m * Tt + tid) * NL + lat];
    const float4* wb = reinterpret_cast<const float4*>(WB + ((size_t)ml * Tt + tid) * Nn);
    const float4* yt = reinterpret_cast<const float4*>(Yt + ((size_t)m * Tt + tid) * Nn);
    const float4* la = reinterpret_cast<const float4*>(lam + ((size_t)m * Tt + tid) * Nn);
    for (int q = 0; q < Nn / 4; ++q) {
      const float4 w = wb[q], y = yt[q], v = la[q];
      ga += w.x * (y.x - v.x) + w.y * (y.y - v.y) + w.z * (y.z - v.z) + w.w * (y.w - v.w);
      dd += w.x * w.x * v.x + w.y * w.y * v.y + w.z * w.z * v.z + w.w * w.w * v.w;
    }
    muv[tid] = m_;
    gv[tid]  = ga;
    const float s = 1.f / (1.f + EPS * dd);
    sv[tid] = s;
    svb[(size_t)ml * TP + tid]  = s;
    delb[(size_t)ml * TP + tid] = dd * s;
  }
  __syncthreads();
  // Phase B: p = C^T mu (fp64) -- 32 cols x 10 chunks of 30 rows
  {
    const int k = tid & 31, ch = tid >> 5;
    double acc = 0.0;
    const int t0 = ch * 30;
    for (int t = t0; t < t0 + 30; ++t)
      acc += (double)Cf[t * CL + k] * (double)muv[t];
    pB[k * 10 + ch] = acc;
  }
  __syncthreads();
  if (tid < R_) {
    double a = 0.0;
    for (int ch = 0; ch < 10; ++ch) a += pB[tid * 10 + ch];
    pv[tid] = a;
  }
  __syncthreads();
  // Phase C: q = Q p (fp64)
  if (tid < R_) {
    double acc = 0.0;
    for (int j = 0; j < R_; ++j) acc += Qg[(size_t)j * R_ + tid] * pv[j];
    qv[tid] = acc;
  }
  __syncthreads();
  // Phase D: grad = g1 - 1000*(mu - C q) [fp64 inner] -- 300-thread parallel
  if (tid < Tt) {
    double cq = 0.0;
    for (int k = 0; k < R_; ++k) cq += (double)Cf[tid * CL + k] * qv[k];
    const double gnew = (double)gv[tid] - 1000.0 * ((double)muv[tid] - cq);
    gv[tid] = (float)gnew;
    sg[tid] = sv[tid] * (float)gnew;
  }
  __syncthreads();
  // Phase E: u = C^T (s*grad)
  {
    const int k = tid & 31, ch = tid >> 5;
    float acc = 0.f;
    const int t0 = ch * 30;
    for (int t = t0; t < t0 + 30; ++t) acc += Cf[t * CL + k] * sg[t];
    pU[k * 10 + ch] = acc;
  }
  __syncthreads();
  if (tid < Tt) gradb[(size_t)ml * TP + tid] = gv[tid];
  if (tid < R_) {
    float a = 0.f;
    for (int ch = 0; ch < 10; ++ch) a += pU[tid * 10 + ch];
    ub[(size_t)ml * R_ + tid] = a;
  }
}

// ---- I3: Mhat = I + C^T diag(delta) C; chol32+trtri32; y = W^T(W u) --------
// One WG per system. 64 tiles x 4 k-chunks (75 rows) = 256 threads.
__global__ __launch_bounds__(256) void k_mcho(
    const float* __restrict__ Cg, const float* __restrict__ delb,
    const float* __restrict__ ub, float* __restrict__ Wg,
    float* __restrict__ yb) {
  const int s = blockIdx.x;
  const int tid = threadIdx.x;
  __shared__ float Cf[Tt * CL];        // 40.8 KB
  __shared__ float dl[Tt];
  __shared__ float part[4 * 64 * 16];  // 16 KB
  __shared__ float A[R_ * LDW];
  __shared__ float W[R_ * LDW];
  __shared__ float V[R_ * LDW];
  __shared__ float rd[R_];
  __shared__ float uv[R_], t1v[R_];
  for (int e = tid; e < Tt * R_; e += 256) {
    const int r = e >> 5, c = e & 31;
    Cf[r * CL + c] = Cg[(size_t)r * CS + c];
  }
  for (int t = tid; t < Tt; t += 256) dl[t] = delb[(size_t)s * TP + t];
  if (tid < R_) uv[tid] = ub[(size_t)s * R_ + tid];
  __syncthreads();
  // tile partials
  {
    const int tile = tid & 63, ch = tid >> 6;
    const int a = tile >> 3, b = tile & 7;
    const int i0 = a * 4, j0 = b * 4;
    float acc[4][4];
#pragma unroll
    for (int r = 0; r < 4; ++r)
#pragma unroll
      for (int c = 0; c < 4; ++c) acc[r][c] = 0.f;
    const int ta = ch * 75, tb = ta + 75;
    for (int t = ta; t < tb; ++t) {
      const float w = dl[t];
      const float2 u0 = *reinterpret_cast<const float2*>(&Cf[t * CL + i0]);
      const float2 u1 = *reinterpret_cast<const float2*>(&Cf[t * CL + i0 + 2]);
      const float2 v0 = *reinterpret_cast<const float2*>(&Cf[t * CL + j0]);
      const float2 v1 = *reinterpret_cast<const float2*>(&Cf[t * CL + j0 + 2]);
      const float ua[4] = {u0.x * w, u0.y * w, u1.x * w, u1.y * w};
      const float vb[4] = {v0.x, v0.y, v1.x, v1.y};
#pragma unroll
      for (int r = 0; r < 4; ++r)
#pragma unroll
        for (int c = 0; c < 4; ++c) acc[r][c] += ua[r] * vb[c];
    }
    float* p = &part[(ch * 64 + tile) * 16];
#pragma unroll
    for (int r = 0; r < 4; ++r)
#pragma unroll
      for (int c = 0; c < 4; ++c) p[r * 4 + c] = acc[r][c];
  }
  __syncthreads();
  // reduce 4 chunks -> A (+I)
  for (int e = tid; e < R_ * R_; e += 256) {
    const int i = e >> 5, j = e & 31;
    const int tile = (i >> 2) * 8 + (j >> 2);
    const int el = (i & 3) * 4 + (j & 3);
    const float val = part[(0 * 64 + tile) * 16 + el] + part[(1 * 64 + tile) * 16 + el]
                    + part[(2 * 64 + tile) * 16 + el] + part[(3 * 64 + tile) * 16 + el];
    A[i * LDW + j] = val + ((i == j) ? 1.f : 0.f);
  }
  __syncthreads();
  chol32_trtri32<float>(A, W, rd, V, tid);
  // y = W^T (W u)
  if (tid < R_) {
    float acc = 0.f;
    for (int j = 0; j <= tid; ++j) acc += W[tid * LDW + j] * uv[j];
    t1v[tid] = acc;
  }
  __syncthreads();
  if (tid < R_) {
    float acc = 0.f;
    for (int i = tid; i < R_; ++i) acc += W[i * LDW + tid] * t1v[i];
    yb[(size_t)s * R_ + tid] = acc;
  }
  float* Wo = Wg + (size_t)s * R_ * LDW;
  for (int e = tid; e < R_ * LDW; e += 256) Wo[e] = W[e];
}

// ---- I4: X = C W^T (3x4 tiles, triangular kmax) -> jsq -> dh, mu update ----
// 512 WGs = (system, t-block of 96). 32 t-groups x 8 j-groups = 256 threads.
__global__ __launch_bounds__(256) void k_fin(
    const float* __restrict__ Cg, const float* __restrict__ Wg,
    const float* __restrict__ yb, const float* __restrict__ gradb,
    const float* __restrict__ svb, float* __restrict__ mug,
    float* __restrict__ dhg) {
  const int bid = blockIdx.x;
  const int ml = bid >> 2, blk = bid & 3;
  const int mt = ml / NL, lat = ml % NL;
  const int tid = threadIdx.x;
  __shared__ float Wf[R_ * CL];       // 32 x 34
  __shared__ float Cb[96 * CL];       // 96 x 34
  __shared__ float red[96 * 9];
  __shared__ float yv[R_];
  {
    const float* Ws = Wg + (size_t)ml * R_ * LDW;
    for (int e = tid; e < R_ * LDW; e += 256) {
      const int r = e / LDW, c = e - r * LDW;
      Wf[r * CL + c] = Ws[e];
    }
    const float* Cs = Cg + (size_t)(blk * 96) * CS;
    for (int e = tid; e < 96 * CS; e += 256) {
      const int r = e / CS, c = e - r * CS;
      Cb[r * CL + c] = Cs[e];
    }
    if (tid < R_) yv[tid] = yb[(size_t)ml * R_ + tid];
  }
  __syncthreads();
  const int tg = tid & 31, jg = tid >> 5;          // 32 x 8
  const int t0 = tg * 3, j0 = jg * 4;
  float acc[3][4];
#pragma unroll
  for (int r = 0; r < 3; ++r)
#pragma unroll
    for (int c = 0; c < 4; ++c) acc[r][c] = 0.f;
  const int kmax = j0 + 4;            // W rows j0..j0+3 zero beyond row index
  for (int k = 0; k < kmax; k += 2) {
    float2 cv[3], wv[4];
#pragma unroll
    for (int r = 0; r < 3; ++r)
      cv[r] = *reinterpret_cast<const float2*>(&Cb[(t0 + r) * CL + k]);
#pragma unroll
    for (int c = 0; c < 4; ++c)
      wv[c] = *reinterpret_cast<const float2*>(&Wf[(j0 + c) * CL + k]);
#pragma unroll
    for (int r = 0; r < 3; ++r)
#pragma unroll
      for (int c = 0; c < 4; ++c)
        acc[r][c] += cv[r].x * wv[c].x + cv[r].y * wv[c].y;
  }
#pragma unroll
  for (int r = 0; r < 3; ++r) {
    float sjp = 0.f;
#pragma unroll
    for (int c = 0; c < 4; ++c) sjp += acc[r][c] * acc[r][c];
    red[(t0 + r) * 9 + jg] = sjp;
  }
  __syncthreads();
  if (tid < 96) {
    const int t = blk * 96 + tid;
    float S = 0.f;
#pragma unroll
    for (int q = 0; q < 8; ++q) S += red[tid * 9 + q];
    float cy = 0.f;
    for (int k = 0; k < R_; ++k) cy += Cb[tid * CL + k] * yv[k];
    if (t < Tt) {
      const float s = svb[(size_t)ml * TP + t];
      const float g = gradb[(size_t)ml * TP + t];
      const size_t idx = ((size_t)mt * Tt + t) * NL + lat;
      const float x = EPS * s * g + s * cy;
      mug[idx] = mug[idx] + 0.5f * x;               // LR = 0.5
      dhg[idx] = -(EPS * s + s * s * S);
    }
  }
}

// ---------------------------------------------------------------- F1: output
__global__ __launch_bounds__(256) void k_out(
    const float* __restrict__ mu, float* __restrict__ out) {
  const int g = blockIdx.x * 256 + threadIdx.x;   // g = (m*NL + l)*Tt + t
  if (g >= Mb * NL * Tt) return;
  const int t = g % Tt;
  const int ml = g / Tt;
  const int m = ml / NL, l = ml % NL;
  out[g] = mu[((size_t)m * Tt + t) * NL + l];
}

// ------------------------------------------------------------------- launcher
extern "C" void kernel_launch(void* const* d_in, const int* in_sizes, int n_in,
                              void* d_out, int out_size, void* d_ws, size_t ws_size,
                              hipStream_t stream) {
  (void)in_sizes; (void)n_in; (void)out_size;
  const float* Yraw  = (const float*)d_in[0];
  const float* kern  = (const float*)d_in[1];
  const float* wproj = (const float*)d_in[2];
  const float* K     = (const float*)d_in[3];
  const float* biasp = (const float*)d_in[4];
  float* out = (float*)d_out;

  char* base = (char*)d_ws;
  size_t off = 0;
  auto alloc = [&](size_t bytes) -> void* {
    void* p = base + off;
    off += (bytes + 511) & ~(size_t)511;
    return p;
  };
  float*  WA    = (float*) alloc((size_t)Mb * Tt * Nn * NL * 4);
  float*  WB    = (float*) alloc((size_t)Mb * Tt * Nn * NL * 4);
  float*  Yt    = (float*) alloc((size_t)Mb * Tt * Nn * 4);
  float*  lam   = (float*) alloc((size_t)Mb * Tt * Nn * 4);
  float*  mu    = (float*) alloc((size_t)Mb * Tt * NL * 4);
  float*  dh    = (float*) alloc((size_t)Mb * Tt * NL * 4);
  float*  gradb = (float*) alloc((size_t)ML * TP * 4);
  float*  svb   = (float*) alloc((size_t)ML * TP * 4);
  float*  delb  = (float*) alloc((size_t)ML * TP * 4);
  float*  ub    = (float*) alloc((size_t)ML * R_ * 4);
  float*  yb    = (float*) alloc((size_t)ML * R_ * 4);
  float*  Cg    = (float*) alloc((size_t)CROWS * CS * 4);
  double* WS64  = (double*)alloc((size_t)R_ * LDW * 8);
  double* W64   = (double*)alloc((size_t)R_ * LDW * 8);
  double* R64   = (double*)alloc((size_t)R_ * R_ * 8);
  double* Q64   = (double*)alloc((size_t)R_ * R_ * 8);
  float*  Wg    = (float*) alloc((size_t)ML * R_ * LDW * 4);
  if (off > ws_size) return;

  const int gMTN = (Mb * Tt * Nn) / 256;       // 1800
  const int gMTL = (Mb * Tt * NL + 255) / 256; // 150
  const int gRR  = (R_ * R_ + 255) / 256;      // 4

  k_weights<<<gMTN, 256, 0, stream>>>(Yraw, kern, wproj, WA, WB, Yt);
  k_scholM<<<1, 256, 0, stream>>>(K, WS64);
  k_cmake<<<R_ + 1, 320, 0, stream>>>(K, WS64, Cg);
  k_rmul<<<gRR, 256, 0, stream>>>(Cg, R64);
  k_qchol<<<1, 256, 0, stream>>>(R64, W64);
  k_qmul<<<gRR, 256, 0, stream>>>(W64, Q64);
  k_init<<<gMTL, 256, 0, stream>>>(mu, dh);

  for (int it = 0; it < 5; ++it) {
    k_lambda<<<gMTN, 256, 0, stream>>>(WA, mu, dh, biasp, lam);
    k_gdpre<<<ML, 320, 0, stream>>>(WB, Yt, lam, Cg, Q64, mu,
                                    gradb, svb, delb, ub);
    k_mcho<<<ML, 256, 0, stream>>>(Cg, delb, ub, Wg, yb);
    k_fin<<<ML * 4, 256, 0, stream>>>(Cg, Wg, yb, gradb, svb, mu, dh);
  }
  k_out<<<gMTL, 256, 0, stream>>>(mu, out);
}

// Round 15
// 436.350 us; speedup vs baseline: 3.8468x; 1.1810x over previous
//
// FCGPFA variational iteration for MI355X (gfx950). Round 15: per-iteration
// chol+trtri ELIMINATED. Mhat = I + C^T diag(delta) C has lambda_min >= 1, so
// Newton-Schulz (X0 = I/Gershgorin, 12 fixed steps, quadratic) converges
// unconditionally to P = Mhat^-1 at fp32 floor -- all GEMM-shaped, no serial
// fence chains. k_mcho (46us, 45% of wall) -> k_mhat (256 WGs, partials) +
// k_ns (128 WGs, reduce+NS+y). k_fin uses P: q_t = sum_j (CP)_tj c_tj.
// Pad rows of delb/svb/gradb now zero-filled (k_mhat reads t in [300,320)).
//
#include <hip/hip_runtime.h>
#include <math.h>

namespace {
constexpr int Mb   = 16;
constexpr int Nn   = 96;
constexpr int NTF  = 350;
constexpr int Tt   = 300;
constexpr int NSUB = 8;
constexpr int NTAU = 20;
constexpr int NL   = 8;
constexpr int ML   = Mb * NL;   // 128 systems
constexpr int R_   = 32;        // low-rank dimension
constexpr int CS   = 33;        // C global row stride
constexpr int CL   = 34;        // C LDS row stride (even -> float2 ok)
constexpr int LDW  = 33;        // P/M row stride
constexpr int TP   = 320;
constexpr int CROWS= 384;       // C rows padded for 4 x 96 t-blocks
constexpr int NSIT = 12;        // Newton-Schulz iterations (fp32 floor @ G<=250)
constexpr float EPS = 0.001f;
}

__device__ __forceinline__ int PIV(int k) { return (600 * k + 300) >> 6; }

__device__ __forceinline__ float  sqrt_(float x)  { return sqrtf(x); }
__device__ __forceinline__ double sqrt_(double x) { return sqrt(x); }

__device__ __forceinline__ void lfence() {
  asm volatile("s_waitcnt lgkmcnt(0)" ::: "memory");
}

// ------------- 32x32 Cholesky (lower) + W = L^-1, 256 threads ---------------
// LDS-resident left-looking mini-chol (tiny code; proven r14) + 1-wave trtri.
// Setup-only now (fp64, K[S,S] and R).
template <typename T>
__device__ void chol32_trtri32(T* A, T* W, T* rd, T* V, int tid) {
  if (tid < 32) {
    const int r = tid;
    for (int c = 0; c < 32; ++c) {
      T dotp = (T)0, dotv = (T)0;
      for (int k = 0; k < c; ++k) {
        const T bc = A[c * LDW + k];       // broadcast (same addr all lanes)
        dotp += bc * bc;
        dotv += A[r * LDW + k] * bc;       // own row, conflict-free
      }
      const T pivot = A[c * LDW + c] - dotp;   // read before lane c writes
      T s, is;
      if (pivot > (T)1e-12) { s = sqrt_(pivot); is = (T)1 / s; }
      else                  { s = (T)0;         is = (T)0; }
      if (r == c)      { A[c * LDW + c] = s; rd[c] = is; }
      else if (r > c)  A[r * LDW + c] = (A[r * LDW + c] - dotv) * is;
      lfence();
    }
  }
  __syncthreads();
  if (tid < 32) {
    const int c = tid;
    V[c * LDW + c] = rd[c];
    for (int r = c + 1; r < 32; ++r) {
      T acc = (T)0;
      for (int k = c; k < r; ++k) acc += A[r * LDW + k] * V[k * LDW + c];
      V[r * LDW + c] = -acc * rd[r];
    }
    for (int r = 0; r < 32; ++r)
      W[r * LDW + c] = (r < c) ? (T)0 : V[r * LDW + c];
  }
  __syncthreads();
}

// ---------------------------------------------------------------- S1: weights
__global__ __launch_bounds__(256) void k_weights(
    const float* __restrict__ Yraw, const float* __restrict__ kern,
    const float* __restrict__ wproj, float* __restrict__ WA,
    float* __restrict__ WB, float* __restrict__ Yt) {
  __shared__ float sk[NTAU * NSUB];
  __shared__ float sp[NSUB * NL];
  const int tid = threadIdx.x;
  if (tid < NTAU * NSUB) sk[tid] = kern[tid];
  if (tid < NSUB * NL)   sp[tid] = wproj[tid];
  __syncthreads();
  const int g = blockIdx.x * 256 + tid;            // g = (m*Tt + t)*Nn + n
  if (g >= Mb * Tt * Nn) return;
  const int n  = g % Nn;
  const int mt = g / Nn;
  const int t  = mt % Tt;
  const int m  = mt / Tt;
  const float* yr = Yraw + ((size_t)m * Nn + n) * NTF + 30 + t;
  float ya[NTAU + 1];
#pragma unroll
  for (int j = 0; j <= NTAU; ++j) ya[j] = yr[j];
  float gs[NSUB];
#pragma unroll
  for (int s = 0; s < NSUB; ++s) {
    float acc = 0.f;
#pragma unroll
    for (int j = 0; j < NTAU; ++j) acc += ya[j] * sk[(NTAU - 1 - j) * NSUB + s];
    gs[s] = (fabsf(acc) < 1e-5f) ? 0.f : acc;      // reference threshold
  }
  float w[NL];
#pragma unroll
  for (int l = 0; l < NL; ++l) {
    float acc = 0.f;
#pragma unroll
    for (int s = 0; s < NSUB; ++s) acc += gs[s] * sp[s * NL + l];
    w[l] = acc;
  }
  float4* wa4 = reinterpret_cast<float4*>(WA + (size_t)g * NL);
  wa4[0] = make_float4(w[0], w[1], w[2], w[3]);
  wa4[1] = make_float4(w[4], w[5], w[6], w[7]);
#pragma unroll
  for (int l = 0; l < NL; ++l)
    WB[(((size_t)m * NL + l) * Tt + t) * Nn + n] = w[l];
  Yt[g] = ya[NTAU];
}

// ---- S2a: M = K[S,S] (fp64) -> chol32+trtri32 -> W_S (global) --------------
__global__ __launch_bounds__(256) void k_scholM(
    const float* __restrict__ K, double* __restrict__ WS64) {
  __shared__ double A[R_ * LDW];
  __shared__ double V[R_ * LDW];
  __shared__ double rd[R_];
  const int tid = threadIdx.x;
  for (int e = tid; e < R_ * R_; e += 256) {
    const int a = e >> 5, b = e & 31;
    A[a * LDW + b] = (double)K[(size_t)PIV(a) * Tt + PIV(b)];
  }
  __syncthreads();
  chol32_trtri32<double>(A, WS64, rd, V, tid);
}

// ---- S2b: C[t][k] = sum_{j<=k} W_S[k][j]*K[p_j][t]; k==R_ zeroes pad col ---
__global__ __launch_bounds__(320) void k_cmake(
    const float* __restrict__ K, const double* __restrict__ WS64,
    float* __restrict__ Cg) {
  const int k = blockIdx.x;            // 0..32
  const int t = threadIdx.x;
  if (k == R_) {
    for (int r = t; r < CROWS; r += 320) Cg[(size_t)r * CS + R_] = 0.f;
    return;
  }
  __shared__ double wrow[R_];
  if (t < R_) wrow[t] = WS64[(size_t)k * LDW + t];
  __syncthreads();
  if (t < Tt) {
    double acc = 0.0;
    for (int j = 0; j <= k; ++j)
      acc += wrow[j] * (double)K[(size_t)PIV(j) * Tt + t];
    Cg[(size_t)t * CS + k] = (float)acc;
  }
  for (int r = Tt + t; r < CROWS; r += 320) Cg[(size_t)r * CS + k] = 0.f;
}

// ---------------- S3a: R64 = eps*I + C^T C (fp64, 4 WGs) --------------------
__global__ __launch_bounds__(256) void k_rmul(
    const float* __restrict__ Cg, double* __restrict__ R64) {
  const int e = blockIdx.x * 256 + threadIdx.x;
  if (e >= R_ * R_) return;
  const int i = e >> 5, j = e & 31;
  double acc = (i == j) ? 0.001 : 0.0;
  for (int r = 0; r < Tt; ++r)
    acc += (double)Cg[(size_t)r * CS + i] * (double)Cg[(size_t)r * CS + j];
  R64[e] = acc;
}

// --------------- S3b: chol32+trtri32 of R (fp64), W -> global ---------------
__global__ __launch_bounds__(256) void k_qchol(
    const double* __restrict__ R64, double* __restrict__ W64) {
  __shared__ double A[R_ * LDW];
  __shared__ double V[R_ * LDW];
  __shared__ double rd[R_];
  const int tid = threadIdx.x;
  for (int e = tid; e < R_ * R_; e += 256) {
    const int i = e >> 5, j = e & 31;
    A[i * LDW + j] = R64[e];
  }
  __syncthreads();
  chol32_trtri32<double>(A, W64, rd, V, tid);
}

// --------------- S3c: Q64 = W^T W (fp64, 4 WGs) -----------------------------
__global__ __launch_bounds__(256) void k_qmul(
    const double* __restrict__ W64, double* __restrict__ Qg) {
  const int e = blockIdx.x * 256 + threadIdx.x;
  if (e >= R_ * R_) return;
  const int i = e >> 5, j = e & 31;
  const int k0 = (i > j) ? i : j;
  double acc = 0.0;
  for (int k = k0; k < R_; ++k) acc += W64[k * LDW + i] * W64[k * LDW + j];
  Qg[e] = acc;
}

// ------------------------------- S4: init (dh0 = 1 + eps) -------------------
__global__ __launch_bounds__(256) void k_init(
    float* __restrict__ mu, float* __restrict__ dh) {
  const int g = blockIdx.x * 256 + threadIdx.x;
  if (g >= Mb * Tt * NL) return;
  mu[g] = 0.f;
  dh[g] = 1.0f + EPS;
}

// ---------------------------------------------------------------- I1: lambda
__global__ __launch_bounds__(256) void k_lambda(
    const float* __restrict__ WA, const float* __restrict__ mu,
    const float* __restrict__ dh, const float* __restrict__ biasp,
    float* __restrict__ lam) {
  const int g = blockIdx.x * 256 + threadIdx.x;
  if (g >= Mb * Tt * Nn) return;
  const int mt = g / Nn;
  const float b = biasp[0];
  const float4* wa = reinterpret_cast<const float4*>(WA + (size_t)g * NL);
  const float4* mp = reinterpret_cast<const float4*>(mu + (size_t)mt * NL);
  const float4* dp = reinterpret_cast<const float4*>(dh + (size_t)mt * NL);
  const float4 w0 = wa[0], w1 = wa[1];
  const float4 m0 = mp[0], m1 = mp[1];
  const float4 h0 = dp[0], h1 = dp[1];
  float e = b;
  e += w0.x * (m0.x + 0.5f * w0.x * h0.x);
  e += w0.y * (m0.y + 0.5f * w0.y * h0.y);
  e += w0.z * (m0.z + 0.5f * w0.z * h0.z);
  e += w0.w * (m0.w + 0.5f * w0.w * h0.w);
  e += w1.x * (m1.x + 0.5f * w1.x * h1.x);
  e += w1.y * (m1.y + 0.5f * w1.y * h1.y);
  e += w1.z * (m1.z + 0.5f * w1.z * h1.z);
  e += w1.w * (m1.w + 0.5f * w1.w * h1.w);
  lam[g] = expf(e);
}

// ---- I2: fused gd + pre, full-C staging (proven r14); pads zero-filled -----
__global__ __launch_bounds__(320) void k_gdpre(
    const float* __restrict__ WB, const float* __restrict__ Yt,
    const float* __restrict__ lam, const float* __restrict__ Cg,
    const double* __restrict__ Qg, const float* __restrict__ mug,
    float* __restrict__ gradb, float* __restrict__ svb,
    float* __restrict__ delb, float* __restrict__ ub) {
  const int ml = blockIdx.x;
  const int m = ml / NL, lat = ml % NL;
  const int tid = threadIdx.x;                     // 0..319
  __shared__ float  Cf[Tt * CL];                   // 40.8 KB
  __shared__ float  muv[Tt], gv[Tt], sv[Tt], sg[Tt];
  __shared__ double pv[R_], qv[R_];
  __shared__ double pB[R_ * 10];
  __shared__ float  pU[R_ * 10];
  // stage C (full) -- all threads
  for (int e = tid; e < Tt * CS; e += 320) {
    const int r = e / CS, c = e - r * CS;
    Cf[r * CL + c] = Cg[e];
  }
  // Phase A: ga, dd from WB/Yt/lam; s, delta (pad rows -> zeros)
  {
    float ga = 0.f, dd = 0.f;
    if (tid < Tt) {
      const float m_ = mug[((size_t)m * Tt + tid) * NL + lat];
      const float4* wb = reinterpret_cast<const float4*>(WB + ((size_t)ml * Tt + tid) * Nn);
      const float4* yt = reinterpret_cast<const float4*>(Yt + ((size_t)m * Tt + tid) * Nn);
      const float4* la = reinterpret_cast<const float4*>(lam + ((size_t)m * Tt + tid) * Nn);
      for (int q = 0; q < Nn / 4; ++q) {
        const float4 w = wb[q], y = yt[q], v = la[q];
        ga += w.x * (y.x - v.x) + w.y * (y.y - v.y) + w.z * (y.z - v.z) + w.w * (y.w - v.w);
        dd += w.x * w.x * v.x + w.y * w.y * v.y + w.z * w.z * v.z + w.w * w.w * v.w;
      }
      muv[tid] = m_;
      gv[tid]  = ga;
      const float s = 1.f / (1.f + EPS * dd);
      sv[tid] = s;
      svb[(size_t)ml * TP + tid]  = s;
      delb[(size_t)ml * TP + tid] = dd * s;
    } else {
      svb[(size_t)ml * TP + tid]  = 0.f;
      delb[(size_t)ml * TP + tid] = 0.f;
      gradb[(size_t)ml * TP + tid] = 0.f;
    }
  }
  __syncthreads();
  // Phase B: p = C^T mu (fp64) -- 32 cols x 10 chunks of 30 rows
  {
    const int k = tid & 31, ch = tid >> 5;
    double acc = 0.0;
    const int t0 = ch * 30;
    for (int t = t0; t < t0 + 30; ++t)
      acc += (double)Cf[t * CL + k] * (double)muv[t];
    pB[k * 10 + ch] = acc;
  }
  __syncthreads();
  if (tid < R_) {
    double a = 0.0;
    for (int ch = 0; ch < 10; ++ch) a += pB[tid * 10 + ch];
    pv[tid] = a;
  }
  __syncthreads();
  // Phase C: q = Q p (fp64)
  if (tid < R_) {
    double acc = 0.0;
    for (int j = 0; j < R_; ++j) acc += Qg[(size_t)j * R_ + tid] * pv[j];
    qv[tid] = acc;
  }
  __syncthreads();
  // Phase D: grad = g1 - 1000*(mu - C q) [fp64 inner] -- 300-thread parallel
  if (tid < Tt) {
    double cq = 0.0;
    for (int k = 0; k < R_; ++k) cq += (double)Cf[tid * CL + k] * qv[k];
    const double gnew = (double)gv[tid] - 1000.0 * ((double)muv[tid] - cq);
    gv[tid] = (float)gnew;
    sg[tid] = sv[tid] * (float)gnew;
  }
  __syncthreads();
  // Phase E: u = C^T (s*grad)
  {
    const int k = tid & 31, ch = tid >> 5;
    float acc = 0.f;
    const int t0 = ch * 30;
    for (int t = t0; t < t0 + 30; ++t) acc += Cf[t * CL + k] * sg[t];
    pU[k * 10 + ch] = acc;
  }
  __syncthreads();
  if (tid < Tt) gradb[(size_t)ml * TP + tid] = gv[tid];
  if (tid < R_) {
    float a = 0.f;
    for (int ch = 0; ch < 10; ++ch) a += pU[tid * 10 + ch];
    ub[(size_t)ml * R_ + tid] = a;
  }
}

// ---- I3a: Mhat partial = C^T diag(delta) C over a 160-row t-half -----------
// 256 WGs = (system, half). 2x2 tiles, 16x16 grid = 256 threads, all live.
__global__ __launch_bounds__(256) void k_mhat(
    const float* __restrict__ Cg, const float* __restrict__ delb,
    float* __restrict__ Mh2) {
  const int s = blockIdx.x >> 1, th = blockIdx.x & 1;
  const int tid = threadIdx.x;
  __shared__ float Cf[160 * CL];      // 21.8 KB
  __shared__ float dl[160];
  {
    const float* Cs = Cg + (size_t)(th * 160) * CS;
    for (int e = tid; e < 160 * CS; e += 256) {
      const int r = e / CS, c = e - r * CS;
      Cf[r * CL + c] = Cs[e];
    }
    for (int e = tid; e < 160; e += 256)
      dl[e] = delb[(size_t)s * TP + th * 160 + e];
  }
  __syncthreads();
  const int i0 = (tid >> 4) * 2, j0 = (tid & 15) * 2;
  float a00 = 0.f, a01 = 0.f, a10 = 0.f, a11 = 0.f;
  for (int t = 0; t < 160; ++t) {
    const float w = dl[t];
    const float2 u = *reinterpret_cast<const float2*>(&Cf[t * CL + i0]);
    const float2 v = *reinterpret_cast<const float2*>(&Cf[t * CL + j0]);
    const float u0 = u.x * w, u1 = u.y * w;
    a00 += u0 * v.x; a01 += u0 * v.y;
    a10 += u1 * v.x; a11 += u1 * v.y;
  }
  float* base = Mh2 + (size_t)blockIdx.x * (R_ * R_);
  base[(i0    ) * R_ + j0    ] = a00;
  base[(i0    ) * R_ + j0 + 1] = a01;
  base[(i0 + 1) * R_ + j0    ] = a10;
  base[(i0 + 1) * R_ + j0 + 1] = a11;
}

// ---- I3b: Mhat = I + sum halves; Newton-Schulz P = Mhat^-1; y = P u --------
// 128 WGs. lambda_min(Mhat) >= 1 and X0 = I/Gershgorin => unconditional
// quadratic convergence; NSIT=12 reaches fp32 floor for G <= 250.
__global__ __launch_bounds__(256) void k_ns(
    const float* __restrict__ Mh2, const float* __restrict__ ub,
    float* __restrict__ Pg, float* __restrict__ yb) {
  const int s = blockIdx.x;
  const int tid = threadIdx.x;
  __shared__ float M[R_ * LDW];
  __shared__ float Xa[R_ * LDW];
  __shared__ float Xb[R_ * LDW];
  __shared__ float T[R_ * LDW];
  __shared__ float uv[R_];
  __shared__ float red[R_ + 2];
  const float* M0 = Mh2 + (size_t)(2 * s) * (R_ * R_);
  const float* M1 = Mh2 + (size_t)(2 * s + 1) * (R_ * R_);
  for (int e = tid; e < R_ * R_; e += 256) {
    const int i = e >> 5, j = e & 31;
    M[i * LDW + j] = M0[e] + M1[e] + ((i == j) ? 1.f : 0.f);
  }
  if (tid < R_) uv[tid] = ub[(size_t)s * R_ + tid];
  __syncthreads();
  // Gershgorin bound G = max_i sum_j |M_ij|  (>= lambda_max)
  if (tid < R_) {
    float rs = 0.f;
    for (int j = 0; j < R_; ++j) rs += fabsf(M[tid * LDW + j]);
    red[tid] = rs;
  }
  __syncthreads();
  if (tid == 0) {
    float g = 0.f;
    for (int i = 0; i < R_; ++i) g = fmaxf(g, red[i]);
    red[R_] = 1.f / g;
  }
  __syncthreads();
  const float c0 = red[R_];
  for (int e = tid; e < R_ * R_; e += 256) {
    const int i = e >> 5, j = e & 31;
    Xa[i * LDW + j] = (i == j) ? c0 : 0.f;
  }
  __syncthreads();
  float* Xc = Xa;
  float* Xn = Xb;
  const int i = tid >> 3, j0 = (tid & 7) * 4;
  for (int it = 0; it < NSIT; ++it) {
    // T = M * Xc
    {
      float a0 = 0.f, a1 = 0.f, a2 = 0.f, a3 = 0.f;
      for (int k = 0; k < R_; ++k) {
        const float mv = M[i * LDW + k];
        const float* xr = &Xc[k * LDW + j0];
        a0 += mv * xr[0]; a1 += mv * xr[1]; a2 += mv * xr[2]; a3 += mv * xr[3];
      }
      float* tr = &T[i * LDW + j0];
      tr[0] = a0; tr[1] = a1; tr[2] = a2; tr[3] = a3;
    }
    __syncthreads();
    // Xn = 2*Xc - Xc*T
    {
      float a0 = 0.f, a1 = 0.f, a2 = 0.f, a3 = 0.f;
      for (int k = 0; k < R_; ++k) {
        const float xv = Xc[i * LDW + k];
        const float* tr = &T[k * LDW + j0];
        a0 += xv * tr[0]; a1 += xv * tr[1]; a2 += xv * tr[2]; a3 += xv * tr[3];
      }
      const float* xc = &Xc[i * LDW + j0];
      float* xn = &Xn[i * LDW + j0];
      xn[0] = 2.f * xc[0] - a0; xn[1] = 2.f * xc[1] - a1;
      xn[2] = 2.f * xc[2] - a2; xn[3] = 2.f * xc[3] - a3;
    }
    __syncthreads();
    float* tmp = Xc; Xc = Xn; Xn = tmp;
  }
  // y = P u ; P -> global
  if (tid < R_) {
    float acc = 0.f;
    for (int j = 0; j < R_; ++j) acc += Xc[tid * LDW + j] * uv[j];
    yb[(size_t)s * R_ + tid] = acc;
  }
  float* Po = Pg + (size_t)s * R_ * LDW;
  for (int e = tid; e < R_ * LDW; e += 256) Po[e] = Xc[e];
}

// ---- I4: X = C P -> q_t = sum_j X_tj c_tj -> dh, mu update -----------------
// 512 WGs = (system, t-block of 96). 32 t-groups x 8 j-groups = 256 threads.
__global__ __launch_bounds__(256) void k_fin(
    const float* __restrict__ Cg, const float* __restrict__ Pg,
    const float* __restrict__ yb, const float* __restrict__ gradb,
    const float* __restrict__ svb, float* __restrict__ mug,
    float* __restrict__ dhg) {
  const int bid = blockIdx.x;
  const int ml = bid >> 2, blk = bid & 3;
  const int mt = ml / NL, lat = ml % NL;
  const int tid = threadIdx.x;
  __shared__ float Pf[R_ * CL];       // 32 x 34
  __shared__ float Cb[96 * CL];       // 96 x 34
  __shared__ float red[96 * 9];
  __shared__ float yv[R_];
  {
    const float* Ps = Pg + (size_t)ml * R_ * LDW;
    for (int e = tid; e < R_ * LDW; e += 256) {
      const int r = e / LDW, c = e - r * LDW;
      Pf[r * CL + c] = Ps[e];
    }
    const float* Cs = Cg + (size_t)(blk * 96) * CS;
    for (int e = tid; e < 96 * CS; e += 256) {
      const int r = e / CS, c = e - r * CS;
      Cb[r * CL + c] = Cs[e];
    }
    if (tid < R_) yv[tid] = yb[(size_t)ml * R_ + tid];
  }
  __syncthreads();
  const int tg = tid & 31, jg = tid >> 5;          // 32 x 8
  const int t0 = tg * 3, j0 = jg * 4;
  float acc[3][4];
#pragma unroll
  for (int r = 0; r < 3; ++r)
#pragma unroll
    for (int c = 0; c < 4; ++c) acc[r][c] = 0.f;
  for (int k = 0; k < R_; k += 2) {
    float2 cv[3], wv[4];
#pragma unroll
    for (int r = 0; r < 3; ++r)
      cv[r] = *reinterpret_cast<const float2*>(&Cb[(t0 + r) * CL + k]);
#pragma unroll
    for (int c = 0; c < 4; ++c)
      wv[c] = *reinterpret_cast<const float2*>(&Pf[(j0 + c) * CL + k]);
#pragma unroll
    for (int r = 0; r < 3; ++r)
#pragma unroll
      for (int c = 0; c < 4; ++c)
        acc[r][c] += cv[r].x * wv[c].x + cv[r].y * wv[c].y;
  }
  // q partial: sum_c X[t][j0+c] * C[t][j0+c]
#pragma unroll
  for (int r = 0; r < 3; ++r) {
    float sjp = 0.f;
#pragma unroll
    for (int c = 0; c < 4; ++c)
      sjp += acc[r][c] * Cb[(t0 + r) * CL + (j0 + c)];
    red[(t0 + r) * 9 + jg] = sjp;
  }
  __syncthreads();
  if (tid < 96) {
    const int t = blk * 96 + tid;
    float S = 0.f;
#pragma unroll
    for (int q = 0; q < 8; ++q) S += red[tid * 9 + q];
    float cy = 0.f;
    for (int k = 0; k < R_; ++k) cy += Cb[tid * CL + k] * yv[k];
    if (t < Tt) {
      const float s = svb[(size_t)ml * TP + t];
      const float g = gradb[(size_t)ml * TP + t];
      const size_t idx = ((size_t)mt * Tt + t) * NL + lat;
      const float x = EPS * s * g + s * cy;
      mug[idx] = mug[idx] + 0.5f * x;               // LR = 0.5
      dhg[idx] = -(EPS * s + s * s * S);
    }
  }
}

// ---------------------------------------------------------------- F1: output
__global__ __launch_bounds__(256) void k_out(
    const float* __restrict__ mu, float* __restrict__ out) {
  const int g = blockIdx.x * 256 + threadIdx.x;   // g = (m*NL + l)*Tt + t
  if (g >= Mb * NL * Tt) return;
  const int t = g % Tt;
  const int ml = g / Tt;
  const int m = ml / NL, l = ml % NL;
  out[g] = mu[((size_t)m * Tt + t) * NL + l];
}

// ------------------------------------------------------------------- launcher
extern "C" void kernel_launch(void* const* d_in, const int* in_sizes, int n_in,
                              void* d_out, int out_size, void* d_ws, size_t ws_size,
                              hipStream_t stream) {
  (void)in_sizes; (void)n_in; (void)out_size;
  const float* Yraw  = (const float*)d_in[0];
  const float* kern  = (const float*)d_in[1];
  const float* wproj = (const float*)d_in[2];
  const float* K     = (const float*)d_in[3];
  const float* biasp = (const float*)d_in[4];
  float* out = (float*)d_out;

  char* base = (char*)d_ws;
  size_t off = 0;
  auto alloc = [&](size_t bytes) -> void* {
    void* p = base + off;
    off += (bytes + 511) & ~(size_t)511;
    return p;
  };
  float*  WA    = (float*) alloc((size_t)Mb * Tt * Nn * NL * 4);
  float*  WB    = (float*) alloc((size_t)Mb * Tt * Nn * NL * 4);
  float*  Yt    = (float*) alloc((size_t)Mb * Tt * Nn * 4);
  float*  lam   = (float*) alloc((size_t)Mb * Tt * Nn * 4);
  float*  mu    = (float*) alloc((size_t)Mb * Tt * NL * 4);
  float*  dh    = (float*) alloc((size_t)Mb * Tt * NL * 4);
  float*  gradb = (float*) alloc((size_t)ML * TP * 4);
  float*  svb   = (float*) alloc((size_t)ML * TP * 4);
  float*  delb  = (float*) alloc((size_t)ML * TP * 4);
  float*  ub    = (float*) alloc((size_t)ML * R_ * 4);
  float*  yb    = (float*) alloc((size_t)ML * R_ * 4);
  float*  Cg    = (float*) alloc((size_t)CROWS * CS * 4);
  double* WS64  = (double*)alloc((size_t)R_ * LDW * 8);
  double* W64   = (double*)alloc((size_t)R_ * LDW * 8);
  double* R64   = (double*)alloc((size_t)R_ * R_ * 8);
  double* Q64   = (double*)alloc((size_t)R_ * R_ * 8);
  float*  Mh2   = (float*) alloc((size_t)ML * 2 * R_ * R_ * 4);
  float*  Pg    = (float*) alloc((size_t)ML * R_ * LDW * 4);
  if (off > ws_size) return;

  const int gMTN = (Mb * Tt * Nn) / 256;       // 1800
  const int gMTL = (Mb * Tt * NL + 255) / 256; // 150
  const int gRR  = (R_ * R_ + 255) / 256;      // 4

  k_weights<<<gMTN, 256, 0, stream>>>(Yraw, kern, wproj, WA, WB, Yt);
  k_scholM<<<1, 256, 0, stream>>>(K, WS64);
  k_cmake<<<R_ + 1, 320, 0, stream>>>(K, WS64, Cg);
  k_rmul<<<gRR, 256, 0, stream>>>(Cg, R64);
  k_qchol<<<1, 256, 0, stream>>>(R64, W64);
  k_qmul<<<gRR, 256, 0, stream>>>(W64, Q64);
  k_init<<<gMTL, 256, 0, stream>>>(mu, dh);

  for (int it = 0; it < 5; ++it) {
    k_lambda<<<gMTN, 256, 0, stream>>>(WA, mu, dh, biasp, lam);
    k_gdpre<<<ML, 320, 0, stream>>>(WB, Yt, lam, Cg, Q64, mu,
                                    gradb, svb, delb, ub);
    k_mhat<<<ML * 2, 256, 0, stream>>>(Cg, delb, Mh2);
    k_ns<<<ML, 256, 0, stream>>>(Mh2, ub, Pg, yb);
    k_fin<<<ML * 4, 256, 0, stream>>>(Cg, Pg, yb, gradb, svb, mu, dh);
  }
  k_out<<<gMTL, 256, 0, stream>>>(mu, out);
}

// Round 16
// 338.967 us; speedup vs baseline: 4.9519x; 1.2873x over previous
//
// FCGPFA variational iteration for MI355X (gfx950). Round 16: iteration loop
// collapsed to TWO dispatches: k_gd2 (lambda fused into gradient -- computed
// ONCE per (m,t,n), all 8 latents accumulated; kills k_lambda/lam/WB) and
// k_sys2 (pre + Mhat + Newton-Schulz + y + fin in one 128-WG kernel, 68KB LDS
// -> 2 WGs/CU; Mh2/Pg/ub/yb/svb/delb/gradb round-trips eliminated).
// Dispatches 33 -> 18. All phases are r14/r15-proven patterns.
//
#include <hip/hip_runtime.h>
#include <math.h>

namespace {
constexpr int Mb   = 16;
constexpr int Nn   = 96;
constexpr int NTF  = 350;
constexpr int Tt   = 300;
constexpr int NSUB = 8;
constexpr int NTAU = 20;
constexpr int NL   = 8;
constexpr int ML   = Mb * NL;   // 128 systems
constexpr int R_   = 32;        // low-rank dimension
constexpr int CS   = 33;        // C global row stride
constexpr int CL   = 34;        // C LDS row stride
constexpr int LDW  = 33;        // P/M row stride
constexpr int TP   = 320;
constexpr int CROWS= 384;
constexpr int NSIT = 12;        // Newton-Schulz iterations (fp32 floor)
constexpr float EPS = 0.001f;
}

__device__ __forceinline__ int PIV(int k) { return (600 * k + 300) >> 6; }

__device__ __forceinline__ float  sqrt_(float x)  { return sqrtf(x); }
__device__ __forceinline__ double sqrt_(double x) { return sqrt(x); }

__device__ __forceinline__ void lfence() {
  asm volatile("s_waitcnt lgkmcnt(0)" ::: "memory");
}

// ------------- 32x32 Cholesky (lower) + W = L^-1 (setup only, proven r14) ---
template <typename T>
__device__ void chol32_trtri32(T* A, T* W, T* rd, T* V, int tid) {
  if (tid < 32) {
    const int r = tid;
    for (int c = 0; c < 32; ++c) {
      T dotp = (T)0, dotv = (T)0;
      for (int k = 0; k < c; ++k) {
        const T bc = A[c * LDW + k];
        dotp += bc * bc;
        dotv += A[r * LDW + k] * bc;
      }
      const T pivot = A[c * LDW + c] - dotp;
      T s, is;
      if (pivot > (T)1e-12) { s = sqrt_(pivot); is = (T)1 / s; }
      else                  { s = (T)0;         is = (T)0; }
      if (r == c)      { A[c * LDW + c] = s; rd[c] = is; }
      else if (r > c)  A[r * LDW + c] = (A[r * LDW + c] - dotv) * is;
      lfence();
    }
  }
  __syncthreads();
  if (tid < 32) {
    const int c = tid;
    V[c * LDW + c] = rd[c];
    for (int r = c + 1; r < 32; ++r) {
      T acc = (T)0;
      for (int k = c; k < r; ++k) acc += A[r * LDW + k] * V[k * LDW + c];
      V[r * LDW + c] = -acc * rd[r];
    }
    for (int r = 0; r < 32; ++r)
      W[r * LDW + c] = (r < c) ? (T)0 : V[r * LDW + c];
  }
  __syncthreads();
}

// ---------------------------------------------------------------- S1: weights
__global__ __launch_bounds__(256) void k_weights(
    const float* __restrict__ Yraw, const float* __restrict__ kern,
    const float* __restrict__ wproj, float* __restrict__ WA,
    float* __restrict__ Yt) {
  __shared__ float sk[NTAU * NSUB];
  __shared__ float sp[NSUB * NL];
  const int tid = threadIdx.x;
  if (tid < NTAU * NSUB) sk[tid] = kern[tid];
  if (tid < NSUB * NL)   sp[tid] = wproj[tid];
  __syncthreads();
  const int g = blockIdx.x * 256 + tid;            // g = (m*Tt + t)*Nn + n
  if (g >= Mb * Tt * Nn) return;
  const int n  = g % Nn;
  const int mt = g / Nn;
  const int t  = mt % Tt;
  const int m  = mt / Tt;
  const float* yr = Yraw + ((size_t)m * Nn + n) * NTF + 30 + t;
  float ya[NTAU + 1];
#pragma unroll
  for (int j = 0; j <= NTAU; ++j) ya[j] = yr[j];
  float gs[NSUB];
#pragma unroll
  for (int s = 0; s < NSUB; ++s) {
    float acc = 0.f;
#pragma unroll
    for (int j = 0; j < NTAU; ++j) acc += ya[j] * sk[(NTAU - 1 - j) * NSUB + s];
    gs[s] = (fabsf(acc) < 1e-5f) ? 0.f : acc;      // reference threshold
  }
  float w[NL];
#pragma unroll
  for (int l = 0; l < NL; ++l) {
    float acc = 0.f;
#pragma unroll
    for (int s = 0; s < NSUB; ++s) acc += gs[s] * sp[s * NL + l];
    w[l] = acc;
  }
  float4* wa4 = reinterpret_cast<float4*>(WA + (size_t)g * NL);
  wa4[0] = make_float4(w[0], w[1], w[2], w[3]);
  wa4[1] = make_float4(w[4], w[5], w[6], w[7]);
  Yt[g] = ya[NTAU];
}

// ---- S2a: M = K[S,S] (fp64) -> chol32+trtri32 -> W_S (global) --------------
__global__ __launch_bounds__(256) void k_scholM(
    const float* __restrict__ K, double* __restrict__ WS64) {
  __shared__ double A[R_ * LDW];
  __shared__ double V[R_ * LDW];
  __shared__ double rd[R_];
  const int tid = threadIdx.x;
  for (int e = tid; e < R_ * R_; e += 256) {
    const int a = e >> 5, b = e & 31;
    A[a * LDW + b] = (double)K[(size_t)PIV(a) * Tt + PIV(b)];
  }
  __syncthreads();
  chol32_trtri32<double>(A, WS64, rd, V, tid);
}

// ---- S2b: C[t][k] = sum_{j<=k} W_S[k][j]*K[p_j][t]; k==R_ zeroes pad col ---
__global__ __launch_bounds__(320) void k_cmake(
    const float* __restrict__ K, const double* __restrict__ WS64,
    float* __restrict__ Cg) {
  const int k = blockIdx.x;            // 0..32
  const int t = threadIdx.x;
  if (k == R_) {
    for (int r = t; r < CROWS; r += 320) Cg[(size_t)r * CS + R_] = 0.f;
    return;
  }
  __shared__ double wrow[R_];
  if (t < R_) wrow[t] = WS64[(size_t)k * LDW + t];
  __syncthreads();
  if (t < Tt) {
    double acc = 0.0;
    for (int j = 0; j <= k; ++j)
      acc += wrow[j] * (double)K[(size_t)PIV(j) * Tt + t];
    Cg[(size_t)t * CS + k] = (float)acc;
  }
  for (int r = Tt + t; r < CROWS; r += 320) Cg[(size_t)r * CS + k] = 0.f;
}

// ---------------- S3a: R64 = eps*I + C^T C (fp64, 4 WGs) --------------------
__global__ __launch_bounds__(256) void k_rmul(
    const float* __restrict__ Cg, double* __restrict__ R64) {
  const int e = blockIdx.x * 256 + threadIdx.x;
  if (e >= R_ * R_) return;
  const int i = e >> 5, j = e & 31;
  double acc = (i == j) ? 0.001 : 0.0;
  for (int r = 0; r < Tt; ++r)
    acc += (double)Cg[(size_t)r * CS + i] * (double)Cg[(size_t)r * CS + j];
  R64[e] = acc;
}

// --------------- S3b: chol32+trtri32 of R (fp64), W -> global ---------------
__global__ __launch_bounds__(256) void k_qchol(
    const double* __restrict__ R64, double* __restrict__ W64) {
  __shared__ double A[R_ * LDW];
  __shared__ double V[R_ * LDW];
  __shared__ double rd[R_];
  const int tid = threadIdx.x;
  for (int e = tid; e < R_ * R_; e += 256) {
    const int i = e >> 5, j = e & 31;
    A[i * LDW + j] = R64[e];
  }
  __syncthreads();
  chol32_trtri32<double>(A, W64, rd, V, tid);
}

// --------------- S3c: Q64 = W^T W (fp64, 4 WGs) -----------------------------
__global__ __launch_bounds__(256) void k_qmul(
    const double* __restrict__ W64, double* __restrict__ Qg) {
  const int e = blockIdx.x * 256 + threadIdx.x;
  if (e >= R_ * R_) return;
  const int i = e >> 5, j = e & 31;
  const int k0 = (i > j) ? i : j;
  double acc = 0.0;
  for (int k = k0; k < R_; ++k) acc += W64[k * LDW + i] * W64[k * LDW + j];
  Qg[e] = acc;
}

// ------------------------------- S4: init (dh0 = 1 + eps) -------------------
__global__ __launch_bounds__(256) void k_init(
    float* __restrict__ mu, float* __restrict__ dh) {
  const int g = blockIdx.x * 256 + threadIdx.x;
  if (g >= Mb * Tt * NL) return;
  mu[g] = 0.f;
  dh[g] = 1.0f + EPS;
}

// ---- I1: fused lambda + gradient: one WG per (m, 30-t chunk) ---------------
// lambda computed ONCE per (m,t,n); all 8 latents accumulated in registers.
// 240 active threads = 30 t x 8 n-groups (n = nq + 8i, i<12: coalesced-ish).
__global__ __launch_bounds__(256) void k_gd2(
    const float* __restrict__ WA, const float* __restrict__ Yt,
    const float* __restrict__ mug, const float* __restrict__ dhg,
    const float* __restrict__ biasp, float* __restrict__ g1,
    float* __restrict__ dvec) {
  const int wg = blockIdx.x;           // 0..159
  const int m = wg / 10, ch = wg - m * 10;
  const int t0 = ch * 30;
  const int tid = threadIdx.x;
  __shared__ float pg[30 * 8 * 8];     // [tl][l][nq]
  __shared__ float pd[30 * 8 * 8];
  if (tid < 240) {
    const int tl = tid >> 3, nq = tid & 7;
    const int t = t0 + tl;
    const float b = biasp[0];
    const float4* mp = reinterpret_cast<const float4*>(mug + ((size_t)m * Tt + t) * NL);
    const float4* dp = reinterpret_cast<const float4*>(dhg + ((size_t)m * Tt + t) * NL);
    const float4 m0 = mp[0], m1 = mp[1], h0 = dp[0], h1 = dp[1];
    const float mv[8] = {m0.x, m0.y, m0.z, m0.w, m1.x, m1.y, m1.z, m1.w};
    const float hv[8] = {0.5f * h0.x, 0.5f * h0.y, 0.5f * h0.z, 0.5f * h0.w,
                         0.5f * h1.x, 0.5f * h1.y, 0.5f * h1.z, 0.5f * h1.w};
    float ga[8], dd[8];
#pragma unroll
    for (int l = 0; l < 8; ++l) { ga[l] = 0.f; dd[l] = 0.f; }
    const float* war = WA + ((size_t)m * Tt + t) * Nn * NL;
    const float* ytr = Yt + ((size_t)m * Tt + t) * Nn;
    for (int i = 0; i < 12; ++i) {
      const int n = nq + 8 * i;
      const float4* w4 = reinterpret_cast<const float4*>(war + n * NL);
      const float4 w0 = w4[0], w1 = w4[1];
      const float wv[8] = {w0.x, w0.y, w0.z, w0.w, w1.x, w1.y, w1.z, w1.w};
      float e = b;
#pragma unroll
      for (int l = 0; l < 8; ++l) e += wv[l] * (mv[l] + wv[l] * hv[l]);
      const float lamn = expf(e);
      const float dy = ytr[n] - lamn;
#pragma unroll
      for (int l = 0; l < 8; ++l) {
        ga[l] += wv[l] * dy;
        dd[l] += wv[l] * wv[l] * lamn;
      }
    }
#pragma unroll
    for (int l = 0; l < 8; ++l) {
      pg[(tl * 8 + l) * 8 + nq] = ga[l];
      pd[(tl * 8 + l) * 8 + nq] = dd[l];
    }
  }
  __syncthreads();
  if (tid < 240) {
    const int tl = tid >> 3, l = tid & 7;
    float sg_ = 0.f, sd_ = 0.f;
#pragma unroll
    for (int nq = 0; nq < 8; ++nq) {
      sg_ += pg[(tl * 8 + l) * 8 + nq];
      sd_ += pd[(tl * 8 + l) * 8 + nq];
    }
    const size_t idx = (size_t)(m * NL + l) * TP + (t0 + tl);
    g1[idx]   = sg_;
    dvec[idx] = sd_;
  }
}

// ---- I2: fused per-system solve: pre + Mhat + Newton-Schulz + y + fin ------
// 128 WGs x 320 threads, ~68KB LDS -> 2 WGs/CU. All phases proven r14/r15.
__global__ __launch_bounds__(320) void k_sys2(
    const float* __restrict__ Cg, const double* __restrict__ Qg,
    const float* __restrict__ g1, const float* __restrict__ dvec,
    float* __restrict__ mug, float* __restrict__ dhg) {
  const int ml = blockIdx.x;
  const int mt = ml / NL, lat = ml % NL;
  const int tid = threadIdx.x;                     // 0..319
  __shared__ float  Cf[Tt * CL];                   // 40.8 KB
  __shared__ float  M[R_ * LDW];
  __shared__ float  Xa[R_ * LDW];
  __shared__ float  Xb[R_ * LDW];
  __shared__ float  T[R_ * LDW];
  __shared__ float  muv[Tt], gv[Tt], sv[Tt], dl[Tt], sg[Tt];
  __shared__ double pv[R_], qv[R_];
  __shared__ double pB[R_ * 10];
  __shared__ float  pU[R_ * 10];
  __shared__ float  uv[R_], yv[R_];
  __shared__ float  red[R_ + 2];
  // P1: stage C + vectors
  for (int e = tid; e < Tt * CS; e += 320) {
    const int r = e / CS, c = e - r * CS;
    Cf[r * CL + c] = Cg[e];
  }
  if (tid < Tt) {
    const float m_ = mug[((size_t)mt * Tt + tid) * NL + lat];
    const float g_ = g1[(size_t)ml * TP + tid];
    const float d_ = dvec[(size_t)ml * TP + tid];
    muv[tid] = m_; gv[tid] = g_;
    const float s = 1.f / (1.f + EPS * d_);
    sv[tid] = s;
    dl[tid] = d_ * s;
  }
  __syncthreads();
  // P2: p = C^T mu (fp64) -- 32 cols x 10 chunks of 30 rows (proven r14)
  {
    const int k = tid & 31, ch = tid >> 5;
    double acc = 0.0;
    const int ta = ch * 30;
    for (int t = ta; t < ta + 30; ++t)
      acc += (double)Cf[t * CL + k] * (double)muv[t];
    pB[k * 10 + ch] = acc;
  }
  __syncthreads();
  if (tid < R_) {
    double a = 0.0;
    for (int ch = 0; ch < 10; ++ch) a += pB[tid * 10 + ch];
    pv[tid] = a;
  }
  __syncthreads();
  // P3: q = Q p (fp64)
  if (tid < R_) {
    double acc = 0.0;
    for (int j = 0; j < R_; ++j) acc += Qg[(size_t)j * R_ + tid] * pv[j];
    qv[tid] = acc;
  }
  __syncthreads();
  // P4: grad = g1 - 1000*(mu - C q) [fp64 inner]
  if (tid < Tt) {
    double cq = 0.0;
    for (int k = 0; k < R_; ++k) cq += (double)Cf[tid * CL + k] * qv[k];
    const double gnew = (double)gv[tid] - 1000.0 * ((double)muv[tid] - cq);
    gv[tid] = (float)gnew;
    sg[tid] = sv[tid] * (float)gnew;
  }
  __syncthreads();
  // P5: u = C^T (s*grad)
  {
    const int k = tid & 31, ch = tid >> 5;
    float acc = 0.f;
    const int ta = ch * 30;
    for (int t = ta; t < ta + 30; ++t) acc += Cf[t * CL + k] * sg[t];
    pU[k * 10 + ch] = acc;
  }
  __syncthreads();
  if (tid < R_) {
    float a = 0.f;
    for (int ch = 0; ch < 10; ++ch) a += pU[tid * 10 + ch];
    uv[tid] = a;
  }
  // P6: Mhat = I + C^T diag(dl) C -- 2x2 tiles, 16x16 grid (tid<256), k=300
  if (tid < 256) {
    const int i0 = (tid >> 4) * 2, j0 = (tid & 15) * 2;
    float a00 = 0.f, a01 = 0.f, a10 = 0.f, a11 = 0.f;
    for (int t = 0; t < Tt; ++t) {
      const float w = dl[t];
      const float2 u = *reinterpret_cast<const float2*>(&Cf[t * CL + i0]);
      const float2 v = *reinterpret_cast<const float2*>(&Cf[t * CL + j0]);
      const float u0 = u.x * w, u1 = u.y * w;
      a00 += u0 * v.x; a01 += u0 * v.y;
      a10 += u1 * v.x; a11 += u1 * v.y;
    }
    M[(i0    ) * LDW + j0    ] = a00 + ((i0     == j0    ) ? 1.f : 0.f);
    M[(i0    ) * LDW + j0 + 1] = a01 + ((i0     == j0 + 1) ? 1.f : 0.f);
    M[(i0 + 1) * LDW + j0    ] = a10 + ((i0 + 1 == j0    ) ? 1.f : 0.f);
    M[(i0 + 1) * LDW + j0 + 1] = a11 + ((i0 + 1 == j0 + 1) ? 1.f : 0.f);
  }
  __syncthreads();
  // P7: Gershgorin bound, X0 = I/G
  if (tid < R_) {
    float rs = 0.f;
    for (int j = 0; j < R_; ++j) rs += fabsf(M[tid * LDW + j]);
    red[tid] = rs;
  }
  __syncthreads();
  if (tid == 0) {
    float g = 0.f;
    for (int i = 0; i < R_; ++i) g = fmaxf(g, red[i]);
    red[R_] = 1.f / g;
  }
  __syncthreads();
  {
    const float c0 = red[R_];
    for (int e = tid; e < R_ * R_; e += 320) {
      const int i = e >> 5, j = e & 31;
      Xa[i * LDW + j] = (i == j) ? c0 : 0.f;
    }
  }
  __syncthreads();
  // P8: Newton-Schulz (proven r15), tid<256: i=tid>>3, j0=(tid&7)*4
  float* Xc = Xa;
  float* Xn = Xb;
  {
    const int i = tid >> 3, j0 = (tid & 7) * 4;
    for (int it = 0; it < NSIT; ++it) {
      if (tid < 256) {
        float a0 = 0.f, a1 = 0.f, a2 = 0.f, a3 = 0.f;
        for (int k = 0; k < R_; ++k) {
          const float mv = M[i * LDW + k];
          const float* xr = &Xc[k * LDW + j0];
          a0 += mv * xr[0]; a1 += mv * xr[1]; a2 += mv * xr[2]; a3 += mv * xr[3];
        }
        float* tr = &T[i * LDW + j0];
        tr[0] = a0; tr[1] = a1; tr[2] = a2; tr[3] = a3;
      }
      __syncthreads();
      if (tid < 256) {
        float a0 = 0.f, a1 = 0.f, a2 = 0.f, a3 = 0.f;
        for (int k = 0; k < R_; ++k) {
          const float xv = Xc[i * LDW + k];
          const float* tr = &T[k * LDW + j0];
          a0 += xv * tr[0]; a1 += xv * tr[1]; a2 += xv * tr[2]; a3 += xv * tr[3];
        }
        const float* xc = &Xc[i * LDW + j0];
        float* xn = &Xn[i * LDW + j0];
        xn[0] = 2.f * xc[0] - a0; xn[1] = 2.f * xc[1] - a1;
        xn[2] = 2.f * xc[2] - a2; xn[3] = 2.f * xc[3] - a3;
      }
      __syncthreads();
      float* tmp = Xc; Xc = Xn; Xn = tmp;
    }
  }
  // P9: y = P u
  if (tid < R_) {
    float acc = 0.f;
    for (int j = 0; j < R_; ++j) acc += Xc[tid * LDW + j] * uv[j];
    yv[tid] = acc;
  }
  __syncthreads();
  // P10: per-t: q_t = c_t^T P c_t (row of X=CP dotted with c_t), cy = c_t.y;
  //      mu += 0.5*(eps*s*g + s*cy); dh = -(eps*s + s^2*q_t)
  if (tid < Tt) {
    const int t = tid;
    float cr[R_];
#pragma unroll
    for (int k = 0; k < R_; ++k) cr[k] = Cf[t * CL + k];
    float q = 0.f, cy = 0.f;
    for (int j = 0; j < R_; ++j) {
      float x = 0.f;
#pragma unroll
      for (int k = 0; k < R_; ++k) x += cr[k] * Xc[k * LDW + j];
      q += x * cr[j];
    }
#pragma unroll
    for (int k = 0; k < R_; ++k) cy += cr[k] * yv[k];
    const float s = sv[t];
    const size_t idx = ((size_t)mt * Tt + t) * NL + lat;
    const float x2 = EPS * s * gv[t] + s * cy;
    mug[idx] = muv[t] + 0.5f * x2;                  // LR = 0.5
    dhg[idx] = -(EPS * s + s * s * q);
  }
}

// ---------------------------------------------------------------- F1: output
__global__ __launch_bounds__(256) void k_out(
    const float* __restrict__ mu, float* __restrict__ out) {
  const int g = blockIdx.x * 256 + threadIdx.x;   // g = (m*NL + l)*Tt + t
  if (g >= Mb * NL * Tt) return;
  const int t = g % Tt;
  const int ml = g / Tt;
  const int m = ml / NL, l = ml % NL;
  out[g] = mu[((size_t)m * Tt + t) * NL + l];
}

// ------------------------------------------------------------------- launcher
extern "C" void kernel_launch(void* const* d_in, const int* in_sizes, int n_in,
                              void* d_out, int out_size, void* d_ws, size_t ws_size,
                              hipStream_t stream) {
  (void)in_sizes; (void)n_in; (void)out_size;
  const float* Yraw  = (const float*)d_in[0];
  const float* kern  = (const float*)d_in[1];
  const float* wproj = (const float*)d_in[2];
  const float* K     = (const float*)d_in[3];
  const float* biasp = (const float*)d_in[4];
  float* out = (float*)d_out;

  char* base = (char*)d_ws;
  size_t off = 0;
  auto alloc = [&](size_t bytes) -> void* {
    void* p = base + off;
    off += (bytes + 511) & ~(size_t)511;
    return p;
  };
  float*  WA   = (float*) alloc((size_t)Mb * Tt * Nn * NL * 4);
  float*  Yt   = (float*) alloc((size_t)Mb * Tt * Nn * 4);
  float*  mu   = (float*) alloc((size_t)Mb * Tt * NL * 4);
  float*  dh   = (float*) alloc((size_t)Mb * Tt * NL * 4);
  float*  g1   = (float*) alloc((size_t)ML * TP * 4);
  float*  dvec = (float*) alloc((size_t)ML * TP * 4);
  float*  Cg   = (float*) alloc((size_t)CROWS * CS * 4);
  double* WS64 = (double*)alloc((size_t)R_ * LDW * 8);
  double* W64  = (double*)alloc((size_t)R_ * LDW * 8);
  double* R64  = (double*)alloc((size_t)R_ * R_ * 8);
  double* Q64  = (double*)alloc((size_t)R_ * R_ * 8);
  if (off > ws_size) return;

  const int gMTN = (Mb * Tt * Nn) / 256;       // 1800
  const int gMTL = (Mb * Tt * NL + 255) / 256; // 150
  const int gRR  = (R_ * R_ + 255) / 256;      // 4

  k_weights<<<gMTN, 256, 0, stream>>>(Yraw, kern, wproj, WA, Yt);
  k_scholM<<<1, 256, 0, stream>>>(K, WS64);
  k_cmake<<<R_ + 1, 320, 0, stream>>>(K, WS64, Cg);
  k_rmul<<<gRR, 256, 0, stream>>>(Cg, R64);
  k_qchol<<<1, 256, 0, stream>>>(R64, W64);
  k_qmul<<<gRR, 256, 0, stream>>>(W64, Q64);
  k_init<<<gMTL, 256, 0, stream>>>(mu, dh);

  for (int it = 0; it < 5; ++it) {
    k_gd2<<<Mb * 10, 256, 0, stream>>>(WA, Yt, mu, dh, biasp, g1, dvec);
    k_sys2<<<ML, 320, 0, stream>>>(Cg, Q64, g1, dvec, mu, dh);
  }
  k_out<<<gMTL, 256, 0, stream>>>(mu, out);
}